// Round 3
// baseline (395.813 us; speedup 1.0000x reference)
//
#include <hip/hip_runtime.h>
#include <hip/hip_bf16.h>
#include <math.h>

// Problem constants
#define T_LEN 2048
#define C_DIM 2048
#define NH 16
#define HD 128
#define RANK 64
#define W_LOCAL 512
#define QKV_LD 6144
#define ROW_BF 12288          // qkv row stride in bf16 elems
#define KB_OFF 4096           // bf16-elem offset of packed K overlay within row
#define VB_OFF 8192           // bf16-elem offset of packed V overlay within row
#define SCALE 0.08838834764831845f    // 1/sqrt(128)
#define SCALE_G 0.17677669529663687f  // scale * 128/64
#define LOG1E4_OVER_64 0.14391156831212787f

typedef __bf16 bf16_t;
typedef __bf16 bf16x8 __attribute__((ext_vector_type(8)));
typedef __bf16 bf16x4 __attribute__((ext_vector_type(4)));
typedef float f32x4 __attribute__((ext_vector_type(4)));

// ---------------------------------------------------------------------------
// async 16B global -> LDS (gfx950). LDS dst must be wave-uniform base+lane*16.
// ---------------------------------------------------------------------------
__device__ __forceinline__ void async_copy16(const bf16_t* g, bf16_t* l) {
    __builtin_amdgcn_global_load_lds(
        (const __attribute__((address_space(1))) unsigned int*)g,
        (__attribute__((address_space(3))) unsigned int*)l, 16, 0, 0);
}

// ---------------------------------------------------------------------------
// Merged prep kernel (block-range dispatch):
//  [0,2048):    x -> (xb, xlo) split-bf16
//  [2048,2560): w1 -> (w1hi, w1lo) split-bf16
//  [2560,8704): w_qkv -> wqb bf16
//  [8704,9216): rope tables
// ---------------------------------------------------------------------------
__global__ __launch_bounds__(256)
void prep_kernel(const float* __restrict__ x, bf16_t* __restrict__ xb,
                 bf16_t* __restrict__ xlo,
                 const float* __restrict__ w1, bf16_t* __restrict__ w1hi,
                 bf16_t* __restrict__ w1lo,
                 const float* __restrict__ w_qkv, bf16_t* __restrict__ wqb,
                 float* __restrict__ tab) {
    const int bid = blockIdx.x;
    const int tid = threadIdx.x;
    if (bid < 2560) {
        // split-bf16: x (blocks [0,2048)) or w1 (blocks [2048,2560))
        const float* in;
        bf16_t *hi, *lo;
        int idx;
        if (bid < 2048) { in = x; hi = xb; lo = xlo; idx = bid * 256 + tid; }
        else            { in = w1; hi = w1hi; lo = w1lo; idx = (bid - 2048) * 256 + tid; }
        const float* p = in + (size_t)idx * 8;
        float4 v0 = *(const float4*)p;
        float4 v1 = *(const float4*)(p + 4);
        float v[8] = {v0.x, v0.y, v0.z, v0.w, v1.x, v1.y, v1.z, v1.w};
        bf16x8 h, l;
#pragma unroll
        for (int i = 0; i < 8; ++i) {
            bf16_t hb = (bf16_t)v[i];
            h[i] = hb;
            l[i] = (bf16_t)(v[i] - (float)hb);
        }
        *(bf16x8*)(hi + (size_t)idx * 8) = h;
        *(bf16x8*)(lo + (size_t)idx * 8) = l;
    } else if (bid < 8704) {
        // w_qkv fp32 -> bf16 (6144x2048)
        int idx = (bid - 2560) * 256 + tid;          // 8 elems each
        const float* p = w_qkv + (size_t)idx * 8;
        float4 v0 = *(const float4*)p;
        float4 v1 = *(const float4*)(p + 4);
        bf16x8 o;
        o[0] = (bf16_t)v0.x; o[1] = (bf16_t)v0.y; o[2] = (bf16_t)v0.z; o[3] = (bf16_t)v0.w;
        o[4] = (bf16_t)v1.x; o[5] = (bf16_t)v1.y; o[6] = (bf16_t)v1.z; o[7] = (bf16_t)v1.w;
        *(bf16x8*)(wqb + (size_t)idx * 8) = o;
    } else {
        // rope tables
        int idx = (bid - 8704) * 256 + tid;          // 2048*64
        int t = idx >> 6, j = idx & 63;
        float inv = expf(-(float)j * LOG1E4_OVER_64);
        float s, c;
        sincosf((float)t * inv, &s, &c);
        tab[t * 128 + j] = c;
        tab[t * 128 + 64 + j] = s;
    }
}

// ---------------------------------------------------------------------------
// bf16 MFMA GEMM (m97 recipe), B operand fp32 converted in-register during
// staging — used for out = ctx @ w_o^T (reads w_o directly, no conversion
// pass / no overlay aliasing).
// ---------------------------------------------------------------------------
#define GBK 32

__global__ __launch_bounds__(256)
void gemm_bf16_f32b_nt(const bf16_t* __restrict__ A, const float* __restrict__ Bf,
                       float* __restrict__ C, int K, int lda, int ldb, int ldc) {
    __shared__ bf16_t As[128 * GBK];
    __shared__ bf16_t Bs[128 * GBK];
    const int tid = threadIdx.x;
    const int wave = tid >> 6, lane = tid & 63;
    const int quad = lane >> 4, l16 = lane & 15;
    const int bm = blockIdx.y * 128, bn = blockIdx.x * 128;
    const int wm = (wave >> 1) * 64, wn = (wave & 1) * 64;
    const int lrow = lane >> 2;
    const int lkb = (lane & 3) * 8;

    f32x4 acc[4][4];
#pragma unroll
    for (int i = 0; i < 4; ++i)
#pragma unroll
        for (int j = 0; j < 4; ++j) acc[i][j] = (f32x4){0.f, 0.f, 0.f, 0.f};

    const bf16_t* gA = A + (size_t)(bm + wave * 16 + lrow) * lda + lkb;
    bf16_t* lA = &As[(wave * 16 + lrow) * GBK + lkb];
    // B staging: thread covers B row (tid>>1), half (tid&1)*16 of the 32-col tile
    const float* gBf = Bf + (size_t)(bn + (tid >> 1)) * ldb + (tid & 1) * 16;
    bf16_t* lBw = &Bs[(tid >> 1) * GBK + (tid & 1) * 16];

    for (int k0 = 0; k0 < K; k0 += GBK) {
        __syncthreads();
        async_copy16(gA + k0, lA);
        async_copy16(gA + (size_t)64 * lda + k0, lA + 64 * GBK);
        {
            float4 f0 = *(const float4*)(gBf + k0);
            float4 f1 = *(const float4*)(gBf + k0 + 4);
            float4 f2 = *(const float4*)(gBf + k0 + 8);
            float4 f3 = *(const float4*)(gBf + k0 + 12);
            bf16x8 w0, w1;
            w0[0] = (bf16_t)f0.x; w0[1] = (bf16_t)f0.y; w0[2] = (bf16_t)f0.z; w0[3] = (bf16_t)f0.w;
            w0[4] = (bf16_t)f1.x; w0[5] = (bf16_t)f1.y; w0[6] = (bf16_t)f1.z; w0[7] = (bf16_t)f1.w;
            w1[0] = (bf16_t)f2.x; w1[1] = (bf16_t)f2.y; w1[2] = (bf16_t)f2.z; w1[3] = (bf16_t)f2.w;
            w1[4] = (bf16_t)f3.x; w1[5] = (bf16_t)f3.y; w1[6] = (bf16_t)f3.z; w1[7] = (bf16_t)f3.w;
            *(bf16x8*)lBw = w0;
            *(bf16x8*)(lBw + 8) = w1;
        }
        __syncthreads();

        bf16x8 a[4], b[4];
#pragma unroll
        for (int mt = 0; mt < 4; ++mt)
            a[mt] = *(const bf16x8*)&As[(wm + mt * 16 + l16) * GBK + quad * 8];
#pragma unroll
        for (int nt = 0; nt < 4; ++nt)
            b[nt] = *(const bf16x8*)&Bs[(wn + nt * 16 + l16) * GBK + quad * 8];
#pragma unroll
        for (int mt = 0; mt < 4; ++mt)
#pragma unroll
            for (int nt = 0; nt < 4; ++nt)
                acc[mt][nt] = __builtin_amdgcn_mfma_f32_16x16x32_bf16(a[mt], b[nt], acc[mt][nt], 0, 0, 0);
    }

#pragma unroll
    for (int mt = 0; mt < 4; ++mt)
#pragma unroll
        for (int r = 0; r < 4; ++r) {
            int row = bm + wm + mt * 16 + quad * 4 + r;
            float* crow = C + (size_t)row * ldc + bn + wn;
#pragma unroll
            for (int nt = 0; nt < 4; ++nt)
                crow[nt * 16 + l16] = acc[mt][nt][r];
        }
}

// ---------------------------------------------------------------------------
// qkv GEMM v4: 128x128 tile / BK=64 / 256 threads (4 waves 2x2) / 64 KiB LDS
// -> 2 blocks/CU (m97's implicit cross-block overlap) + pipelined counted
// vmcnt + both-sides XOR swizzle + fused RoPE epilogue.
//
// Per K-tile kt (buf b=kt&1):
//   ds_read all 16 frags (A 8 + B 8) from buf b; lgkmcnt(0); barrier
//   MFMA k0-sweep (16, dep-dist 16); stage A(kt+2)->buf b (4 glds)
//   MFMA k1-sweep (16);              stage B(kt+2)->buf b (4 glds)
//   vmcnt(8)  [forces tile kt+1's 8 loads complete; kt+2's stay in flight]
//   barrier
// Grid 768 = 16 bm x 48 bn, XCD-chunked so each XCD owns a 6-bn stripe
// (B stripe 3.1 MB fits the 4 MB per-XCD L2).
// LDS linear (global_load_lds constraint); logical->phys 16B chunk
// permutation p = c ^ (row&7) applied on the GLOBAL src addr at stage time
// and on the ds_read addr (rule #21).
// ---------------------------------------------------------------------------
#define NTK 32      // 2048 / 64

#define STG_A(bb, ktile) do {                                                  \
    _Pragma("unroll")                                                          \
    for (int c_ = 0; c_ < 4; ++c_)                                             \
        async_copy16(gA + (size_t)(c_ * 32) * 2048 + (ktile) * 64,             \
                     &lds[bb][0][(c_ * 32 + rS) * 64 + dS]);                   \
} while (0)

#define STG_B(bb, ktile) do {                                                  \
    _Pragma("unroll")                                                          \
    for (int c_ = 0; c_ < 4; ++c_)                                             \
        async_copy16(gB + (size_t)(c_ * 32) * 2048 + (ktile) * 64,             \
                     &lds[bb][1][(c_ * 32 + rS) * 64 + dS]);                   \
} while (0)

#define RD_A(bb, m, k) (*(const bf16x8*)&lds[bb][0][(wr * 64 + (m) * 16 + l16) * 64 + (((k) * 4 + quad) ^ xsw) * 8])
#define RD_B(bb, n, k) (*(const bf16x8*)&lds[bb][1][(wc * 64 + (n) * 16 + l16) * 64 + (((k) * 4 + quad) ^ xsw) * 8])

__global__ __launch_bounds__(256, 2)
void gemm_qkv_rope(const bf16_t* __restrict__ A, const bf16_t* __restrict__ B,
                   float* __restrict__ qkv, bf16_t* __restrict__ qkv_bf,
                   const float* __restrict__ tab) {
    __shared__ __align__(16) bf16_t lds[2][2][128 * 64];   // 64 KiB

    const int bid = blockIdx.x;                // 0..767
    const int xcd = bid & 7, idx = bid >> 3;   // 96 blocks per XCD, contiguous bn stripe
    const int bn_ = xcd * 6 + (idx >> 4);      // 0..47
    const int bm_ = idx & 15;                  // 0..15
    const int tid = threadIdx.x;
    const int wave = tid >> 6, lane = tid & 63;
    const int quad = lane >> 4, l16 = lane & 15;
    const int wr = wave >> 1, wc = wave & 1;   // 2x2 wave grid, wave tile 64x64
    const int xsw = l16 & 7;

    // staging geometry: thread covers (row rS + 32*c, phys chunk tid&7);
    // global source chunk pre-swizzled: phys chunk p holds logical p^(row&7)
    const int rS = tid >> 3;                   // 0..31
    const int cS = ((tid & 7) ^ (rS & 7)) * 8; // global col (bf16)
    const int dS = (tid & 7) * 8;              // linear LDS chunk
    const bf16_t* gA = A + (size_t)(bm_ * 128 + rS) * 2048 + cS;
    const bf16_t* gB = B + (size_t)(bn_ * 128 + rS) * 2048 + cS;

    f32x4 acc[4][4];
#pragma unroll
    for (int i = 0; i < 4; ++i)
#pragma unroll
        for (int j = 0; j < 4; ++j) acc[i][j] = (f32x4){0.f, 0.f, 0.f, 0.f};

    // Prologue: stage tiles 0 and 1; wait for tile 0, leave tile 1 in flight.
    STG_A(0, 0); STG_B(0, 0);
    STG_A(1, 1); STG_B(1, 1);
    asm volatile("s_waitcnt vmcnt(8)" ::: "memory");
    __builtin_amdgcn_s_barrier();

    for (int kt = 0; kt < NTK; ++kt) {
        const int b = kt & 1;
        bf16x8 af[4][2], bfr[4][2];
#pragma unroll
        for (int m = 0; m < 4; ++m) { af[m][0] = RD_A(b, m, 0); af[m][1] = RD_A(b, m, 1); }
#pragma unroll
        for (int n = 0; n < 4; ++n) { bfr[n][0] = RD_B(b, n, 0); bfr[n][1] = RD_B(b, n, 1); }
        asm volatile("s_waitcnt lgkmcnt(0)" ::: "memory");
        __builtin_amdgcn_s_barrier();          // all waves done reading buf b

        __builtin_amdgcn_s_setprio(1);
#pragma unroll
        for (int m = 0; m < 4; ++m)
#pragma unroll
            for (int n = 0; n < 4; ++n)
                acc[m][n] = __builtin_amdgcn_mfma_f32_16x16x32_bf16(af[m][0], bfr[n][0], acc[m][n], 0, 0, 0);
        __builtin_amdgcn_s_setprio(0);
        if (kt + 2 < NTK) STG_A(b, kt + 2);    // buf b safe to overwrite now

        __builtin_amdgcn_s_setprio(1);
#pragma unroll
        for (int m = 0; m < 4; ++m)
#pragma unroll
            for (int n = 0; n < 4; ++n)
                acc[m][n] = __builtin_amdgcn_mfma_f32_16x16x32_bf16(af[m][1], bfr[n][1], acc[m][n], 0, 0, 0);
        __builtin_amdgcn_s_setprio(0);
        if (kt + 2 < NTK) STG_B(b, kt + 2);

        if (kt < NTK - 2) { asm volatile("s_waitcnt vmcnt(8)" ::: "memory"); }
        else              { asm volatile("s_waitcnt vmcnt(0)" ::: "memory"); }
        __builtin_amdgcn_s_barrier();
    }

    // ---- epilogue: RoPE for q/k regions, plain bf16 for v region ----
    const int colbase = bn_ * 128 + wc * 64;
    const int region = colbase >> 11;          // 0=q, 1=k, 2=v (uniform: 128-tile in one region)
    const int rowbase = bm_ * 128 + wr * 64;
    const bool odd = (l16 & 1);

    if (region == 2) {
#pragma unroll
        for (int mt = 0; mt < 4; ++mt)
#pragma unroll
            for (int r = 0; r < 4; ++r) {
                int t = rowbase + mt * 16 + quad * 4 + r;
                bf16_t* brow = qkv_bf + (size_t)t * ROW_BF + VB_OFF + (colbase - 4096);
#pragma unroll
                for (int nt = 0; nt < 4; ++nt)
                    brow[nt * 16 + l16] = (bf16_t)acc[mt][nt][r];
            }
    } else {
#pragma unroll
        for (int mt = 0; mt < 4; ++mt)
#pragma unroll
            for (int r = 0; r < 4; ++r) {
                int t = rowbase + mt * 16 + quad * 4 + r;
                const float* trow = tab + t * 128;
#pragma unroll
                for (int nt = 0; nt < 4; ++nt) {
                    float v = acc[mt][nt][r];
                    float vp = __shfl_xor(v, 1);    // pair column value
                    int col = colbase + nt * 16 + l16;
                    int j = col & 63;
                    float c = trow[j], s = trow[64 + j];
                    float y = odd ? (v * c + vp * s) : (v * c - vp * s);
                    if (region == 0)
                        qkv[(size_t)t * QKV_LD + col] = y;
                    else
                        qkv_bf[(size_t)t * ROW_BF + KB_OFF + (col - 2048)] = (bf16_t)y;
                }
            }
    }
}

// ---------------------------------------------------------------------------
// Split-bf16 (3x bf16-MFMA) GEMM for the gate-critical info MLP.
// ---------------------------------------------------------------------------
__global__ __launch_bounds__(256)
void info_gemm_mfma(const bf16_t* __restrict__ Ahi, const bf16_t* __restrict__ Alo,
                    const bf16_t* __restrict__ Bhi, const bf16_t* __restrict__ Blo,
                    float* __restrict__ Cpart) {
    __shared__ bf16_t Ah[128 * GBK];
    __shared__ bf16_t Al[128 * GBK];
    __shared__ bf16_t Bh[128 * GBK];
    __shared__ bf16_t Bl[128 * GBK];
    const int tid = threadIdx.x;
    const int wave = tid >> 6, lane = tid & 63;
    const int quad = lane >> 4, l16 = lane & 15;
    const int bm = blockIdx.y * 128, bn = blockIdx.x * 128;
    const int ks = blockIdx.z;
    const int wm = (wave >> 1) * 64, wn = (wave & 1) * 64;
    const int lrow = lane >> 2;
    const int lkb = (lane & 3) * 8;
    const int kbeg = ks * 512;

    f32x4 acc[4][4];
#pragma unroll
    for (int i = 0; i < 4; ++i)
#pragma unroll
        for (int j = 0; j < 4; ++j) acc[i][j] = (f32x4){0.f, 0.f, 0.f, 0.f};

    const size_t aoff = (size_t)(bm + wave * 16 + lrow) * 2048 + lkb + kbeg;
    const size_t boff = (size_t)(bn + wave * 16 + lrow) * 2048 + lkb + kbeg;
    bf16_t* lAh = &Ah[(wave * 16 + lrow) * GBK + lkb];
    bf16_t* lAl = &Al[(wave * 16 + lrow) * GBK + lkb];
    bf16_t* lBh = &Bh[(wave * 16 + lrow) * GBK + lkb];
    bf16_t* lBl = &Bl[(wave * 16 + lrow) * GBK + lkb];

    for (int k0 = 0; k0 < 512; k0 += GBK) {
        __syncthreads();
        async_copy16(Ahi + aoff + k0, lAh);
        async_copy16(Ahi + aoff + (size_t)64 * 2048 + k0, lAh + 64 * GBK);
        async_copy16(Alo + aoff + k0, lAl);
        async_copy16(Alo + aoff + (size_t)64 * 2048 + k0, lAl + 64 * GBK);
        async_copy16(Bhi + boff + k0, lBh);
        async_copy16(Bhi + boff + (size_t)64 * 2048 + k0, lBh + 64 * GBK);
        async_copy16(Blo + boff + k0, lBl);
        async_copy16(Blo + boff + (size_t)64 * 2048 + k0, lBl + 64 * GBK);
        __syncthreads();

        bf16x8 ah[4], al[4], bh[4], bl[4];
#pragma unroll
        for (int mt = 0; mt < 4; ++mt) {
            ah[mt] = *(const bf16x8*)&Ah[(wm + mt * 16 + l16) * GBK + quad * 8];
            al[mt] = *(const bf16x8*)&Al[(wm + mt * 16 + l16) * GBK + quad * 8];
        }
#pragma unroll
        for (int nt = 0; nt < 4; ++nt) {
            bh[nt] = *(const bf16x8*)&Bh[(wn + nt * 16 + l16) * GBK + quad * 8];
            bl[nt] = *(const bf16x8*)&Bl[(wn + nt * 16 + l16) * GBK + quad * 8];
        }
#pragma unroll
        for (int mt = 0; mt < 4; ++mt)
#pragma unroll
            for (int nt = 0; nt < 4; ++nt) {
                acc[mt][nt] = __builtin_amdgcn_mfma_f32_16x16x32_bf16(ah[mt], bh[nt], acc[mt][nt], 0, 0, 0);
                acc[mt][nt] = __builtin_amdgcn_mfma_f32_16x16x32_bf16(ah[mt], bl[nt], acc[mt][nt], 0, 0, 0);
                acc[mt][nt] = __builtin_amdgcn_mfma_f32_16x16x32_bf16(al[mt], bh[nt], acc[mt][nt], 0, 0, 0);
            }
    }

    float* cp = Cpart + (size_t)ks * 2048 * 512;
#pragma unroll
    for (int mt = 0; mt < 4; ++mt)
#pragma unroll
        for (int r = 0; r < 4; ++r) {
            int row = bm + wm + mt * 16 + quad * 4 + r;
            float* crow = cp + (size_t)row * 512 + bn + wn;
#pragma unroll
            for (int nt = 0; nt < 4; ++nt)
                crow[nt * 16 + l16] = acc[mt][nt][r];
        }
}

__device__ __forceinline__ float gelu_exact(float v) {
    return 0.5f * v * (1.0f + erff(v * 0.70710678118654752f));
}

// ---------------------------------------------------------------------------
// Fused: reduce 4 split-K partials + gelu + dot(w2) + sigmoid -> gate[t].
// ---------------------------------------------------------------------------
__global__ __launch_bounds__(64)
void info_gate_kernel(const float* __restrict__ Cpart, const float* __restrict__ w2,
                      float* __restrict__ gate) {
    const int t = blockIdx.x;
    const int lane = threadIdx.x;
    const float* p0 = Cpart + (size_t)t * 512;
    float s = 0.f;
#pragma unroll
    for (int i = lane; i < 512; i += 64) {
        float v = ((p0[i] + p0[i + 1048576]) + p0[i + 2097152]) + p0[i + 3145728];
        s += gelu_exact(v) * w2[i];
    }
#pragma unroll
    for (int off = 32; off > 0; off >>= 1) s += __shfl_down(s, off);
    if (lane == 0) {
        float sig = 1.f / (1.f + expf(-s));
        gate[t] = (sig > 0.75f) ? 1.f : 0.f;
    }
}

// ---------------------------------------------------------------------------
// MFMA kvr: K/V from bf16 overlays, Q from fp32 (roped by gemm epilogue).
// ---------------------------------------------------------------------------
#define KV_LD 136

__global__ __launch_bounds__(256)
void kvr_mfma_kernel(const float* __restrict__ qkv, const bf16_t* __restrict__ qkv_bf,
                     const float* __restrict__ pk, const float* __restrict__ pv,
                     float* __restrict__ kr, float* __restrict__ vr,
                     bf16_t* __restrict__ qr) {
    __shared__ bf16_t Kt[64 * KV_LD];
    __shared__ bf16_t Vt[64 * KV_LD];
    __shared__ bf16_t Qt[64 * KV_LD];
    __shared__ bf16_t Pk[64 * KV_LD];
    __shared__ bf16_t Pv[64 * KV_LD];

    const int h = blockIdx.y;
    const int s0 = blockIdx.x * 64;
    const int tid = threadIdx.x;
    const int wave = tid >> 6, lane = tid & 63;
    const int quad = lane >> 4, l16 = lane & 15;

#pragma unroll
    for (int i = 0; i < 4; ++i) {
        int gid = i * 256 + tid;
        int row = gid >> 4, ch = (gid & 15) << 3;
        const bf16_t* rb = qkv_bf + (size_t)(s0 + row) * ROW_BF + h * HD + ch;
        *(bf16x8*)&Kt[row * KV_LD + ch] = *(const bf16x8*)(rb + KB_OFF);
        *(bf16x8*)&Vt[row * KV_LD + ch] = *(const bf16x8*)(rb + VB_OFF);
    }
#pragma unroll
    for (int i = 0; i < 8; ++i) {
        int gid = i * 256 + tid;
        int row = gid >> 5, c = (gid & 31) << 2;
        float4 vq = *(const float4*)(qkv + (size_t)(s0 + row) * QKV_LD + h * HD + c);
        bf16x4 pq;
        pq[0] = (bf16_t)vq.x; pq[1] = (bf16_t)vq.y; pq[2] = (bf16_t)vq.z; pq[3] = (bf16_t)vq.w;
        *(bf16x4*)&Qt[row * KV_LD + c] = pq;
        float4 wk = *(const float4*)(pk + (size_t)row * HD + c);
        float4 wv = *(const float4*)(pv + (size_t)row * HD + c);
        bf16x4 qk4, qv4;
        qk4[0] = (bf16_t)wk.x; qk4[1] = (bf16_t)wk.y; qk4[2] = (bf16_t)wk.z; qk4[3] = (bf16_t)wk.w;
        qv4[0] = (bf16_t)wv.x; qv4[1] = (bf16_t)wv.y; qv4[2] = (bf16_t)wv.z; qv4[3] = (bf16_t)wv.w;
        *(bf16x4*)&Pk[row * KV_LD + c] = qk4;
        *(bf16x4*)&Pv[row * KV_LD + c] = qv4;
    }
    __syncthreads();

    f32x4 ak[4], av[4], aq[4];
#pragma unroll
    for (int nt = 0; nt < 4; ++nt) {
        ak[nt] = (f32x4){0.f, 0.f, 0.f, 0.f};
        av[nt] = (f32x4){0.f, 0.f, 0.f, 0.f};
        aq[nt] = (f32x4){0.f, 0.f, 0.f, 0.f};
    }

#pragma unroll
    for (int ks = 0; ks < 4; ++ks) {
        const int ao = (wave * 16 + l16) * KV_LD + ks * 32 + quad * 8;
        bf16x8 a_k = *(const bf16x8*)&Kt[ao];
        bf16x8 a_v = *(const bf16x8*)&Vt[ao];
        bf16x8 a_q = *(const bf16x8*)&Qt[ao];
#pragma unroll
        for (int nt = 0; nt < 4; ++nt) {
            const int bo = (nt * 16 + l16) * KV_LD + ks * 32 + quad * 8;
            bf16x8 bk = *(const bf16x8*)&Pk[bo];
            bf16x8 bv = *(const bf16x8*)&Pv[bo];
            ak[nt] = __builtin_amdgcn_mfma_f32_16x16x32_bf16(a_k, bk, ak[nt], 0, 0, 0);
            av[nt] = __builtin_amdgcn_mfma_f32_16x16x32_bf16(a_v, bv, av[nt], 0, 0, 0);
            aq[nt] = __builtin_amdgcn_mfma_f32_16x16x32_bf16(a_q, bk, aq[nt], 0, 0, 0);
        }
    }

#pragma unroll
    for (int nt = 0; nt < 4; ++nt)
#pragma unroll
        for (int r = 0; r < 4; ++r) {
            int s = s0 + wave * 16 + quad * 4 + r;
            size_t idx = ((size_t)h * T_LEN + s) * RANK + nt * 16 + l16;
            kr[idx] = ak[nt][r];
            vr[idx] = av[nt][r];
            qr[idx] = (bf16_t)aq[nt][r];
        }
}

// ---------------------------------------------------------------------------
// MFMA bf16 flash local attention (v2 + mask elision on interior tiles).
// Masking provably needed only for kt==0 (window lower edge) and kt==8
// (causal diagonal): interior tiles satisfy s<=t and s>t-512 for all t0.
// ---------------------------------------------------------------------------
#define QTI 64
#define KTI 64
#define QS_LD 136
#define VT_LD 68
#define PS_LD 72

__global__ __launch_bounds__(256)
void local_attn_kernel(const float* __restrict__ qkv, const bf16_t* __restrict__ qkv_bf,
                       bf16_t* __restrict__ cxb) {
    __shared__ bf16_t Qs[QTI * QS_LD];
    __shared__ bf16_t Ks[KTI * HD];
    __shared__ bf16_t Vt[HD * VT_LD];
    __shared__ bf16_t Ps[4][16 * PS_LD];

    const int h = blockIdx.y;
    const int t0 = blockIdx.x * QTI;
    const int tid = threadIdx.x;
    const int wave = tid >> 6, lane = tid & 63;
    const int quad = lane >> 4, l16 = lane & 15;

#pragma unroll
    for (int i = 0; i < 8; ++i) {
        int gid = i * 256 + tid;
        int row = gid >> 5, c4 = (gid & 31) << 2;
        const float4 v = *(const float4*)(qkv + (size_t)(t0 + row) * QKV_LD + h * HD + c4);
        bf16x4 p;
        p[0] = (bf16_t)(v.x * SCALE); p[1] = (bf16_t)(v.y * SCALE);
        p[2] = (bf16_t)(v.z * SCALE); p[3] = (bf16_t)(v.w * SCALE);
        *(bf16x4*)&Qs[row * QS_LD + c4] = p;
    }

    f32x4 o[8];
#pragma unroll
    for (int d8 = 0; d8 < 8; ++d8) o[d8] = (f32x4){0.f, 0.f, 0.f, 0.f};
    float m_i[4] = {-1e30f, -1e30f, -1e30f, -1e30f};
    float l_i[4] = {0.f, 0.f, 0.f, 0.f};

    __syncthreads();

    for (int kt = 0; kt < 9; ++kt) {
        const int sbase = t0 - 512 + kt * KTI;
        if (sbase < 0) continue;
        __syncthreads();
#pragma unroll
        for (int i = 0; i < 4; ++i) {
            int s = i * 256 + tid;
            int row = s >> 4, ch = s & 15;
            int gch = ch ^ (row & 7);
            const bf16_t* src = qkv_bf + (size_t)(sbase + row) * ROW_BF + KB_OFF + h * HD + gch * 8;
            async_copy16(src, &Ks[s * 8]);
        }
#pragma unroll
        for (int i = 0; i < 8; ++i) {
            int gid = i * 256 + tid;
            int row = gid >> 5, c4 = (gid & 31) << 2;
            bf16x4 vv = *(const bf16x4*)(qkv_bf + (size_t)(sbase + row) * ROW_BF + VB_OFF + h * HD + c4);
            Vt[(c4 + 0) * VT_LD + row] = vv[0];
            Vt[(c4 + 1) * VT_LD + row] = vv[1];
            Vt[(c4 + 2) * VT_LD + row] = vv[2];
            Vt[(c4 + 3) * VT_LD + row] = vv[3];
        }
        __syncthreads();

        f32x4 sacc[4];
#pragma unroll
        for (int nt = 0; nt < 4; ++nt) sacc[nt] = (f32x4){0.f, 0.f, 0.f, 0.f};
#pragma unroll
        for (int ks = 0; ks < 4; ++ks) {
            bf16x8 a = *(const bf16x8*)&Qs[(wave * 16 + l16) * QS_LD + ks * 32 + quad * 8];
#pragma unroll
            for (int nt = 0; nt < 4; ++nt) {
                int r = nt * 16 + l16;
                int ch = (ks * 4 + quad) ^ (r & 7);
                bf16x8 b = *(const bf16x8*)&Ks[r * HD + ch * 8];
                sacc[nt] = __builtin_amdgcn_mfma_f32_16x16x32_bf16(a, b, sacc[nt], 0, 0, 0);
            }
        }

        if (kt == 0 || kt == 8) {   // uniform branch; interior tiles need no mask
#pragma unroll
            for (int nt = 0; nt < 4; ++nt) {
                int s_g = sbase + nt * 16 + l16;
#pragma unroll
                for (int r = 0; r < 4; ++r) {
                    int t_g = t0 + wave * 16 + quad * 4 + r;
                    bool valid = (s_g <= t_g) && (s_g + W_LOCAL > t_g);
                    if (!valid) sacc[nt][r] = -1e30f;
                }
            }
        }

#pragma unroll
        for (int r = 0; r < 4; ++r) {
            float mx = fmaxf(fmaxf(sacc[0][r], sacc[1][r]), fmaxf(sacc[2][r], sacc[3][r]));
            mx = fmaxf(mx, __shfl_xor(mx, 1));
            mx = fmaxf(mx, __shfl_xor(mx, 2));
            mx = fmaxf(mx, __shfl_xor(mx, 4));
            mx = fmaxf(mx, __shfl_xor(mx, 8));
            float mnew = fmaxf(m_i[r], mx);
            float alpha = __expf(m_i[r] - mnew);
            m_i[r] = mnew;
            float rs = 0.f;
#pragma unroll
            for (int nt = 0; nt < 4; ++nt) {
                float p = __expf(sacc[nt][r] - mnew);
                sacc[nt][r] = p;
                rs += p;
            }
            rs += __shfl_xor(rs, 1);
            rs += __shfl_xor(rs, 2);
            rs += __shfl_xor(rs, 4);
            rs += __shfl_xor(rs, 8);
            l_i[r] = l_i[r] * alpha + rs;
#pragma unroll
            for (int d8 = 0; d8 < 8; ++d8) o[d8][r] *= alpha;
        }

#pragma unroll
        for (int r = 0; r < 4; ++r)
#pragma unroll
            for (int nt = 0; nt < 4; ++nt)
                Ps[wave][(quad * 4 + r) * PS_LD + nt * 16 + l16] = (bf16_t)sacc[nt][r];

#pragma unroll
        for (int ks2 = 0; ks2 < 2; ++ks2) {
            bf16x8 a = *(const bf16x8*)&Ps[wave][l16 * PS_LD + ks2 * 32 + quad * 8];
#pragma unroll
            for (int d8 = 0; d8 < 8; ++d8) {
                const bf16_t* vb = &Vt[(d8 * 16 + l16) * VT_LD + ks2 * 32 + quad * 8];
                bf16x4 b0 = *(const bf16x4*)vb;
                bf16x4 b1 = *(const bf16x4*)(vb + 4);
                bf16x8 b;
                b[0] = b0[0]; b[1] = b0[1]; b[2] = b0[2]; b[3] = b0[3];
                b[4] = b1[0]; b[5] = b1[1]; b[6] = b1[2]; b[7] = b1[3];
                o[d8] = __builtin_amdgcn_mfma_f32_16x16x32_bf16(a, b, o[d8], 0, 0, 0);
            }
        }
    }

#pragma unroll
    for (int r = 0; r < 4; ++r) {
        float inv = 1.0f / l_i[r];
        size_t rowoff = (size_t)(t0 + wave * 16 + quad * 4 + r) * 2048 + h * HD;
#pragma unroll
        for (int d8 = 0; d8 < 8; ++d8)
            cxb[rowoff + d8 * 16 + l16] = (bf16_t)(o[d8][r] * inv);
    }
}

// ---------------------------------------------------------------------------
// Gated global low-rank branch (early-exit when gate==0); bf16 RMW into cxb
// ---------------------------------------------------------------------------
__device__ __forceinline__ float block_reduce_max512(float v, float* red, int tid) {
    red[tid] = v; __syncthreads();
    for (int s = 256; s > 0; s >>= 1) {
        if (tid < s) red[tid] = fmaxf(red[tid], red[tid + s]);
        __syncthreads();
    }
    float r = red[0]; __syncthreads();
    return r;
}
__device__ __forceinline__ float block_reduce_sum512(float v, float* red, int tid) {
    red[tid] = v; __syncthreads();
    for (int s = 256; s > 0; s >>= 1) {
        if (tid < s) red[tid] = red[tid] + red[tid + s];
        __syncthreads();
    }
    float r = red[0]; __syncthreads();
    return r;
}

__global__ __launch_bounds__(512)
void global_attn_kernel(bf16_t* __restrict__ cxb, const float* __restrict__ kr,
                        const float* __restrict__ vr, const bf16_t* __restrict__ qr,
                        const float* __restrict__ uo, const float* __restrict__ gate) {
    const int t = blockIdx.x, h = blockIdx.y;
    if (gate[t] <= 0.5f) return;

    __shared__ float qrs[64];
    __shared__ float red[512];
    __shared__ float cgr[64];
    __shared__ float sg[2048];
    const int tid = threadIdx.x;

    if (tid < 64) qrs[tid] = (float)qr[((size_t)h * T_LEN + t) * RANK + tid];
    __syncthreads();

    const float* krh = kr + (size_t)h * T_LEN * RANK;
    const float* vrh = vr + (size_t)h * T_LEN * RANK;
    float lmax = -INFINITY;
    for (int s = tid; s < T_LEN; s += 512) {
        const float* krr = krh + (size_t)s * RANK;
        float acc = 0.f;
#pragma unroll
        for (int r = 0; r < RANK; r += 4) {
            float4 k4 = *(const float4*)(krr + r);
            acc += qrs[r] * k4.x + qrs[r + 1] * k4.y + qrs[r + 2] * k4.z + qrs[r + 3] * k4.w;
        }
        float sc = acc * SCALE_G;
        sg[s] = sc;
        lmax = fmaxf(lmax, sc);
    }
    float gmx = block_reduce_max512(lmax, red, tid);
    float lsum = 0.f;
    for (int s = tid; s < T_LEN; s += 512) {
        float pp = expf(sg[s] - gmx);
        sg[s] = pp;
        lsum += pp;
    }
    float gsum = block_reduce_sum512(lsum, red, tid);

    {
        const int r = tid & 63, part = tid >> 6;
        float pacc = 0.f;
        for (int s = part; s < T_LEN; s += 8) pacc += sg[s] * vrh[(size_t)s * RANK + r];
        red[tid] = pacc;
        __syncthreads();
        if (tid < 64) {
            float c = 0.f;
#pragma unroll
            for (int pp = 0; pp < 8; ++pp) c += red[pp * 64 + tid];
            cgr[tid] = c / gsum;
        }
        __syncthreads();
    }

    if (tid < 128) {
        float cg = 0.f;
#pragma unroll
        for (int r = 0; r < RANK; ++r) cg += cgr[r] * uo[tid * RANK + r];
        size_t off = (size_t)t * 2048 + h * HD + tid;
        cxb[off] = (bf16_t)((float)cxb[off] + cg);
    }
}

// ---------------------------------------------------------------------------
extern "C" void kernel_launch(void* const* d_in, const int* in_sizes, int n_in,
                              void* d_out, int out_size, void* d_ws, size_t ws_size,
                              hipStream_t stream) {
    const float* x     = (const float*)d_in[0];
    const float* w_qkv = (const float*)d_in[1];
    const float* w_o   = (const float*)d_in[2];
    const float* pk    = (const float*)d_in[3];
    const float* pv    = (const float*)d_in[4];
    const float* uo    = (const float*)d_in[5];
    const float* w1    = (const float*)d_in[6];
    const float* w2    = (const float*)d_in[7];
    float* out = (float*)d_out;

    // Workspace layout (floats), lifetime-aliased (~84 MB):
    float* ws = (float*)d_ws;
    float* qkv   = ws;                        // 12,582,912 f: pre-GEMM info scratch;
                                              //  post-GEMM rows: q fp32 | K bf16 | (free) | V bf16
    float* hinfo = qkv + (size_t)12582912;    // 1,048,576 f: rope tab, later qr bf16
    float* gatep = hinfo + (size_t)1048576;   // 2048 f
    bf16_t* xb   = (bf16_t*)(gatep + 2048);   // x_hi bf16 (later ctx bf16)
    float* wqbf  = gatep + 2048 + 2097152;    // 6,291,456 f region:
    bf16_t* wqb  = (bf16_t*)wqbf;             //   w_qkv bf16 (entire region)
    float* krp   = wqbf;                      //   later: kr
    float* vrp   = wqbf + (size_t)2097152;    //   later: vr
    float* tabp  = hinfo;                     // rope tables (dead before qr)
    bf16_t* qrp  = (bf16_t*)hinfo;            // qr bf16 (written by kvr)
    bf16_t* cxb  = xb;                        // ctx bf16
    bf16_t* qkvb = (bf16_t*)qkv;              // bf16 overlay view of qkv rows
    // Info-MLP scratch inside the pre-GEMM qkv region:
    float* ipart  = qkv;                          // 4x2048x512 f
    bf16_t* xlo   = (bf16_t*)(qkv + 4194304);
    bf16_t* w1hi  = (bf16_t*)(qkv + 6291456);
    bf16_t* w1lo  = (bf16_t*)(qkv + 6815744);

    // 1) merged prep: x/w1 split-bf16, w_qkv->bf16, rope tables
    prep_kernel<<<9216, 256, 0, stream>>>(x, xb, xlo, w1, w1hi, w1lo, w_qkv, wqb, tabp);
    // 2) info MLP (3x bf16 MFMA split-K) -> fused reduce+gelu+gate
    info_gemm_mfma<<<dim3(4, 16, 4), 256, 0, stream>>>(xb, xlo, w1hi, w1lo, ipart);
    info_gate_kernel<<<T_LEN, 64, 0, stream>>>(ipart, w2, gatep);
    // 3) qkv GEMM (128x128, 2 blocks/CU, counted vmcnt) + fused RoPE
    gemm_qkv_rope<<<768, 256, 0, stream>>>(xb, wqb, qkv, qkvb, tabp);
    // 4) k_r, v_r, q_r via MFMA (kr/vr overwrite dead wqb; qr over dead tab)
    kvr_mfma_kernel<<<dim3(T_LEN / 64, NH), 256, 0, stream>>>(qkv, qkvb, pk, pv, krp, vrp, qrp);
    // 5) flash local attention -> ctx bf16 (cxb)
    local_attn_kernel<<<dim3(T_LEN / QTI, NH), 256, 0, stream>>>(qkv, qkvb, cxb);
    // 6) gated global branch (bf16 RMW into cxb)
    global_attn_kernel<<<dim3(T_LEN, NH), 512, 0, stream>>>(cxb, krp, vrp, qrp, uo, gatep);
    // 7) out = ctx @ w_o^T  (B = w_o fp32, converted in-register during staging)
    gemm_bf16_f32b_nt<<<dim3(16, 16), 256, 0, stream>>>(cxb, w_o, out, 2048, 2048, 2048, 2048);
}

// Round 4
// 343.408 us; speedup vs baseline: 1.1526x; 1.1526x over previous
//
#include <hip/hip_runtime.h>
#include <hip/hip_bf16.h>
#include <math.h>

// Problem constants
#define T_LEN 2048
#define C_DIM 2048
#define NH 16
#define HD 128
#define RANK 64
#define W_LOCAL 512
#define QKV_LD 6144
#define ROW_BF 12288          // qkv row stride in bf16 elems
#define KB_OFF 4096           // bf16-elem offset of packed K overlay within row
#define VB_OFF 8192           // bf16-elem offset of packed V overlay within row
#define WO_OFF 6144           // bf16-elem offset of packed w_o row within qkv row
#define SCALE 0.08838834764831845f    // 1/sqrt(128)
#define SCALE_G 0.17677669529663687f  // scale * 128/64
#define LOG1E4_OVER_64 0.14391156831212787f

typedef __bf16 bf16_t;
typedef __bf16 bf16x8 __attribute__((ext_vector_type(8)));
typedef __bf16 bf16x4 __attribute__((ext_vector_type(4)));
typedef float f32x4 __attribute__((ext_vector_type(4)));

// ---------------------------------------------------------------------------
// async 16B global -> LDS (gfx950). LDS dst must be wave-uniform base+lane*16.
// ---------------------------------------------------------------------------
__device__ __forceinline__ void async_copy16(const bf16_t* g, bf16_t* l) {
    __builtin_amdgcn_global_load_lds(
        (const __attribute__((address_space(1))) unsigned int*)g,
        (__attribute__((address_space(3))) unsigned int*)l, 16, 0, 0);
}

// ---------------------------------------------------------------------------
// Merged prep kernel (block-range dispatch):
//  [0,2048):    x -> (xb, xlo) split-bf16
//  [2048,2560): w1 -> (w1hi, w1lo) split-bf16
//  [2560,8704): w_qkv -> wqb bf16
//  [8704,9216): rope tables
// ---------------------------------------------------------------------------
__global__ __launch_bounds__(256)
void prep_kernel(const float* __restrict__ x, bf16_t* __restrict__ xb,
                 bf16_t* __restrict__ xlo,
                 const float* __restrict__ w1, bf16_t* __restrict__ w1hi,
                 bf16_t* __restrict__ w1lo,
                 const float* __restrict__ w_qkv, bf16_t* __restrict__ wqb,
                 float* __restrict__ tab) {
    const int bid = blockIdx.x;
    const int tid = threadIdx.x;
    if (bid < 2560) {
        // split-bf16: x (blocks [0,2048)) or w1 (blocks [2048,2560))
        const float* in;
        bf16_t *hi, *lo;
        int idx;
        if (bid < 2048) { in = x; hi = xb; lo = xlo; idx = bid * 256 + tid; }
        else            { in = w1; hi = w1hi; lo = w1lo; idx = (bid - 2048) * 256 + tid; }
        const float* p = in + (size_t)idx * 8;
        float4 v0 = *(const float4*)p;
        float4 v1 = *(const float4*)(p + 4);
        float v[8] = {v0.x, v0.y, v0.z, v0.w, v1.x, v1.y, v1.z, v1.w};
        bf16x8 h, l;
#pragma unroll
        for (int i = 0; i < 8; ++i) {
            bf16_t hb = (bf16_t)v[i];
            h[i] = hb;
            l[i] = (bf16_t)(v[i] - (float)hb);
        }
        *(bf16x8*)(hi + (size_t)idx * 8) = h;
        *(bf16x8*)(lo + (size_t)idx * 8) = l;
    } else if (bid < 8704) {
        // w_qkv fp32 -> bf16 (6144x2048)
        int idx = (bid - 2560) * 256 + tid;          // 8 elems each
        const float* p = w_qkv + (size_t)idx * 8;
        float4 v0 = *(const float4*)p;
        float4 v1 = *(const float4*)(p + 4);
        bf16x8 o;
        o[0] = (bf16_t)v0.x; o[1] = (bf16_t)v0.y; o[2] = (bf16_t)v0.z; o[3] = (bf16_t)v0.w;
        o[4] = (bf16_t)v1.x; o[5] = (bf16_t)v1.y; o[6] = (bf16_t)v1.z; o[7] = (bf16_t)v1.w;
        *(bf16x8*)(wqb + (size_t)idx * 8) = o;
    } else {
        // rope tables
        int idx = (bid - 8704) * 256 + tid;          // 2048*64
        int t = idx >> 6, j = idx & 63;
        float inv = expf(-(float)j * LOG1E4_OVER_64);
        float s, c;
        sincosf((float)t * inv, &s, &c);
        tab[t * 128 + j] = c;
        tab[t * 128 + 64 + j] = s;
    }
}

// ---------------------------------------------------------------------------
// qkv GEMM v4: 128x128 tile / BK=64 / 256 threads (4 waves 2x2) / 64 KiB LDS
// -> 2 blocks/CU (m97's implicit cross-block overlap) + pipelined counted
// vmcnt + both-sides XOR swizzle + fused RoPE epilogue.
//
// Per K-tile kt (buf b=kt&1):
//   ds_read all 16 frags (A 8 + B 8) from buf b; lgkmcnt(0); barrier
//   MFMA k0-sweep (16, dep-dist 16); stage A(kt+2)->buf b (4 glds)
//   MFMA k1-sweep (16);              stage B(kt+2)->buf b (4 glds)
//   vmcnt(8)  [forces tile kt+1's 8 loads complete; kt+2's stay in flight]
//   barrier
// GEMM blocks [0,768) = 16 bm x 48 bn, XCD-chunked (6-bn stripe per XCD).
// Blocks [768,2816): piggy-backed w_o row conversion into the free WO_OFF
// chunk of each qkv row (consumed later by gemm_ctx_wo).
// LDS linear (global_load_lds constraint); logical->phys 16B chunk
// permutation p = c ^ (row&7) applied on the GLOBAL src addr at stage time
// and on the ds_read addr (rule #21).
// ---------------------------------------------------------------------------
#define NTK 32      // 2048 / 64

#define STG_A(bb, ktile) do {                                                  \
    _Pragma("unroll")                                                          \
    for (int c_ = 0; c_ < 4; ++c_)                                             \
        async_copy16(gA + (size_t)(c_ * 32) * 2048 + (ktile) * 64,             \
                     &lds[bb][0][(c_ * 32 + rS) * 64 + dS]);                   \
} while (0)

#define STG_B(bb, ktile) do {                                                  \
    _Pragma("unroll")                                                          \
    for (int c_ = 0; c_ < 4; ++c_)                                             \
        async_copy16(gB + (size_t)(c_ * 32) * 2048 + (ktile) * 64,             \
                     &lds[bb][1][(c_ * 32 + rS) * 64 + dS]);                   \
} while (0)

#define RD_A(bb, m, k) (*(const bf16x8*)&lds[bb][0][(wr * 64 + (m) * 16 + l16) * 64 + (((k) * 4 + quad) ^ xsw) * 8])
#define RD_B(bb, n, k) (*(const bf16x8*)&lds[bb][1][(wc * 64 + (n) * 16 + l16) * 64 + (((k) * 4 + quad) ^ xsw) * 8])

__global__ __launch_bounds__(256, 2)
void gemm_qkv_rope(const bf16_t* __restrict__ A, const bf16_t* __restrict__ B,
                   float* __restrict__ qkv, bf16_t* __restrict__ qkv_bf,
                   const float* __restrict__ tab, const float* __restrict__ w_o) {
    const int bid = blockIdx.x;
    const int tid = threadIdx.x;
    if (bid >= 768) {
        // w_o conversion: one row per block (256 threads x 8 elems)
        int row = bid - 768;
        int c = tid * 8;
        const float* p = w_o + (size_t)row * 2048 + c;
        float4 v0 = *(const float4*)p;
        float4 v1 = *(const float4*)(p + 4);
        bf16x8 o;
        o[0] = (bf16_t)v0.x; o[1] = (bf16_t)v0.y; o[2] = (bf16_t)v0.z; o[3] = (bf16_t)v0.w;
        o[4] = (bf16_t)v1.x; o[5] = (bf16_t)v1.y; o[6] = (bf16_t)v1.z; o[7] = (bf16_t)v1.w;
        *(bf16x8*)(qkv_bf + (size_t)row * ROW_BF + WO_OFF + c) = o;
        return;
    }

    __shared__ __align__(16) bf16_t lds[2][2][128 * 64];   // 64 KiB

    const int xcd = bid & 7, idx = bid >> 3;   // 96 blocks per XCD, contiguous bn stripe
    const int bn_ = xcd * 6 + (idx >> 4);      // 0..47
    const int bm_ = idx & 15;                  // 0..15
    const int wave = tid >> 6, lane = tid & 63;
    const int quad = lane >> 4, l16 = lane & 15;
    const int wr = wave >> 1, wc = wave & 1;   // 2x2 wave grid, wave tile 64x64
    const int xsw = l16 & 7;

    // staging geometry: thread covers (row rS + 32*c, phys chunk tid&7);
    // global source chunk pre-swizzled: phys chunk p holds logical p^(row&7)
    const int rS = tid >> 3;                   // 0..31
    const int cS = ((tid & 7) ^ (rS & 7)) * 8; // global col (bf16)
    const int dS = (tid & 7) * 8;              // linear LDS chunk
    const bf16_t* gA = A + (size_t)(bm_ * 128 + rS) * 2048 + cS;
    const bf16_t* gB = B + (size_t)(bn_ * 128 + rS) * 2048 + cS;

    f32x4 acc[4][4];
#pragma unroll
    for (int i = 0; i < 4; ++i)
#pragma unroll
        for (int j = 0; j < 4; ++j) acc[i][j] = (f32x4){0.f, 0.f, 0.f, 0.f};

    // Prologue: stage tiles 0 and 1; wait for tile 0, leave tile 1 in flight.
    STG_A(0, 0); STG_B(0, 0);
    STG_A(1, 1); STG_B(1, 1);
    asm volatile("s_waitcnt vmcnt(8)" ::: "memory");
    __builtin_amdgcn_s_barrier();

    for (int kt = 0; kt < NTK; ++kt) {
        const int b = kt & 1;
        bf16x8 af[4][2], bfr[4][2];
#pragma unroll
        for (int m = 0; m < 4; ++m) { af[m][0] = RD_A(b, m, 0); af[m][1] = RD_A(b, m, 1); }
#pragma unroll
        for (int n = 0; n < 4; ++n) { bfr[n][0] = RD_B(b, n, 0); bfr[n][1] = RD_B(b, n, 1); }
        asm volatile("s_waitcnt lgkmcnt(0)" ::: "memory");
        __builtin_amdgcn_s_barrier();          // all waves done reading buf b

        __builtin_amdgcn_s_setprio(1);
#pragma unroll
        for (int m = 0; m < 4; ++m)
#pragma unroll
            for (int n = 0; n < 4; ++n)
                acc[m][n] = __builtin_amdgcn_mfma_f32_16x16x32_bf16(af[m][0], bfr[n][0], acc[m][n], 0, 0, 0);
        __builtin_amdgcn_s_setprio(0);
        if (kt + 2 < NTK) STG_A(b, kt + 2);    // buf b safe to overwrite now

        __builtin_amdgcn_s_setprio(1);
#pragma unroll
        for (int m = 0; m < 4; ++m)
#pragma unroll
            for (int n = 0; n < 4; ++n)
                acc[m][n] = __builtin_amdgcn_mfma_f32_16x16x32_bf16(af[m][1], bfr[n][1], acc[m][n], 0, 0, 0);
        __builtin_amdgcn_s_setprio(0);
        if (kt + 2 < NTK) STG_B(b, kt + 2);

        if (kt < NTK - 2) { asm volatile("s_waitcnt vmcnt(8)" ::: "memory"); }
        else              { asm volatile("s_waitcnt vmcnt(0)" ::: "memory"); }
        __builtin_amdgcn_s_barrier();
    }

    // ---- epilogue: RoPE for q/k regions, plain bf16 for v region ----
    const int colbase = bn_ * 128 + wc * 64;
    const int region = colbase >> 11;          // 0=q, 1=k, 2=v (uniform: 128-tile in one region)
    const int rowbase = bm_ * 128 + wr * 64;
    const bool odd = (l16 & 1);

    if (region == 2) {
#pragma unroll
        for (int mt = 0; mt < 4; ++mt)
#pragma unroll
            for (int r = 0; r < 4; ++r) {
                int t = rowbase + mt * 16 + quad * 4 + r;
                bf16_t* brow = qkv_bf + (size_t)t * ROW_BF + VB_OFF + (colbase - 4096);
#pragma unroll
                for (int nt = 0; nt < 4; ++nt)
                    brow[nt * 16 + l16] = (bf16_t)acc[mt][nt][r];
            }
    } else {
#pragma unroll
        for (int mt = 0; mt < 4; ++mt)
#pragma unroll
            for (int r = 0; r < 4; ++r) {
                int t = rowbase + mt * 16 + quad * 4 + r;
                const float* trow = tab + t * 128;
#pragma unroll
                for (int nt = 0; nt < 4; ++nt) {
                    float v = acc[mt][nt][r];
                    float vp = __shfl_xor(v, 1);    // pair column value
                    int col = colbase + nt * 16 + l16;
                    int j = col & 63;
                    float c = trow[j], s = trow[64 + j];
                    float y = odd ? (v * c + vp * s) : (v * c - vp * s);
                    if (region == 0)
                        qkv[(size_t)t * QKV_LD + col] = y;
                    else
                        qkv_bf[(size_t)t * ROW_BF + KB_OFF + (col - 2048)] = (bf16_t)y;
                }
            }
    }
}

// ---------------------------------------------------------------------------
// Final GEMM: out = ctx @ w_o^T, v4 pipelined structure. A = cxb (bf16,
// lda 2048); B = wob (bf16 overlay inside qkv rows, ldb ROW_BF). Grid 256
// (16x16), XCD-chunked. Same counted-vmcnt schedule + both-sides swizzle.
// ---------------------------------------------------------------------------
#define STG_A2(bb, ktile) do {                                                 \
    _Pragma("unroll")                                                          \
    for (int c_ = 0; c_ < 4; ++c_)                                             \
        async_copy16(gA + (size_t)(c_ * 32) * 2048 + (ktile) * 64,             \
                     &lds[bb][0][(c_ * 32 + rS) * 64 + dS]);                   \
} while (0)

#define STG_B2(bb, ktile) do {                                                 \
    _Pragma("unroll")                                                          \
    for (int c_ = 0; c_ < 4; ++c_)                                             \
        async_copy16(gB + (size_t)(c_ * 32) * ROW_BF + (ktile) * 64,           \
                     &lds[bb][1][(c_ * 32 + rS) * 64 + dS]);                   \
} while (0)

__global__ __launch_bounds__(256, 2)
void gemm_ctx_wo(const bf16_t* __restrict__ A, const bf16_t* __restrict__ Bov,
                 float* __restrict__ C) {
    __shared__ __align__(16) bf16_t lds[2][2][128 * 64];   // 64 KiB

    const int bid = blockIdx.x;                // 0..255
    const int xcd = bid & 7, idx = bid >> 3;   // 32 blocks per XCD
    const int bn_ = xcd * 2 + (idx >> 4);      // 0..15
    const int bm_ = idx & 15;                  // 0..15
    const int tid = threadIdx.x;
    const int wave = tid >> 6, lane = tid & 63;
    const int quad = lane >> 4, l16 = lane & 15;
    const int wr = wave >> 1, wc = wave & 1;
    const int xsw = l16 & 7;

    const int rS = tid >> 3;
    const int cS = ((tid & 7) ^ (rS & 7)) * 8;
    const int dS = (tid & 7) * 8;
    const bf16_t* gA = A + (size_t)(bm_ * 128 + rS) * 2048 + cS;
    const bf16_t* gB = Bov + (size_t)(bn_ * 128 + rS) * ROW_BF + cS;

    f32x4 acc[4][4];
#pragma unroll
    for (int i = 0; i < 4; ++i)
#pragma unroll
        for (int j = 0; j < 4; ++j) acc[i][j] = (f32x4){0.f, 0.f, 0.f, 0.f};

    STG_A2(0, 0); STG_B2(0, 0);
    STG_A2(1, 1); STG_B2(1, 1);
    asm volatile("s_waitcnt vmcnt(8)" ::: "memory");
    __builtin_amdgcn_s_barrier();

    for (int kt = 0; kt < NTK; ++kt) {
        const int b = kt & 1;
        bf16x8 af[4][2], bfr[4][2];
#pragma unroll
        for (int m = 0; m < 4; ++m) { af[m][0] = RD_A(b, m, 0); af[m][1] = RD_A(b, m, 1); }
#pragma unroll
        for (int n = 0; n < 4; ++n) { bfr[n][0] = RD_B(b, n, 0); bfr[n][1] = RD_B(b, n, 1); }
        asm volatile("s_waitcnt lgkmcnt(0)" ::: "memory");
        __builtin_amdgcn_s_barrier();

        __builtin_amdgcn_s_setprio(1);
#pragma unroll
        for (int m = 0; m < 4; ++m)
#pragma unroll
            for (int n = 0; n < 4; ++n)
                acc[m][n] = __builtin_amdgcn_mfma_f32_16x16x32_bf16(af[m][0], bfr[n][0], acc[m][n], 0, 0, 0);
        __builtin_amdgcn_s_setprio(0);
        if (kt + 2 < NTK) STG_A2(b, kt + 2);

        __builtin_amdgcn_s_setprio(1);
#pragma unroll
        for (int m = 0; m < 4; ++m)
#pragma unroll
            for (int n = 0; n < 4; ++n)
                acc[m][n] = __builtin_amdgcn_mfma_f32_16x16x32_bf16(af[m][1], bfr[n][1], acc[m][n], 0, 0, 0);
        __builtin_amdgcn_s_setprio(0);
        if (kt + 2 < NTK) STG_B2(b, kt + 2);

        if (kt < NTK - 2) { asm volatile("s_waitcnt vmcnt(8)" ::: "memory"); }
        else              { asm volatile("s_waitcnt vmcnt(0)" ::: "memory"); }
        __builtin_amdgcn_s_barrier();
    }

    const int colbase = bn_ * 128 + wc * 64;
    const int rowbase = bm_ * 128 + wr * 64;
#pragma unroll
    for (int mt = 0; mt < 4; ++mt)
#pragma unroll
        for (int r = 0; r < 4; ++r) {
            int row = rowbase + mt * 16 + quad * 4 + r;
            float* crow = C + (size_t)row * 2048 + colbase;
#pragma unroll
            for (int nt = 0; nt < 4; ++nt)
                crow[nt * 16 + l16] = acc[mt][nt][r];
        }
}

// ---------------------------------------------------------------------------
// Split-bf16 (3x bf16-MFMA) GEMM for the gate-critical info MLP.
// ---------------------------------------------------------------------------
#define GBK 32

__global__ __launch_bounds__(256)
void info_gemm_mfma(const bf16_t* __restrict__ Ahi, const bf16_t* __restrict__ Alo,
                    const bf16_t* __restrict__ Bhi, const bf16_t* __restrict__ Blo,
                    float* __restrict__ Cpart) {
    __shared__ bf16_t Ah[128 * GBK];
    __shared__ bf16_t Al[128 * GBK];
    __shared__ bf16_t Bh[128 * GBK];
    __shared__ bf16_t Bl[128 * GBK];
    const int tid = threadIdx.x;
    const int wave = tid >> 6, lane = tid & 63;
    const int quad = lane >> 4, l16 = lane & 15;
    const int bm = blockIdx.y * 128, bn = blockIdx.x * 128;
    const int ks = blockIdx.z;
    const int wm = (wave >> 1) * 64, wn = (wave & 1) * 64;
    const int lrow = lane >> 2;
    const int lkb = (lane & 3) * 8;
    const int kbeg = ks * 512;

    f32x4 acc[4][4];
#pragma unroll
    for (int i = 0; i < 4; ++i)
#pragma unroll
        for (int j = 0; j < 4; ++j) acc[i][j] = (f32x4){0.f, 0.f, 0.f, 0.f};

    const size_t aoff = (size_t)(bm + wave * 16 + lrow) * 2048 + lkb + kbeg;
    const size_t boff = (size_t)(bn + wave * 16 + lrow) * 2048 + lkb + kbeg;
    bf16_t* lAh = &Ah[(wave * 16 + lrow) * GBK + lkb];
    bf16_t* lAl = &Al[(wave * 16 + lrow) * GBK + lkb];
    bf16_t* lBh = &Bh[(wave * 16 + lrow) * GBK + lkb];
    bf16_t* lBl = &Bl[(wave * 16 + lrow) * GBK + lkb];

    for (int k0 = 0; k0 < 512; k0 += GBK) {
        __syncthreads();
        async_copy16(Ahi + aoff + k0, lAh);
        async_copy16(Ahi + aoff + (size_t)64 * 2048 + k0, lAh + 64 * GBK);
        async_copy16(Alo + aoff + k0, lAl);
        async_copy16(Alo + aoff + (size_t)64 * 2048 + k0, lAl + 64 * GBK);
        async_copy16(Bhi + boff + k0, lBh);
        async_copy16(Bhi + boff + (size_t)64 * 2048 + k0, lBh + 64 * GBK);
        async_copy16(Blo + boff + k0, lBl);
        async_copy16(Blo + boff + (size_t)64 * 2048 + k0, lBl + 64 * GBK);
        __syncthreads();

        bf16x8 ah[4], al[4], bh[4], bl[4];
#pragma unroll
        for (int mt = 0; mt < 4; ++mt) {
            ah[mt] = *(const bf16x8*)&Ah[(wm + mt * 16 + l16) * GBK + quad * 8];
            al[mt] = *(const bf16x8*)&Al[(wm + mt * 16 + l16) * GBK + quad * 8];
        }
#pragma unroll
        for (int nt = 0; nt < 4; ++nt) {
            bh[nt] = *(const bf16x8*)&Bh[(wn + nt * 16 + l16) * GBK + quad * 8];
            bl[nt] = *(const bf16x8*)&Bl[(wn + nt * 16 + l16) * GBK + quad * 8];
        }
#pragma unroll
        for (int mt = 0; mt < 4; ++mt)
#pragma unroll
            for (int nt = 0; nt < 4; ++nt) {
                acc[mt][nt] = __builtin_amdgcn_mfma_f32_16x16x32_bf16(ah[mt], bh[nt], acc[mt][nt], 0, 0, 0);
                acc[mt][nt] = __builtin_amdgcn_mfma_f32_16x16x32_bf16(ah[mt], bl[nt], acc[mt][nt], 0, 0, 0);
                acc[mt][nt] = __builtin_amdgcn_mfma_f32_16x16x32_bf16(al[mt], bh[nt], acc[mt][nt], 0, 0, 0);
            }
    }

    float* cp = Cpart + (size_t)ks * 2048 * 512;
#pragma unroll
    for (int mt = 0; mt < 4; ++mt)
#pragma unroll
        for (int r = 0; r < 4; ++r) {
            int row = bm + wm + mt * 16 + quad * 4 + r;
            float* crow = cp + (size_t)row * 512 + bn + wn;
#pragma unroll
            for (int nt = 0; nt < 4; ++nt)
                crow[nt * 16 + l16] = acc[mt][nt][r];
        }
}

__device__ __forceinline__ float gelu_exact(float v) {
    return 0.5f * v * (1.0f + erff(v * 0.70710678118654752f));
}

// ---------------------------------------------------------------------------
// Fused: reduce 4 split-K partials + gelu + dot(w2) + sigmoid -> gate[t].
// ---------------------------------------------------------------------------
__global__ __launch_bounds__(64)
void info_gate_kernel(const float* __restrict__ Cpart, const float* __restrict__ w2,
                      float* __restrict__ gate) {
    const int t = blockIdx.x;
    const int lane = threadIdx.x;
    const float* p0 = Cpart + (size_t)t * 512;
    float s = 0.f;
#pragma unroll
    for (int i = lane; i < 512; i += 64) {
        float v = ((p0[i] + p0[i + 1048576]) + p0[i + 2097152]) + p0[i + 3145728];
        s += gelu_exact(v) * w2[i];
    }
#pragma unroll
    for (int off = 32; off > 0; off >>= 1) s += __shfl_down(s, off);
    if (lane == 0) {
        float sig = 1.f / (1.f + expf(-s));
        gate[t] = (sig > 0.75f) ? 1.f : 0.f;
    }
}

// ---------------------------------------------------------------------------
// MFMA kvr: K/V from bf16 overlays, Q from fp32 (roped by gemm epilogue).
// ---------------------------------------------------------------------------
#define KV_LD 136

__global__ __launch_bounds__(256)
void kvr_mfma_kernel(const float* __restrict__ qkv, const bf16_t* __restrict__ qkv_bf,
                     const float* __restrict__ pk, const float* __restrict__ pv,
                     float* __restrict__ kr, float* __restrict__ vr,
                     bf16_t* __restrict__ qr) {
    __shared__ bf16_t Kt[64 * KV_LD];
    __shared__ bf16_t Vt[64 * KV_LD];
    __shared__ bf16_t Qt[64 * KV_LD];
    __shared__ bf16_t Pk[64 * KV_LD];
    __shared__ bf16_t Pv[64 * KV_LD];

    const int h = blockIdx.y;
    const int s0 = blockIdx.x * 64;
    const int tid = threadIdx.x;
    const int wave = tid >> 6, lane = tid & 63;
    const int quad = lane >> 4, l16 = lane & 15;

#pragma unroll
    for (int i = 0; i < 4; ++i) {
        int gid = i * 256 + tid;
        int row = gid >> 4, ch = (gid & 15) << 3;
        const bf16_t* rb = qkv_bf + (size_t)(s0 + row) * ROW_BF + h * HD + ch;
        *(bf16x8*)&Kt[row * KV_LD + ch] = *(const bf16x8*)(rb + KB_OFF);
        *(bf16x8*)&Vt[row * KV_LD + ch] = *(const bf16x8*)(rb + VB_OFF);
    }
#pragma unroll
    for (int i = 0; i < 8; ++i) {
        int gid = i * 256 + tid;
        int row = gid >> 5, c = (gid & 31) << 2;
        float4 vq = *(const float4*)(qkv + (size_t)(s0 + row) * QKV_LD + h * HD + c);
        bf16x4 pq;
        pq[0] = (bf16_t)vq.x; pq[1] = (bf16_t)vq.y; pq[2] = (bf16_t)vq.z; pq[3] = (bf16_t)vq.w;
        *(bf16x4*)&Qt[row * KV_LD + c] = pq;
        float4 wk = *(const float4*)(pk + (size_t)row * HD + c);
        float4 wv = *(const float4*)(pv + (size_t)row * HD + c);
        bf16x4 qk4, qv4;
        qk4[0] = (bf16_t)wk.x; qk4[1] = (bf16_t)wk.y; qk4[2] = (bf16_t)wk.z; qk4[3] = (bf16_t)wk.w;
        qv4[0] = (bf16_t)wv.x; qv4[1] = (bf16_t)wv.y; qv4[2] = (bf16_t)wv.z; qv4[3] = (bf16_t)wv.w;
        *(bf16x4*)&Pk[row * KV_LD + c] = qk4;
        *(bf16x4*)&Pv[row * KV_LD + c] = qv4;
    }
    __syncthreads();

    f32x4 ak[4], av[4], aq[4];
#pragma unroll
    for (int nt = 0; nt < 4; ++nt) {
        ak[nt] = (f32x4){0.f, 0.f, 0.f, 0.f};
        av[nt] = (f32x4){0.f, 0.f, 0.f, 0.f};
        aq[nt] = (f32x4){0.f, 0.f, 0.f, 0.f};
    }

#pragma unroll
    for (int ks = 0; ks < 4; ++ks) {
        const int ao = (wave * 16 + l16) * KV_LD + ks * 32 + quad * 8;
        bf16x8 a_k = *(const bf16x8*)&Kt[ao];
        bf16x8 a_v = *(const bf16x8*)&Vt[ao];
        bf16x8 a_q = *(const bf16x8*)&Qt[ao];
#pragma unroll
        for (int nt = 0; nt < 4; ++nt) {
            const int bo = (nt * 16 + l16) * KV_LD + ks * 32 + quad * 8;
            bf16x8 bk = *(const bf16x8*)&Pk[bo];
            bf16x8 bv = *(const bf16x8*)&Pv[bo];
            ak[nt] = __builtin_amdgcn_mfma_f32_16x16x32_bf16(a_k, bk, ak[nt], 0, 0, 0);
            av[nt] = __builtin_amdgcn_mfma_f32_16x16x32_bf16(a_v, bv, av[nt], 0, 0, 0);
            aq[nt] = __builtin_amdgcn_mfma_f32_16x16x32_bf16(a_q, bk, aq[nt], 0, 0, 0);
        }
    }

#pragma unroll
    for (int nt = 0; nt < 4; ++nt)
#pragma unroll
        for (int r = 0; r < 4; ++r) {
            int s = s0 + wave * 16 + quad * 4 + r;
            size_t idx = ((size_t)h * T_LEN + s) * RANK + nt * 16 + l16;
            kr[idx] = ak[nt][r];
            vr[idx] = av[nt][r];
            qr[idx] = (bf16_t)aq[nt][r];
        }
}

// ---------------------------------------------------------------------------
// MFMA bf16 flash local attention (v2 + mask elision on interior tiles).
// Masking provably needed only for kt==0 (window lower edge) and kt==8
// (causal diagonal): interior tiles satisfy s<=t and s>t-512 for all t0.
// ---------------------------------------------------------------------------
#define QTI 64
#define KTI 64
#define QS_LD 136
#define VT_LD 68
#define PS_LD 72

__global__ __launch_bounds__(256)
void local_attn_kernel(const float* __restrict__ qkv, const bf16_t* __restrict__ qkv_bf,
                       bf16_t* __restrict__ cxb) {
    __shared__ bf16_t Qs[QTI * QS_LD];
    __shared__ bf16_t Ks[KTI * HD];
    __shared__ bf16_t Vt[HD * VT_LD];
    __shared__ bf16_t Ps[4][16 * PS_LD];

    const int h = blockIdx.y;
    const int t0 = blockIdx.x * QTI;
    const int tid = threadIdx.x;
    const int wave = tid >> 6, lane = tid & 63;
    const int quad = lane >> 4, l16 = lane & 15;

#pragma unroll
    for (int i = 0; i < 8; ++i) {
        int gid = i * 256 + tid;
        int row = gid >> 5, c4 = (gid & 31) << 2;
        const float4 v = *(const float4*)(qkv + (size_t)(t0 + row) * QKV_LD + h * HD + c4);
        bf16x4 p;
        p[0] = (bf16_t)(v.x * SCALE); p[1] = (bf16_t)(v.y * SCALE);
        p[2] = (bf16_t)(v.z * SCALE); p[3] = (bf16_t)(v.w * SCALE);
        *(bf16x4*)&Qs[row * QS_LD + c4] = p;
    }

    f32x4 o[8];
#pragma unroll
    for (int d8 = 0; d8 < 8; ++d8) o[d8] = (f32x4){0.f, 0.f, 0.f, 0.f};
    float m_i[4] = {-1e30f, -1e30f, -1e30f, -1e30f};
    float l_i[4] = {0.f, 0.f, 0.f, 0.f};

    __syncthreads();

    for (int kt = 0; kt < 9; ++kt) {
        const int sbase = t0 - 512 + kt * KTI;
        if (sbase < 0) continue;
        __syncthreads();
#pragma unroll
        for (int i = 0; i < 4; ++i) {
            int s = i * 256 + tid;
            int row = s >> 4, ch = s & 15;
            int gch = ch ^ (row & 7);
            const bf16_t* src = qkv_bf + (size_t)(sbase + row) * ROW_BF + KB_OFF + h * HD + gch * 8;
            async_copy16(src, &Ks[s * 8]);
        }
#pragma unroll
        for (int i = 0; i < 8; ++i) {
            int gid = i * 256 + tid;
            int row = gid >> 5, c4 = (gid & 31) << 2;
            bf16x4 vv = *(const bf16x4*)(qkv_bf + (size_t)(sbase + row) * ROW_BF + VB_OFF + h * HD + c4);
            Vt[(c4 + 0) * VT_LD + row] = vv[0];
            Vt[(c4 + 1) * VT_LD + row] = vv[1];
            Vt[(c4 + 2) * VT_LD + row] = vv[2];
            Vt[(c4 + 3) * VT_LD + row] = vv[3];
        }
        __syncthreads();

        f32x4 sacc[4];
#pragma unroll
        for (int nt = 0; nt < 4; ++nt) sacc[nt] = (f32x4){0.f, 0.f, 0.f, 0.f};
#pragma unroll
        for (int ks = 0; ks < 4; ++ks) {
            bf16x8 a = *(const bf16x8*)&Qs[(wave * 16 + l16) * QS_LD + ks * 32 + quad * 8];
#pragma unroll
            for (int nt = 0; nt < 4; ++nt) {
                int r = nt * 16 + l16;
                int ch = (ks * 4 + quad) ^ (r & 7);
                bf16x8 b = *(const bf16x8*)&Ks[r * HD + ch * 8];
                sacc[nt] = __builtin_amdgcn_mfma_f32_16x16x32_bf16(a, b, sacc[nt], 0, 0, 0);
            }
        }

        if (kt == 0 || kt == 8) {   // uniform branch; interior tiles need no mask
#pragma unroll
            for (int nt = 0; nt < 4; ++nt) {
                int s_g = sbase + nt * 16 + l16;
#pragma unroll
                for (int r = 0; r < 4; ++r) {
                    int t_g = t0 + wave * 16 + quad * 4 + r;
                    bool valid = (s_g <= t_g) && (s_g + W_LOCAL > t_g);
                    if (!valid) sacc[nt][r] = -1e30f;
                }
            }
        }

#pragma unroll
        for (int r = 0; r < 4; ++r) {
            float mx = fmaxf(fmaxf(sacc[0][r], sacc[1][r]), fmaxf(sacc[2][r], sacc[3][r]));
            mx = fmaxf(mx, __shfl_xor(mx, 1));
            mx = fmaxf(mx, __shfl_xor(mx, 2));
            mx = fmaxf(mx, __shfl_xor(mx, 4));
            mx = fmaxf(mx, __shfl_xor(mx, 8));
            float mnew = fmaxf(m_i[r], mx);
            float alpha = __expf(m_i[r] - mnew);
            m_i[r] = mnew;
            float rs = 0.f;
#pragma unroll
            for (int nt = 0; nt < 4; ++nt) {
                float p = __expf(sacc[nt][r] - mnew);
                sacc[nt][r] = p;
                rs += p;
            }
            rs += __shfl_xor(rs, 1);
            rs += __shfl_xor(rs, 2);
            rs += __shfl_xor(rs, 4);
            rs += __shfl_xor(rs, 8);
            l_i[r] = l_i[r] * alpha + rs;
#pragma unroll
            for (int d8 = 0; d8 < 8; ++d8) o[d8][r] *= alpha;
        }

#pragma unroll
        for (int r = 0; r < 4; ++r)
#pragma unroll
            for (int nt = 0; nt < 4; ++nt)
                Ps[wave][(quad * 4 + r) * PS_LD + nt * 16 + l16] = (bf16_t)sacc[nt][r];

#pragma unroll
        for (int ks2 = 0; ks2 < 2; ++ks2) {
            bf16x8 a = *(const bf16x8*)&Ps[wave][l16 * PS_LD + ks2 * 32 + quad * 8];
#pragma unroll
            for (int d8 = 0; d8 < 8; ++d8) {
                const bf16_t* vb = &Vt[(d8 * 16 + l16) * VT_LD + ks2 * 32 + quad * 8];
                bf16x4 b0 = *(const bf16x4*)vb;
                bf16x4 b1 = *(const bf16x4*)(vb + 4);
                bf16x8 b;
                b[0] = b0[0]; b[1] = b0[1]; b[2] = b0[2]; b[3] = b0[3];
                b[4] = b1[0]; b[5] = b1[1]; b[6] = b1[2]; b[7] = b1[3];
                o[d8] = __builtin_amdgcn_mfma_f32_16x16x32_bf16(a, b, o[d8], 0, 0, 0);
            }
        }
    }

#pragma unroll
    for (int r = 0; r < 4; ++r) {
        float inv = 1.0f / l_i[r];
        size_t rowoff = (size_t)(t0 + wave * 16 + quad * 4 + r) * 2048 + h * HD;
#pragma unroll
        for (int d8 = 0; d8 < 8; ++d8)
            cxb[rowoff + d8 * 16 + l16] = (bf16_t)(o[d8][r] * inv);
    }
}

// ---------------------------------------------------------------------------
// Gated global low-rank branch (early-exit when gate==0); bf16 RMW into cxb
// ---------------------------------------------------------------------------
__device__ __forceinline__ float block_reduce_max512(float v, float* red, int tid) {
    red[tid] = v; __syncthreads();
    for (int s = 256; s > 0; s >>= 1) {
        if (tid < s) red[tid] = fmaxf(red[tid], red[tid + s]);
        __syncthreads();
    }
    float r = red[0]; __syncthreads();
    return r;
}
__device__ __forceinline__ float block_reduce_sum512(float v, float* red, int tid) {
    red[tid] = v; __syncthreads();
    for (int s = 256; s > 0; s >>= 1) {
        if (tid < s) red[tid] = red[tid] + red[tid + s];
        __syncthreads();
    }
    float r = red[0]; __syncthreads();
    return r;
}

__global__ __launch_bounds__(512)
void global_attn_kernel(bf16_t* __restrict__ cxb, const float* __restrict__ kr,
                        const float* __restrict__ vr, const bf16_t* __restrict__ qr,
                        const float* __restrict__ uo, const float* __restrict__ gate) {
    const int t = blockIdx.x, h = blockIdx.y;
    if (gate[t] <= 0.5f) return;

    __shared__ float qrs[64];
    __shared__ float red[512];
    __shared__ float cgr[64];
    __shared__ float sg[2048];
    const int tid = threadIdx.x;

    if (tid < 64) qrs[tid] = (float)qr[((size_t)h * T_LEN + t) * RANK + tid];
    __syncthreads();

    const float* krh = kr + (size_t)h * T_LEN * RANK;
    const float* vrh = vr + (size_t)h * T_LEN * RANK;
    float lmax = -INFINITY;
    for (int s = tid; s < T_LEN; s += 512) {
        const float* krr = krh + (size_t)s * RANK;
        float acc = 0.f;
#pragma unroll
        for (int r = 0; r < RANK; r += 4) {
            float4 k4 = *(const float4*)(krr + r);
            acc += qrs[r] * k4.x + qrs[r + 1] * k4.y + qrs[r + 2] * k4.z + qrs[r + 3] * k4.w;
        }
        float sc = acc * SCALE_G;
        sg[s] = sc;
        lmax = fmaxf(lmax, sc);
    }
    float gmx = block_reduce_max512(lmax, red, tid);
    float lsum = 0.f;
    for (int s = tid; s < T_LEN; s += 512) {
        float pp = expf(sg[s] - gmx);
        sg[s] = pp;
        lsum += pp;
    }
    float gsum = block_reduce_sum512(lsum, red, tid);

    {
        const int r = tid & 63, part = tid >> 6;
        float pacc = 0.f;
        for (int s = part; s < T_LEN; s += 8) pacc += sg[s] * vrh[(size_t)s * RANK + r];
        red[tid] = pacc;
        __syncthreads();
        if (tid < 64) {
            float c = 0.f;
#pragma unroll
            for (int pp = 0; pp < 8; ++pp) c += red[pp * 64 + tid];
            cgr[tid] = c / gsum;
        }
        __syncthreads();
    }

    if (tid < 128) {
        float cg = 0.f;
#pragma unroll
        for (int r = 0; r < RANK; ++r) cg += cgr[r] * uo[tid * RANK + r];
        size_t off = (size_t)t * 2048 + h * HD + tid;
        cxb[off] = (bf16_t)((float)cxb[off] + cg);
    }
}

// ---------------------------------------------------------------------------
extern "C" void kernel_launch(void* const* d_in, const int* in_sizes, int n_in,
                              void* d_out, int out_size, void* d_ws, size_t ws_size,
                              hipStream_t stream) {
    const float* x     = (const float*)d_in[0];
    const float* w_qkv = (const float*)d_in[1];
    const float* w_o   = (const float*)d_in[2];
    const float* pk    = (const float*)d_in[3];
    const float* pv    = (const float*)d_in[4];
    const float* uo    = (const float*)d_in[5];
    const float* w1    = (const float*)d_in[6];
    const float* w2    = (const float*)d_in[7];
    float* out = (float*)d_out;

    // Workspace layout (floats), lifetime-aliased (~84 MB):
    float* ws = (float*)d_ws;
    float* qkv   = ws;                        // 12,582,912 f: pre-GEMM info scratch;
                                              //  post-GEMM rows: q fp32 | K bf16 | wo bf16 | V bf16
    float* hinfo = qkv + (size_t)12582912;    // 1,048,576 f: rope tab, later qr bf16
    float* gatep = hinfo + (size_t)1048576;   // 2048 f
    bf16_t* xb   = (bf16_t*)(gatep + 2048);   // x_hi bf16 (later ctx bf16)
    float* wqbf  = gatep + 2048 + 2097152;    // 6,291,456 f region:
    bf16_t* wqb  = (bf16_t*)wqbf;             //   w_qkv bf16 (entire region)
    float* krp   = wqbf;                      //   later: kr
    float* vrp   = wqbf + (size_t)2097152;    //   later: vr
    float* tabp  = hinfo;                     // rope tables (dead before qr)
    bf16_t* qrp  = (bf16_t*)hinfo;            // qr bf16 (written by kvr)
    bf16_t* cxb  = xb;                        // ctx bf16
    bf16_t* qkvb = (bf16_t*)qkv;              // bf16 overlay view of qkv rows
    bf16_t* wob  = qkvb + WO_OFF;             // w_o bf16, row stride ROW_BF
    // Info-MLP scratch inside the pre-GEMM qkv region:
    float* ipart  = qkv;                          // 4x2048x512 f
    bf16_t* xlo   = (bf16_t*)(qkv + 4194304);
    bf16_t* w1hi  = (bf16_t*)(qkv + 6291456);
    bf16_t* w1lo  = (bf16_t*)(qkv + 6815744);

    // 1) merged prep: x/w1 split-bf16, w_qkv->bf16, rope tables
    prep_kernel<<<9216, 256, 0, stream>>>(x, xb, xlo, w1, w1hi, w1lo, w_qkv, wqb, tabp);
    // 2) info MLP (3x bf16 MFMA split-K) -> fused reduce+gelu+gate
    info_gemm_mfma<<<dim3(4, 16, 4), 256, 0, stream>>>(xb, xlo, w1hi, w1lo, ipart);
    info_gate_kernel<<<T_LEN, 64, 0, stream>>>(ipart, w2, gatep);
    // 3) qkv GEMM (128x128 v4, 2 blocks/CU, counted vmcnt) + fused RoPE
    //    + piggy-backed w_o->bf16 into WO_OFF overlay (blocks [768,2816))
    gemm_qkv_rope<<<2816, 256, 0, stream>>>(xb, wqb, qkv, qkvb, tabp, w_o);
    // 4) k_r, v_r, q_r via MFMA (kr/vr overwrite dead wqb; qr over dead tab)
    kvr_mfma_kernel<<<dim3(T_LEN / 64, NH), 256, 0, stream>>>(qkv, qkvb, pk, pv, krp, vrp, qrp);
    // 5) flash local attention -> ctx bf16 (cxb)
    local_attn_kernel<<<dim3(T_LEN / QTI, NH), 256, 0, stream>>>(qkv, qkvb, cxb);
    // 6) gated global branch (bf16 RMW into cxb)
    global_attn_kernel<<<dim3(T_LEN, NH), 512, 0, stream>>>(cxb, krp, vrp, qrp, uo, gatep);
    // 7) out = ctx @ w_o^T  (v4 pipelined, B = wob overlay strided ROW_BF)
    gemm_ctx_wo<<<256, 256, 0, stream>>>(cxb, wob, out);
}

// Round 5
// 307.681 us; speedup vs baseline: 1.2864x; 1.1161x over previous
//
#include <hip/hip_runtime.h>
#include <hip/hip_bf16.h>
#include <math.h>

// Problem constants
#define T_LEN 2048
#define C_DIM 2048
#define NH 16
#define HD 128
#define RANK 64
#define W_LOCAL 512
#define QKV_LD 6144
#define ROW_BF 12288          // qkv row stride in bf16 elems
#define KB_OFF 4096           // bf16-elem offset of packed K overlay within row
#define VB_OFF 8192           // bf16-elem offset of packed V overlay within row
#define WO_OFF 6144           // bf16-elem offset of packed w_o row within qkv row
#define SCALE 0.08838834764831845f    // 1/sqrt(128)
#define SCALE_G 0.17677669529663687f  // scale * 128/64
#define LOG1E4_OVER_64 0.14391156831212787f

typedef __bf16 bf16_t;
typedef __bf16 bf16x8 __attribute__((ext_vector_type(8)));
typedef __bf16 bf16x4 __attribute__((ext_vector_type(4)));
typedef float f32x4 __attribute__((ext_vector_type(4)));

// ---------------------------------------------------------------------------
// async 16B global -> LDS (gfx950). LDS dst must be wave-uniform base+lane*16.
// ---------------------------------------------------------------------------
__device__ __forceinline__ void async_copy16(const bf16_t* g, bf16_t* l) {
    __builtin_amdgcn_global_load_lds(
        (const __attribute__((address_space(1))) unsigned int*)g,
        (__attribute__((address_space(3))) unsigned int*)l, 16, 0, 0);
}

// ---------------------------------------------------------------------------
// Merged prep kernel (block-range dispatch):
//  [0,2048):    x -> (xb, xlo) split-bf16
//  [2048,2560): w1 -> (w1hi, w1lo) split-bf16
//  [2560,8704): w_qkv -> wqb bf16
//  [8704,9216): rope tables
// ---------------------------------------------------------------------------
__global__ __launch_bounds__(256)
void prep_kernel(const float* __restrict__ x, bf16_t* __restrict__ xb,
                 bf16_t* __restrict__ xlo,
                 const float* __restrict__ w1, bf16_t* __restrict__ w1hi,
                 bf16_t* __restrict__ w1lo,
                 const float* __restrict__ w_qkv, bf16_t* __restrict__ wqb,
                 float* __restrict__ tab) {
    const int bid = blockIdx.x;
    const int tid = threadIdx.x;
    if (bid < 2560) {
        // split-bf16: x (blocks [0,2048)) or w1 (blocks [2048,2560))
        const float* in;
        bf16_t *hi, *lo;
        int idx;
        if (bid < 2048) { in = x; hi = xb; lo = xlo; idx = bid * 256 + tid; }
        else            { in = w1; hi = w1hi; lo = w1lo; idx = (bid - 2048) * 256 + tid; }
        const float* p = in + (size_t)idx * 8;
        float4 v0 = *(const float4*)p;
        float4 v1 = *(const float4*)(p + 4);
        float v[8] = {v0.x, v0.y, v0.z, v0.w, v1.x, v1.y, v1.z, v1.w};
        bf16x8 h, l;
#pragma unroll
        for (int i = 0; i < 8; ++i) {
            bf16_t hb = (bf16_t)v[i];
            h[i] = hb;
            l[i] = (bf16_t)(v[i] - (float)hb);
        }
        *(bf16x8*)(hi + (size_t)idx * 8) = h;
        *(bf16x8*)(lo + (size_t)idx * 8) = l;
    } else if (bid < 8704) {
        // w_qkv fp32 -> bf16 (6144x2048)
        int idx = (bid - 2560) * 256 + tid;          // 8 elems each
        const float* p = w_qkv + (size_t)idx * 8;
        float4 v0 = *(const float4*)p;
        float4 v1 = *(const float4*)(p + 4);
        bf16x8 o;
        o[0] = (bf16_t)v0.x; o[1] = (bf16_t)v0.y; o[2] = (bf16_t)v0.z; o[3] = (bf16_t)v0.w;
        o[4] = (bf16_t)v1.x; o[5] = (bf16_t)v1.y; o[6] = (bf16_t)v1.z; o[7] = (bf16_t)v1.w;
        *(bf16x8*)(wqb + (size_t)idx * 8) = o;
    } else {
        // rope tables
        int idx = (bid - 8704) * 256 + tid;          // 2048*64
        int t = idx >> 6, j = idx & 63;
        float inv = expf(-(float)j * LOG1E4_OVER_64);
        float s, c;
        sincosf((float)t * inv, &s, &c);
        tab[t * 128 + j] = c;
        tab[t * 128 + 64 + j] = s;
    }
}

// ---------------------------------------------------------------------------
// qkv GEMM v4: 128x128 tile / BK=64 / 256 threads (4 waves 2x2) / 64 KiB LDS
// -> 2 blocks/CU + pipelined counted vmcnt + both-sides XOR swizzle.
// Epilogue: RoPE'd q -> bf16 overlay @0, RoPE'd k -> overlay @KB_OFF,
// v -> overlay @VB_OFF (row-major, for kvr) AND transposed vt[h][128][2048]
// (for local_attn PV), via in-LDS transpose + coalesced stores.
// GEMM blocks [0,768) = 16 bm x 48 bn, XCD-chunked (6-bn stripe per XCD).
// Blocks [768,2816): piggy-backed w_o row conversion into WO_OFF overlay.
// ---------------------------------------------------------------------------
#define NTK 32      // 2048 / 64

#define STG_A(bb, ktile) do {                                                  \
    _Pragma("unroll")                                                          \
    for (int c_ = 0; c_ < 4; ++c_)                                             \
        async_copy16(gA + (size_t)(c_ * 32) * 2048 + (ktile) * 64,             \
                     &lds[bb][0][(c_ * 32 + rS) * 64 + dS]);                   \
} while (0)

#define STG_B(bb, ktile) do {                                                  \
    _Pragma("unroll")                                                          \
    for (int c_ = 0; c_ < 4; ++c_)                                             \
        async_copy16(gB + (size_t)(c_ * 32) * 2048 + (ktile) * 64,             \
                     &lds[bb][1][(c_ * 32 + rS) * 64 + dS]);                   \
} while (0)

#define RD_A(bb, m, k) (*(const bf16x8*)&lds[bb][0][(wr * 64 + (m) * 16 + l16) * 64 + (((k) * 4 + quad) ^ xsw) * 8])
#define RD_B(bb, n, k) (*(const bf16x8*)&lds[bb][1][(wc * 64 + (n) * 16 + l16) * 64 + (((k) * 4 + quad) ^ xsw) * 8])

__global__ __launch_bounds__(256, 2)
void gemm_qkv_rope(const bf16_t* __restrict__ A, const bf16_t* __restrict__ B,
                   bf16_t* __restrict__ qkv_bf, bf16_t* __restrict__ vt,
                   const float* __restrict__ tab, const float* __restrict__ w_o) {
    const int bid = blockIdx.x;
    const int tid = threadIdx.x;
    if (bid >= 768) {
        // w_o conversion: one row per block (256 threads x 8 elems)
        int row = bid - 768;
        int c = tid * 8;
        const float* p = w_o + (size_t)row * 2048 + c;
        float4 v0 = *(const float4*)p;
        float4 v1 = *(const float4*)(p + 4);
        bf16x8 o;
        o[0] = (bf16_t)v0.x; o[1] = (bf16_t)v0.y; o[2] = (bf16_t)v0.z; o[3] = (bf16_t)v0.w;
        o[4] = (bf16_t)v1.x; o[5] = (bf16_t)v1.y; o[6] = (bf16_t)v1.z; o[7] = (bf16_t)v1.w;
        *(bf16x8*)(qkv_bf + (size_t)row * ROW_BF + WO_OFF + c) = o;
        return;
    }

    __shared__ __align__(16) bf16_t lds[2][2][128 * 64];   // 64 KiB

    const int xcd = bid & 7, idx = bid >> 3;   // 96 blocks per XCD, contiguous bn stripe
    const int bn_ = xcd * 6 + (idx >> 4);      // 0..47
    const int bm_ = idx & 15;                  // 0..15
    const int wave = tid >> 6, lane = tid & 63;
    const int quad = lane >> 4, l16 = lane & 15;
    const int wr = wave >> 1, wc = wave & 1;   // 2x2 wave grid, wave tile 64x64
    const int xsw = l16 & 7;

    // staging geometry: thread covers (row rS + 32*c, phys chunk tid&7);
    // global source chunk pre-swizzled: phys chunk p holds logical p^(row&7)
    const int rS = tid >> 3;                   // 0..31
    const int cS = ((tid & 7) ^ (rS & 7)) * 8; // global col (bf16)
    const int dS = (tid & 7) * 8;              // linear LDS chunk
    const bf16_t* gA = A + (size_t)(bm_ * 128 + rS) * 2048 + cS;
    const bf16_t* gB = B + (size_t)(bn_ * 128 + rS) * 2048 + cS;

    f32x4 acc[4][4];
#pragma unroll
    for (int i = 0; i < 4; ++i)
#pragma unroll
        for (int j = 0; j < 4; ++j) acc[i][j] = (f32x4){0.f, 0.f, 0.f, 0.f};

    // Prologue: stage tiles 0 and 1; wait for tile 0, leave tile 1 in flight.
    STG_A(0, 0); STG_B(0, 0);
    STG_A(1, 1); STG_B(1, 1);
    asm volatile("s_waitcnt vmcnt(8)" ::: "memory");
    __builtin_amdgcn_s_barrier();

    for (int kt = 0; kt < NTK; ++kt) {
        const int b = kt & 1;
        bf16x8 af[4][2], bfr[4][2];
#pragma unroll
        for (int m = 0; m < 4; ++m) { af[m][0] = RD_A(b, m, 0); af[m][1] = RD_A(b, m, 1); }
#pragma unroll
        for (int n = 0; n < 4; ++n) { bfr[n][0] = RD_B(b, n, 0); bfr[n][1] = RD_B(b, n, 1); }
        asm volatile("s_waitcnt lgkmcnt(0)" ::: "memory");
        __builtin_amdgcn_s_barrier();          // all waves done reading buf b

        __builtin_amdgcn_s_setprio(1);
#pragma unroll
        for (int m = 0; m < 4; ++m)
#pragma unroll
            for (int n = 0; n < 4; ++n)
                acc[m][n] = __builtin_amdgcn_mfma_f32_16x16x32_bf16(af[m][0], bfr[n][0], acc[m][n], 0, 0, 0);
        __builtin_amdgcn_s_setprio(0);
        if (kt + 2 < NTK) STG_A(b, kt + 2);    // buf b safe to overwrite now

        __builtin_amdgcn_s_setprio(1);
#pragma unroll
        for (int m = 0; m < 4; ++m)
#pragma unroll
            for (int n = 0; n < 4; ++n)
                acc[m][n] = __builtin_amdgcn_mfma_f32_16x16x32_bf16(af[m][1], bfr[n][1], acc[m][n], 0, 0, 0);
        __builtin_amdgcn_s_setprio(0);
        if (kt + 2 < NTK) STG_B(b, kt + 2);

        if (kt < NTK - 2) { asm volatile("s_waitcnt vmcnt(8)" ::: "memory"); }
        else              { asm volatile("s_waitcnt vmcnt(0)" ::: "memory"); }
        __builtin_amdgcn_s_barrier();
    }

    // ---- epilogue ----
    const int colbase = bn_ * 128 + wc * 64;
    const int region = (bn_ * 128) >> 11;      // 0=q, 1=k, 2=v (block-uniform)
    const int rowbase = bm_ * 128 + wr * 64;
    const bool odd = (l16 & 1);

    if (region == 2) {
        // (a) row-major V overlay (for kvr)
#pragma unroll
        for (int mt = 0; mt < 4; ++mt)
#pragma unroll
            for (int r = 0; r < 4; ++r) {
                int t = rowbase + mt * 16 + quad * 4 + r;
                bf16_t* brow = qkv_bf + (size_t)t * ROW_BF + VB_OFF + (colbase - 4096);
#pragma unroll
                for (int nt = 0; nt < 4; ++nt)
                    brow[nt * 16 + l16] = (bf16_t)acc[mt][nt][r];
            }
        // (b) transposed vt[h][d][t] via LDS transpose (tile = exactly one head)
        bf16_t* Tl = (bf16_t*)lds;             // [128][136] bf16, 34.8 KB
#pragma unroll
        for (int mt = 0; mt < 4; ++mt)
#pragma unroll
            for (int r = 0; r < 4; ++r) {
                int rloc = wr * 64 + mt * 16 + quad * 4 + r;
#pragma unroll
                for (int nt = 0; nt < 4; ++nt) {
                    int cloc = wc * 64 + nt * 16 + l16;
                    Tl[cloc * 136 + rloc] = (bf16_t)acc[mt][nt][r];
                }
            }
        __syncthreads();
        const int hh = bn_ - 32;               // head index
        const int d = tid >> 1, th = (tid & 1) * 64;
        bf16_t* dst = vt + ((size_t)(hh * 128 + d)) * 2048 + bm_ * 128 + th;
        const bf16_t* srcT = Tl + d * 136 + th;
#pragma unroll
        for (int j = 0; j < 8; ++j)
            *(bf16x8*)(dst + j * 8) = *(const bf16x8*)(srcT + j * 8);
    } else {
        // RoPE for q/k; store bf16 overlay (q @0, k @KB_OFF)
#pragma unroll
        for (int mt = 0; mt < 4; ++mt)
#pragma unroll
            for (int r = 0; r < 4; ++r) {
                int t = rowbase + mt * 16 + quad * 4 + r;
                const float* trow = tab + t * 128;
#pragma unroll
                for (int nt = 0; nt < 4; ++nt) {
                    float v = acc[mt][nt][r];
                    float vp = __shfl_xor(v, 1);    // pair column value
                    int col = colbase + nt * 16 + l16;
                    int j = col & 63;
                    float c = trow[j], s = trow[64 + j];
                    float y = odd ? (v * c + vp * s) : (v * c - vp * s);
                    qkv_bf[(size_t)t * ROW_BF + (region == 0 ? col : col + 2048)] = (bf16_t)y;
                }
            }
    }
}

// ---------------------------------------------------------------------------
// Final GEMM: out = ctx @ w_o^T, v4 pipelined structure. A = cxb (bf16,
// lda 2048); B = wob (bf16 overlay inside qkv rows, ldb ROW_BF). Grid 256
// (16x16), XCD-chunked. Same counted-vmcnt schedule + both-sides swizzle.
// ---------------------------------------------------------------------------
#define STG_A2(bb, ktile) do {                                                 \
    _Pragma("unroll")                                                          \
    for (int c_ = 0; c_ < 4; ++c_)                                             \
        async_copy16(gA + (size_t)(c_ * 32) * 2048 + (ktile) * 64,             \
                     &lds[bb][0][(c_ * 32 + rS) * 64 + dS]);                   \
} while (0)

#define STG_B2(bb, ktile) do {                                                 \
    _Pragma("unroll")                                                          \
    for (int c_ = 0; c_ < 4; ++c_)                                             \
        async_copy16(gB + (size_t)(c_ * 32) * ROW_BF + (ktile) * 64,           \
                     &lds[bb][1][(c_ * 32 + rS) * 64 + dS]);                   \
} while (0)

__global__ __launch_bounds__(256, 2)
void gemm_ctx_wo(const bf16_t* __restrict__ A, const bf16_t* __restrict__ Bov,
                 float* __restrict__ C) {
    __shared__ __align__(16) bf16_t lds[2][2][128 * 64];   // 64 KiB

    const int bid = blockIdx.x;                // 0..255
    const int xcd = bid & 7, idx = bid >> 3;   // 32 blocks per XCD
    const int bn_ = xcd * 2 + (idx >> 4);      // 0..15
    const int bm_ = idx & 15;                  // 0..15
    const int tid = threadIdx.x;
    const int wave = tid >> 6, lane = tid & 63;
    const int quad = lane >> 4, l16 = lane & 15;
    const int wr = wave >> 1, wc = wave & 1;
    const int xsw = l16 & 7;

    const int rS = tid >> 3;
    const int cS = ((tid & 7) ^ (rS & 7)) * 8;
    const int dS = (tid & 7) * 8;
    const bf16_t* gA = A + (size_t)(bm_ * 128 + rS) * 2048 + cS;
    const bf16_t* gB = Bov + (size_t)(bn_ * 128 + rS) * ROW_BF + cS;

    f32x4 acc[4][4];
#pragma unroll
    for (int i = 0; i < 4; ++i)
#pragma unroll
        for (int j = 0; j < 4; ++j) acc[i][j] = (f32x4){0.f, 0.f, 0.f, 0.f};

    STG_A2(0, 0); STG_B2(0, 0);
    STG_A2(1, 1); STG_B2(1, 1);
    asm volatile("s_waitcnt vmcnt(8)" ::: "memory");
    __builtin_amdgcn_s_barrier();

    for (int kt = 0; kt < NTK; ++kt) {
        const int b = kt & 1;
        bf16x8 af[4][2], bfr[4][2];
#pragma unroll
        for (int m = 0; m < 4; ++m) { af[m][0] = RD_A(b, m, 0); af[m][1] = RD_A(b, m, 1); }
#pragma unroll
        for (int n = 0; n < 4; ++n) { bfr[n][0] = RD_B(b, n, 0); bfr[n][1] = RD_B(b, n, 1); }
        asm volatile("s_waitcnt lgkmcnt(0)" ::: "memory");
        __builtin_amdgcn_s_barrier();

        __builtin_amdgcn_s_setprio(1);
#pragma unroll
        for (int m = 0; m < 4; ++m)
#pragma unroll
            for (int n = 0; n < 4; ++n)
                acc[m][n] = __builtin_amdgcn_mfma_f32_16x16x32_bf16(af[m][0], bfr[n][0], acc[m][n], 0, 0, 0);
        __builtin_amdgcn_s_setprio(0);
        if (kt + 2 < NTK) STG_A2(b, kt + 2);

        __builtin_amdgcn_s_setprio(1);
#pragma unroll
        for (int m = 0; m < 4; ++m)
#pragma unroll
            for (int n = 0; n < 4; ++n)
                acc[m][n] = __builtin_amdgcn_mfma_f32_16x16x32_bf16(af[m][1], bfr[n][1], acc[m][n], 0, 0, 0);
        __builtin_amdgcn_s_setprio(0);
        if (kt + 2 < NTK) STG_B2(b, kt + 2);

        if (kt < NTK - 2) { asm volatile("s_waitcnt vmcnt(8)" ::: "memory"); }
        else              { asm volatile("s_waitcnt vmcnt(0)" ::: "memory"); }
        __builtin_amdgcn_s_barrier();
    }

    const int colbase = bn_ * 128 + wc * 64;
    const int rowbase = bm_ * 128 + wr * 64;
#pragma unroll
    for (int mt = 0; mt < 4; ++mt)
#pragma unroll
        for (int r = 0; r < 4; ++r) {
            int row = rowbase + mt * 16 + quad * 4 + r;
            float* crow = C + (size_t)row * 2048 + colbase;
#pragma unroll
            for (int nt = 0; nt < 4; ++nt)
                crow[nt * 16 + l16] = acc[mt][nt][r];
        }
}

// ---------------------------------------------------------------------------
// Split-bf16 (3x bf16-MFMA) GEMM for the gate-critical info MLP.
// ---------------------------------------------------------------------------
#define GBK 32

__global__ __launch_bounds__(256)
void info_gemm_mfma(const bf16_t* __restrict__ Ahi, const bf16_t* __restrict__ Alo,
                    const bf16_t* __restrict__ Bhi, const bf16_t* __restrict__ Blo,
                    float* __restrict__ Cpart) {
    __shared__ bf16_t Ah[128 * GBK];
    __shared__ bf16_t Al[128 * GBK];
    __shared__ bf16_t Bh[128 * GBK];
    __shared__ bf16_t Bl[128 * GBK];
    const int tid = threadIdx.x;
    const int wave = tid >> 6, lane = tid & 63;
    const int quad = lane >> 4, l16 = lane & 15;
    const int bm = blockIdx.y * 128, bn = blockIdx.x * 128;
    const int ks = blockIdx.z;
    const int wm = (wave >> 1) * 64, wn = (wave & 1) * 64;
    const int lrow = lane >> 2;
    const int lkb = (lane & 3) * 8;
    const int kbeg = ks * 512;

    f32x4 acc[4][4];
#pragma unroll
    for (int i = 0; i < 4; ++i)
#pragma unroll
        for (int j = 0; j < 4; ++j) acc[i][j] = (f32x4){0.f, 0.f, 0.f, 0.f};

    const size_t aoff = (size_t)(bm + wave * 16 + lrow) * 2048 + lkb + kbeg;
    const size_t boff = (size_t)(bn + wave * 16 + lrow) * 2048 + lkb + kbeg;
    bf16_t* lAh = &Ah[(wave * 16 + lrow) * GBK + lkb];
    bf16_t* lAl = &Al[(wave * 16 + lrow) * GBK + lkb];
    bf16_t* lBh = &Bh[(wave * 16 + lrow) * GBK + lkb];
    bf16_t* lBl = &Bl[(wave * 16 + lrow) * GBK + lkb];

    for (int k0 = 0; k0 < 512; k0 += GBK) {
        __syncthreads();
        async_copy16(Ahi + aoff + k0, lAh);
        async_copy16(Ahi + aoff + (size_t)64 * 2048 + k0, lAh + 64 * GBK);
        async_copy16(Alo + aoff + k0, lAl);
        async_copy16(Alo + aoff + (size_t)64 * 2048 + k0, lAl + 64 * GBK);
        async_copy16(Bhi + boff + k0, lBh);
        async_copy16(Bhi + boff + (size_t)64 * 2048 + k0, lBh + 64 * GBK);
        async_copy16(Blo + boff + k0, lBl);
        async_copy16(Blo + boff + (size_t)64 * 2048 + k0, lBl + 64 * GBK);
        __syncthreads();

        bf16x8 ah[4], al[4], bh[4], bl[4];
#pragma unroll
        for (int mt = 0; mt < 4; ++mt) {
            ah[mt] = *(const bf16x8*)&Ah[(wm + mt * 16 + l16) * GBK + quad * 8];
            al[mt] = *(const bf16x8*)&Al[(wm + mt * 16 + l16) * GBK + quad * 8];
        }
#pragma unroll
        for (int nt = 0; nt < 4; ++nt) {
            bh[nt] = *(const bf16x8*)&Bh[(wn + nt * 16 + l16) * GBK + quad * 8];
            bl[nt] = *(const bf16x8*)&Bl[(wn + nt * 16 + l16) * GBK + quad * 8];
        }
#pragma unroll
        for (int mt = 0; mt < 4; ++mt)
#pragma unroll
            for (int nt = 0; nt < 4; ++nt) {
                acc[mt][nt] = __builtin_amdgcn_mfma_f32_16x16x32_bf16(ah[mt], bh[nt], acc[mt][nt], 0, 0, 0);
                acc[mt][nt] = __builtin_amdgcn_mfma_f32_16x16x32_bf16(ah[mt], bl[nt], acc[mt][nt], 0, 0, 0);
                acc[mt][nt] = __builtin_amdgcn_mfma_f32_16x16x32_bf16(al[mt], bh[nt], acc[mt][nt], 0, 0, 0);
            }
    }

    float* cp = Cpart + (size_t)ks * 2048 * 512;
#pragma unroll
    for (int mt = 0; mt < 4; ++mt)
#pragma unroll
        for (int r = 0; r < 4; ++r) {
            int row = bm + wm + mt * 16 + quad * 4 + r;
            float* crow = cp + (size_t)row * 512 + bn + wn;
#pragma unroll
            for (int nt = 0; nt < 4; ++nt)
                crow[nt * 16 + l16] = acc[mt][nt][r];
        }
}

__device__ __forceinline__ float gelu_exact(float v) {
    return 0.5f * v * (1.0f + erff(v * 0.70710678118654752f));
}

// ---------------------------------------------------------------------------
// Fused: reduce 4 split-K partials + gelu + dot(w2) + sigmoid -> gate[t].
// ---------------------------------------------------------------------------
__global__ __launch_bounds__(64)
void info_gate_kernel(const float* __restrict__ Cpart, const float* __restrict__ w2,
                      float* __restrict__ gate) {
    const int t = blockIdx.x;
    const int lane = threadIdx.x;
    const float* p0 = Cpart + (size_t)t * 512;
    float s = 0.f;
#pragma unroll
    for (int i = lane; i < 512; i += 64) {
        float v = ((p0[i] + p0[i + 1048576]) + p0[i + 2097152]) + p0[i + 3145728];
        s += gelu_exact(v) * w2[i];
    }
#pragma unroll
    for (int off = 32; off > 0; off >>= 1) s += __shfl_down(s, off);
    if (lane == 0) {
        float sig = 1.f / (1.f + expf(-s));
        gate[t] = (sig > 0.75f) ? 1.f : 0.f;
    }
}

// ---------------------------------------------------------------------------
// MFMA kvr: Q/K/V all bf16 overlays (q roped unscaled @0).
// ---------------------------------------------------------------------------
#define KV_LD 136

__global__ __launch_bounds__(256)
void kvr_mfma_kernel(const bf16_t* __restrict__ qkv_bf,
                     const float* __restrict__ pk, const float* __restrict__ pv,
                     float* __restrict__ kr, float* __restrict__ vr,
                     bf16_t* __restrict__ qr) {
    __shared__ bf16_t Kt[64 * KV_LD];
    __shared__ bf16_t Vt[64 * KV_LD];
    __shared__ bf16_t Qt[64 * KV_LD];
    __shared__ bf16_t Pk[64 * KV_LD];
    __shared__ bf16_t Pv[64 * KV_LD];

    const int h = blockIdx.y;
    const int s0 = blockIdx.x * 64;
    const int tid = threadIdx.x;
    const int wave = tid >> 6, lane = tid & 63;
    const int quad = lane >> 4, l16 = lane & 15;

#pragma unroll
    for (int i = 0; i < 4; ++i) {
        int gid = i * 256 + tid;
        int row = gid >> 4, ch = (gid & 15) << 3;
        const bf16_t* rb = qkv_bf + (size_t)(s0 + row) * ROW_BF + h * HD + ch;
        *(bf16x8*)&Qt[row * KV_LD + ch] = *(const bf16x8*)(rb);
        *(bf16x8*)&Kt[row * KV_LD + ch] = *(const bf16x8*)(rb + KB_OFF);
        *(bf16x8*)&Vt[row * KV_LD + ch] = *(const bf16x8*)(rb + VB_OFF);
    }
#pragma unroll
    for (int i = 0; i < 8; ++i) {
        int gid = i * 256 + tid;
        int row = gid >> 5, c = (gid & 31) << 2;
        float4 wk = *(const float4*)(pk + (size_t)row * HD + c);
        float4 wv = *(const float4*)(pv + (size_t)row * HD + c);
        bf16x4 qk4, qv4;
        qk4[0] = (bf16_t)wk.x; qk4[1] = (bf16_t)wk.y; qk4[2] = (bf16_t)wk.z; qk4[3] = (bf16_t)wk.w;
        qv4[0] = (bf16_t)wv.x; qv4[1] = (bf16_t)wv.y; qv4[2] = (bf16_t)wv.z; qv4[3] = (bf16_t)wv.w;
        *(bf16x4*)&Pk[row * KV_LD + c] = qk4;
        *(bf16x4*)&Pv[row * KV_LD + c] = qv4;
    }
    __syncthreads();

    f32x4 ak[4], av[4], aq[4];
#pragma unroll
    for (int nt = 0; nt < 4; ++nt) {
        ak[nt] = (f32x4){0.f, 0.f, 0.f, 0.f};
        av[nt] = (f32x4){0.f, 0.f, 0.f, 0.f};
        aq[nt] = (f32x4){0.f, 0.f, 0.f, 0.f};
    }

#pragma unroll
    for (int ks = 0; ks < 4; ++ks) {
        const int ao = (wave * 16 + l16) * KV_LD + ks * 32 + quad * 8;
        bf16x8 a_k = *(const bf16x8*)&Kt[ao];
        bf16x8 a_v = *(const bf16x8*)&Vt[ao];
        bf16x8 a_q = *(const bf16x8*)&Qt[ao];
#pragma unroll
        for (int nt = 0; nt < 4; ++nt) {
            const int bo = (nt * 16 + l16) * KV_LD + ks * 32 + quad * 8;
            bf16x8 bk = *(const bf16x8*)&Pk[bo];
            bf16x8 bv = *(const bf16x8*)&Pv[bo];
            ak[nt] = __builtin_amdgcn_mfma_f32_16x16x32_bf16(a_k, bk, ak[nt], 0, 0, 0);
            av[nt] = __builtin_amdgcn_mfma_f32_16x16x32_bf16(a_v, bv, av[nt], 0, 0, 0);
            aq[nt] = __builtin_amdgcn_mfma_f32_16x16x32_bf16(a_q, bk, aq[nt], 0, 0, 0);
        }
    }

#pragma unroll
    for (int nt = 0; nt < 4; ++nt)
#pragma unroll
        for (int r = 0; r < 4; ++r) {
            int s = s0 + wave * 16 + quad * 4 + r;
            size_t idx = ((size_t)h * T_LEN + s) * RANK + nt * 16 + l16;
            kr[idx] = ak[nt][r];
            vr[idx] = av[nt][r];
            qr[idx] = (bf16_t)aq[nt][r];
        }
}

// ---------------------------------------------------------------------------
// MFMA bf16 flash local attention v3: all operands async-staged bf16.
// Q (roped, unscaled) from overlay @0; K from @KB_OFF; V^T from vt[h][d][t].
// All LDS tiles linear + chunk-swizzled (p = c ^ (row&7) on src and read).
// Scores scaled by SCALE post-MFMA. Mask only on kt==0 / kt==8.
// ---------------------------------------------------------------------------
#define QTI 64
#define KTI 64
#define PS_LD 72

__global__ __launch_bounds__(256)
void local_attn_kernel(const bf16_t* __restrict__ qkv_bf, const bf16_t* __restrict__ vt,
                       bf16_t* __restrict__ cxb) {
    __shared__ __align__(16) bf16_t Qs[QTI * 128];
    __shared__ __align__(16) bf16_t Ks[KTI * 128];
    __shared__ __align__(16) bf16_t Vts[128 * KTI];
    __shared__ bf16_t Ps[4][16 * PS_LD];

    const int h = blockIdx.y;
    const int t0 = blockIdx.x * QTI;
    const int tid = threadIdx.x;
    const int wave = tid >> 6, lane = tid & 63;
    const int quad = lane >> 4, l16 = lane & 15;
    const int xsw = l16 & 7;

    const bf16_t* vth = vt + (size_t)h * 128 * 2048;

    // stage Q once (async, swizzled): 1024 chunks
#pragma unroll
    for (int i = 0; i < 4; ++i) {
        int c = i * 256 + tid;
        int row = c >> 4, pc = c & 15;
        int lc = pc ^ (row & 7);
        async_copy16(qkv_bf + (size_t)(t0 + row) * ROW_BF + h * HD + lc * 8, &Qs[c * 8]);
    }

    f32x4 o[8];
#pragma unroll
    for (int d8 = 0; d8 < 8; ++d8) o[d8] = (f32x4){0.f, 0.f, 0.f, 0.f};
    float m_i[4] = {-1e30f, -1e30f, -1e30f, -1e30f};
    float l_i[4] = {0.f, 0.f, 0.f, 0.f};

    __syncthreads();

    for (int kt = 0; kt < 9; ++kt) {
        const int sbase = t0 - 512 + kt * KTI;
        if (sbase < 0) continue;
        __syncthreads();
        // K tile [64 s][128 d], async swizzled
#pragma unroll
        for (int i = 0; i < 4; ++i) {
            int c = i * 256 + tid;
            int row = c >> 4, pc = c & 15;
            int lc = pc ^ (row & 7);
            async_copy16(qkv_bf + (size_t)(sbase + row) * ROW_BF + KB_OFF + h * HD + lc * 8,
                         &Ks[c * 8]);
        }
        // V^T tile [128 d][64 s], async swizzled
#pragma unroll
        for (int i = 0; i < 4; ++i) {
            int c = i * 256 + tid;
            int row = c >> 3, pc = c & 7;
            int lc = pc ^ (row & 7);
            async_copy16(vth + (size_t)row * 2048 + sbase + lc * 8, &Vts[c * 8]);
        }
        __syncthreads();

        f32x4 sacc[4];
#pragma unroll
        for (int nt = 0; nt < 4; ++nt) sacc[nt] = (f32x4){0.f, 0.f, 0.f, 0.f};
#pragma unroll
        for (int ks = 0; ks < 4; ++ks) {
            bf16x8 a = *(const bf16x8*)&Qs[(wave * 16 + l16) * 128 + (((ks * 4 + quad) ^ xsw)) * 8];
#pragma unroll
            for (int nt = 0; nt < 4; ++nt) {
                bf16x8 b = *(const bf16x8*)&Ks[(nt * 16 + l16) * 128 + (((ks * 4 + quad) ^ xsw)) * 8];
                sacc[nt] = __builtin_amdgcn_mfma_f32_16x16x32_bf16(a, b, sacc[nt], 0, 0, 0);
            }
        }

#pragma unroll
        for (int nt = 0; nt < 4; ++nt)
#pragma unroll
            for (int r = 0; r < 4; ++r) sacc[nt][r] *= SCALE;

        if (kt == 0 || kt == 8) {   // uniform branch; interior tiles need no mask
#pragma unroll
            for (int nt = 0; nt < 4; ++nt) {
                int s_g = sbase + nt * 16 + l16;
#pragma unroll
                for (int r = 0; r < 4; ++r) {
                    int t_g = t0 + wave * 16 + quad * 4 + r;
                    bool valid = (s_g <= t_g) && (s_g + W_LOCAL > t_g);
                    if (!valid) sacc[nt][r] = -1e30f;
                }
            }
        }

#pragma unroll
        for (int r = 0; r < 4; ++r) {
            float mx = fmaxf(fmaxf(sacc[0][r], sacc[1][r]), fmaxf(sacc[2][r], sacc[3][r]));
            mx = fmaxf(mx, __shfl_xor(mx, 1));
            mx = fmaxf(mx, __shfl_xor(mx, 2));
            mx = fmaxf(mx, __shfl_xor(mx, 4));
            mx = fmaxf(mx, __shfl_xor(mx, 8));
            float mnew = fmaxf(m_i[r], mx);
            float alpha = __expf(m_i[r] - mnew);
            m_i[r] = mnew;
            float rs = 0.f;
#pragma unroll
            for (int nt = 0; nt < 4; ++nt) {
                float p = __expf(sacc[nt][r] - mnew);
                sacc[nt][r] = p;
                rs += p;
            }
            rs += __shfl_xor(rs, 1);
            rs += __shfl_xor(rs, 2);
            rs += __shfl_xor(rs, 4);
            rs += __shfl_xor(rs, 8);
            l_i[r] = l_i[r] * alpha + rs;
#pragma unroll
            for (int d8 = 0; d8 < 8; ++d8) o[d8][r] *= alpha;
        }

#pragma unroll
        for (int r = 0; r < 4; ++r)
#pragma unroll
            for (int nt = 0; nt < 4; ++nt)
                Ps[wave][(quad * 4 + r) * PS_LD + nt * 16 + l16] = (bf16_t)sacc[nt][r];

#pragma unroll
        for (int ks2 = 0; ks2 < 2; ++ks2) {
            bf16x8 a = *(const bf16x8*)&Ps[wave][l16 * PS_LD + ks2 * 32 + quad * 8];
#pragma unroll
            for (int d8 = 0; d8 < 8; ++d8) {
                int rw = d8 * 16 + l16;
                bf16x8 b = *(const bf16x8*)&Vts[rw * 64 + (((ks2 * 4 + quad) ^ xsw)) * 8];
                o[d8] = __builtin_amdgcn_mfma_f32_16x16x32_bf16(a, b, o[d8], 0, 0, 0);
            }
        }
    }

#pragma unroll
    for (int r = 0; r < 4; ++r) {
        float inv = 1.0f / l_i[r];
        size_t rowoff = (size_t)(t0 + wave * 16 + quad * 4 + r) * 2048 + h * HD;
#pragma unroll
        for (int d8 = 0; d8 < 8; ++d8)
            cxb[rowoff + d8 * 16 + l16] = (bf16_t)(o[d8][r] * inv);
    }
}

// ---------------------------------------------------------------------------
// Gated global low-rank branch (early-exit when gate==0); bf16 RMW into cxb
// ---------------------------------------------------------------------------
__device__ __forceinline__ float block_reduce_max512(float v, float* red, int tid) {
    red[tid] = v; __syncthreads();
    for (int s = 256; s > 0; s >>= 1) {
        if (tid < s) red[tid] = fmaxf(red[tid], red[tid + s]);
        __syncthreads();
    }
    float r = red[0]; __syncthreads();
    return r;
}
__device__ __forceinline__ float block_reduce_sum512(float v, float* red, int tid) {
    red[tid] = v; __syncthreads();
    for (int s = 256; s > 0; s >>= 1) {
        if (tid < s) red[tid] = red[tid] + red[tid + s];
        __syncthreads();
    }
    float r = red[0]; __syncthreads();
    return r;
}

__global__ __launch_bounds__(512)
void global_attn_kernel(bf16_t* __restrict__ cxb, const float* __restrict__ kr,
                        const float* __restrict__ vr, const bf16_t* __restrict__ qr,
                        const float* __restrict__ uo, const float* __restrict__ gate) {
    const int t = blockIdx.x, h = blockIdx.y;
    if (gate[t] <= 0.5f) return;

    __shared__ float qrs[64];
    __shared__ float red[512];
    __shared__ float cgr[64];
    __shared__ float sg[2048];
    const int tid = threadIdx.x;

    if (tid < 64) qrs[tid] = (float)qr[((size_t)h * T_LEN + t) * RANK + tid];
    __syncthreads();

    const float* krh = kr + (size_t)h * T_LEN * RANK;
    const float* vrh = vr + (size_t)h * T_LEN * RANK;
    float lmax = -INFINITY;
    for (int s = tid; s < T_LEN; s += 512) {
        const float* krr = krh + (size_t)s * RANK;
        float acc = 0.f;
#pragma unroll
        for (int r = 0; r < RANK; r += 4) {
            float4 k4 = *(const float4*)(krr + r);
            acc += qrs[r] * k4.x + qrs[r + 1] * k4.y + qrs[r + 2] * k4.z + qrs[r + 3] * k4.w;
        }
        float sc = acc * SCALE_G;
        sg[s] = sc;
        lmax = fmaxf(lmax, sc);
    }
    float gmx = block_reduce_max512(lmax, red, tid);
    float lsum = 0.f;
    for (int s = tid; s < T_LEN; s += 512) {
        float pp = expf(sg[s] - gmx);
        sg[s] = pp;
        lsum += pp;
    }
    float gsum = block_reduce_sum512(lsum, red, tid);

    {
        const int r = tid & 63, part = tid >> 6;
        float pacc = 0.f;
        for (int s = part; s < T_LEN; s += 8) pacc += sg[s] * vrh[(size_t)s * RANK + r];
        red[tid] = pacc;
        __syncthreads();
        if (tid < 64) {
            float c = 0.f;
#pragma unroll
            for (int pp = 0; pp < 8; ++pp) c += red[pp * 64 + tid];
            cgr[tid] = c / gsum;
        }
        __syncthreads();
    }

    if (tid < 128) {
        float cg = 0.f;
#pragma unroll
        for (int r = 0; r < RANK; ++r) cg += cgr[r] * uo[tid * RANK + r];
        size_t off = (size_t)t * 2048 + h * HD + tid;
        cxb[off] = (bf16_t)((float)cxb[off] + cg);
    }
}

// ---------------------------------------------------------------------------
extern "C" void kernel_launch(void* const* d_in, const int* in_sizes, int n_in,
                              void* d_out, int out_size, void* d_ws, size_t ws_size,
                              hipStream_t stream) {
    const float* x     = (const float*)d_in[0];
    const float* w_qkv = (const float*)d_in[1];
    const float* w_o   = (const float*)d_in[2];
    const float* pk    = (const float*)d_in[3];
    const float* pv    = (const float*)d_in[4];
    const float* uo    = (const float*)d_in[5];
    const float* w1    = (const float*)d_in[6];
    const float* w2    = (const float*)d_in[7];
    float* out = (float*)d_out;

    // Workspace layout (floats), lifetime-aliased (~84 MB):
    float* ws = (float*)d_ws;
    float* qkv   = ws;                        // 12,582,912 f: pre-GEMM info scratch;
                                              //  post-GEMM rows: q bf16 | K bf16 | wo bf16 | V bf16
    float* hinfo = qkv + (size_t)12582912;    // 1,048,576 f: rope tab, later qr bf16
    float* gatep = hinfo + (size_t)1048576;   // 2048 f
    bf16_t* xb   = (bf16_t*)(gatep + 2048);   // x_hi bf16 (later ctx bf16)
    float* wqbf  = gatep + 2048 + 2097152;    // 6,291,456 f region:
    bf16_t* wqb  = (bf16_t*)wqbf;             //   w_qkv bf16 (entire region)
    float* krp   = wqbf;                      //   later: kr
    float* vrp   = wqbf + (size_t)2097152;    //   later: vr
    float* tabp  = hinfo;                     // rope tables (dead before qr)
    bf16_t* qrp  = (bf16_t*)hinfo;            // qr bf16 (written by kvr)
    bf16_t* cxb  = xb;                        // ctx bf16
    bf16_t* qkvb = (bf16_t*)qkv;              // bf16 overlay view of qkv rows
    bf16_t* wob  = qkvb + WO_OFF;             // w_o bf16, row stride ROW_BF
    bf16_t* vtp  = (bf16_t*)d_out;            // V^T [h][128][2048] scratch in d_out
                                              // (dead before gemm_ctx_wo writes out)
    // Info-MLP scratch inside the pre-GEMM qkv region:
    float* ipart  = qkv;                          // 4x2048x512 f
    bf16_t* xlo   = (bf16_t*)(qkv + 4194304);
    bf16_t* w1hi  = (bf16_t*)(qkv + 6291456);
    bf16_t* w1lo  = (bf16_t*)(qkv + 6815744);

    // 1) merged prep: x/w1 split-bf16, w_qkv->bf16, rope tables
    prep_kernel<<<9216, 256, 0, stream>>>(x, xb, xlo, w1, w1hi, w1lo, w_qkv, wqb, tabp);
    // 2) info MLP (3x bf16 MFMA split-K) -> fused reduce+gelu+gate
    info_gemm_mfma<<<dim3(4, 16, 4), 256, 0, stream>>>(xb, xlo, w1hi, w1lo, ipart);
    info_gate_kernel<<<T_LEN, 64, 0, stream>>>(ipart, w2, gatep);
    // 3) qkv GEMM (128x128 v4) + fused RoPE (q/k bf16 overlays) + V row-major
    //    overlay + V^T (vtp) + piggy-backed w_o->bf16 (blocks [768,2816))
    gemm_qkv_rope<<<2816, 256, 0, stream>>>(xb, wqb, qkvb, vtp, tabp, w_o);
    // 4) k_r, v_r, q_r via MFMA (kr/vr overwrite dead wqb; qr over dead tab)
    kvr_mfma_kernel<<<dim3(T_LEN / 64, NH), 256, 0, stream>>>(qkvb, pk, pv, krp, vrp, qrp);
    // 5) flash local attention (async-staged Q/K/V^T) -> ctx bf16 (cxb)
    local_attn_kernel<<<dim3(T_LEN / QTI, NH), 256, 0, stream>>>(qkvb, vtp, cxb);
    // 6) gated global branch (bf16 RMW into cxb)
    global_attn_kernel<<<dim3(T_LEN, NH), 512, 0, stream>>>(cxb, krp, vrp, qrp, uo, gatep);
    // 7) out = ctx @ w_o^T  (v4 pipelined, B = wob overlay strided ROW_BF)
    gemm_ctx_wo<<<256, 256, 0, stream>>>(cxb, wob, out);
}

// Round 7
// 293.964 us; speedup vs baseline: 1.3465x; 1.0467x over previous
//
#include <hip/hip_runtime.h>
#include <hip/hip_bf16.h>
#include <math.h>

// Problem constants
#define T_LEN 2048
#define C_DIM 2048
#define NH 16
#define HD 128
#define RANK 64
#define W_LOCAL 512
#define QKV_LD 6144
#define ROW_BF 12288          // qkv row stride in bf16 elems
#define KB_OFF 4096           // bf16-elem offset of packed K overlay within row
#define VB_OFF 8192           // bf16-elem offset of packed V overlay within row
#define WO_OFF 6144           // bf16-elem offset of packed w_o row within qkv row
#define SCALE 0.08838834764831845f    // 1/sqrt(128)
#define SCALE_G 0.17677669529663687f  // scale * 128/64
#define LOG1E4_OVER_64 0.14391156831212787f

typedef __bf16 bf16_t;
typedef __bf16 bf16x8 __attribute__((ext_vector_type(8)));
typedef __bf16 bf16x4 __attribute__((ext_vector_type(4)));
typedef float f32x4 __attribute__((ext_vector_type(4)));

// ---------------------------------------------------------------------------
// async 16B global -> LDS (gfx950). LDS dst must be wave-uniform base+lane*16.
// ---------------------------------------------------------------------------
__device__ __forceinline__ void async_copy16(const bf16_t* g, bf16_t* l) {
    __builtin_amdgcn_global_load_lds(
        (const __attribute__((address_space(1))) unsigned int*)g,
        (__attribute__((address_space(3))) unsigned int*)l, 16, 0, 0);
}

// ---------------------------------------------------------------------------
// Merged prep kernel (block-range dispatch):
//  [0,2048):    x -> xb bf16 (hi only; info MLP re-derives lo from fp32 x)
//  [2048,8192): w_qkv -> wqb bf16
//  [8192,8704): rope tables
// ---------------------------------------------------------------------------
__global__ __launch_bounds__(256)
void prep_kernel(const float* __restrict__ x, bf16_t* __restrict__ xb,
                 const float* __restrict__ w_qkv, bf16_t* __restrict__ wqb,
                 float* __restrict__ tab) {
    const int bid = blockIdx.x;
    const int tid = threadIdx.x;
    if (bid < 2048) {
        int idx = bid * 256 + tid;                   // 8 elems each
        const float* p = x + (size_t)idx * 8;
        float4 v0 = *(const float4*)p;
        float4 v1 = *(const float4*)(p + 4);
        bf16x8 o;
        o[0] = (bf16_t)v0.x; o[1] = (bf16_t)v0.y; o[2] = (bf16_t)v0.z; o[3] = (bf16_t)v0.w;
        o[4] = (bf16_t)v1.x; o[5] = (bf16_t)v1.y; o[6] = (bf16_t)v1.z; o[7] = (bf16_t)v1.w;
        *(bf16x8*)(xb + (size_t)idx * 8) = o;
    } else if (bid < 8192) {
        // w_qkv fp32 -> bf16 (6144x2048)
        int idx = (bid - 2048) * 256 + tid;          // 8 elems each
        const float* p = w_qkv + (size_t)idx * 8;
        float4 v0 = *(const float4*)p;
        float4 v1 = *(const float4*)(p + 4);
        bf16x8 o;
        o[0] = (bf16_t)v0.x; o[1] = (bf16_t)v0.y; o[2] = (bf16_t)v0.z; o[3] = (bf16_t)v0.w;
        o[4] = (bf16_t)v1.x; o[5] = (bf16_t)v1.y; o[6] = (bf16_t)v1.z; o[7] = (bf16_t)v1.w;
        *(bf16x8*)(wqb + (size_t)idx * 8) = o;
    } else {
        // rope tables
        int idx = (bid - 8192) * 256 + tid;          // 2048*64
        int t = idx >> 6, j = idx & 63;
        float inv = expf(-(float)j * LOG1E4_OVER_64);
        float s, c;
        sincosf((float)t * inv, &s, &c);
        tab[t * 128 + j] = c;
        tab[t * 128 + 64 + j] = s;
    }
}

// ---------------------------------------------------------------------------
// MERGED dispatch: info-MLP GEMM + qkv GEMM v4 + piggy-backed w_o conversion.
//  Blocks [0,128):    info MLP split-bf16 GEMM (split-K=2), reg-staged from
//                     fp32 x/w1 (hi/lo derived in-register), partials->ipart
//                     (second half of d_out scratch).
//  Blocks [128,896):  qkv GEMM 128x128/BK=64/2 blocks/CU, counted vmcnt,
//                     both-sides XOR swizzle, fused RoPE epilogue, V overlay
//                     + V^T (vt, first half of d_out).
//  Blocks [896,2944): w_o row -> bf16 WO_OFF overlay.
// info and qkv blocks are fully independent (both read only prep outputs /
// kernel inputs, write disjoint buffers) -> they co-schedule and info fills
// qkv's idle CU slots instead of serializing as a separate dispatch.
// Shared-memory is a 64 KiB union (qkv 64K, info 41K, piggy none).
// ---------------------------------------------------------------------------
#define NTK 32      // 2048 / 64
#define ILD 40      // info LDS leading dim (padded: 128x40 bf16 per buffer)

#define STG_A(bb, ktile) do {                                                  \
    _Pragma("unroll")                                                          \
    for (int c_ = 0; c_ < 4; ++c_)                                             \
        async_copy16(gA + (size_t)(c_ * 32) * 2048 + (ktile) * 64,             \
                     &lds[bb][0][(c_ * 32 + rS) * 64 + dS]);                   \
} while (0)

#define STG_B(bb, ktile) do {                                                  \
    _Pragma("unroll")                                                          \
    for (int c_ = 0; c_ < 4; ++c_)                                             \
        async_copy16(gB + (size_t)(c_ * 32) * 2048 + (ktile) * 64,             \
                     &lds[bb][1][(c_ * 32 + rS) * 64 + dS]);                   \
} while (0)

#define RD_A(bb, m, k) (*(const bf16x8*)&lds[bb][0][(wr * 64 + (m) * 16 + l16) * 64 + (((k) * 4 + quad) ^ xsw) * 8])
#define RD_B(bb, n, k) (*(const bf16x8*)&lds[bb][1][(wc * 64 + (n) * 16 + l16) * 64 + (((k) * 4 + quad) ^ xsw) * 8])

__global__ __launch_bounds__(256, 2)
void gemm_qkv_rope(const bf16_t* __restrict__ A, const bf16_t* __restrict__ B,
                   bf16_t* __restrict__ qkv_bf, bf16_t* __restrict__ vt,
                   const float* __restrict__ tab, const float* __restrict__ w_o,
                   const float* __restrict__ x, const float* __restrict__ w1,
                   float* __restrict__ ipart) {
    __shared__ __align__(16) unsigned char smem[65536];
    const int bid = blockIdx.x;
    const int tid = threadIdx.x;

    if (bid < 128) {
        // ---------------- info MLP block (split-bf16, 3x MFMA) ----------------
        bf16_t* Ah = (bf16_t*)smem;            // [128][ILD]
        bf16_t* Al = Ah + 128 * ILD;
        bf16_t* Bh = Al + 128 * ILD;
        bf16_t* Bl = Bh + 128 * ILD;
        const int bn = bid & 3, bm = (bid >> 2) & 15, ks = bid >> 6;
        const int wave = tid >> 6, lane = tid & 63;
        const int quad = lane >> 4, l16 = lane & 15;
        const int wm = (wave >> 1) * 64, wn = (wave & 1) * 64;
        const int lrow = lane >> 2;
        const int lkb = (lane & 3) * 8;
        const int kbeg = ks * 1024;

        f32x4 acc[4][4];
#pragma unroll
        for (int i = 0; i < 4; ++i)
#pragma unroll
            for (int j = 0; j < 4; ++j) acc[i][j] = (f32x4){0.f, 0.f, 0.f, 0.f};

        const float* gx = x + (size_t)(bm * 128 + wave * 16 + lrow) * 2048 + kbeg + lkb;
        const float* gw = w1 + (size_t)(bn * 128 + wave * 16 + lrow) * 2048 + kbeg + lkb;
        const int wrow = (wave * 16 + lrow) * ILD + lkb;

        for (int k0 = 0; k0 < 1024; k0 += 32) {
            __syncthreads();
#pragma unroll
            for (int hr = 0; hr < 2; ++hr) {
                const float* px = gx + (size_t)hr * 64 * 2048 + k0;
                float4 a0 = *(const float4*)px, a1 = *(const float4*)(px + 4);
                float av[8] = {a0.x, a0.y, a0.z, a0.w, a1.x, a1.y, a1.z, a1.w};
                bf16x8 h, l;
#pragma unroll
                for (int i = 0; i < 8; ++i) {
                    bf16_t hb = (bf16_t)av[i];
                    h[i] = hb; l[i] = (bf16_t)(av[i] - (float)hb);
                }
                *(bf16x8*)&Ah[wrow + hr * 64 * ILD] = h;
                *(bf16x8*)&Al[wrow + hr * 64 * ILD] = l;

                const float* pw = gw + (size_t)hr * 64 * 2048 + k0;
                float4 b0 = *(const float4*)pw, b1 = *(const float4*)(pw + 4);
                float bv[8] = {b0.x, b0.y, b0.z, b0.w, b1.x, b1.y, b1.z, b1.w};
                bf16x8 hb2, lb2;
#pragma unroll
                for (int i = 0; i < 8; ++i) {
                    bf16_t hh = (bf16_t)bv[i];
                    hb2[i] = hh; lb2[i] = (bf16_t)(bv[i] - (float)hh);
                }
                *(bf16x8*)&Bh[wrow + hr * 64 * ILD] = hb2;
                *(bf16x8*)&Bl[wrow + hr * 64 * ILD] = lb2;
            }
            __syncthreads();

            bf16x8 ah[4], al[4], bh[4], bl[4];
#pragma unroll
            for (int mt = 0; mt < 4; ++mt) {
                ah[mt] = *(const bf16x8*)&Ah[(wm + mt * 16 + l16) * ILD + quad * 8];
                al[mt] = *(const bf16x8*)&Al[(wm + mt * 16 + l16) * ILD + quad * 8];
            }
#pragma unroll
            for (int nt = 0; nt < 4; ++nt) {
                bh[nt] = *(const bf16x8*)&Bh[(wn + nt * 16 + l16) * ILD + quad * 8];
                bl[nt] = *(const bf16x8*)&Bl[(wn + nt * 16 + l16) * ILD + quad * 8];
            }
#pragma unroll
            for (int mt = 0; mt < 4; ++mt)
#pragma unroll
                for (int nt = 0; nt < 4; ++nt) {
                    acc[mt][nt] = __builtin_amdgcn_mfma_f32_16x16x32_bf16(ah[mt], bh[nt], acc[mt][nt], 0, 0, 0);
                    acc[mt][nt] = __builtin_amdgcn_mfma_f32_16x16x32_bf16(ah[mt], bl[nt], acc[mt][nt], 0, 0, 0);
                    acc[mt][nt] = __builtin_amdgcn_mfma_f32_16x16x32_bf16(al[mt], bh[nt], acc[mt][nt], 0, 0, 0);
                }
        }

        float* cp = ipart + (size_t)ks * 2048 * 512;
#pragma unroll
        for (int mt = 0; mt < 4; ++mt)
#pragma unroll
            for (int r = 0; r < 4; ++r) {
                int row = bm * 128 + wm + mt * 16 + quad * 4 + r;
                float* crow = cp + (size_t)row * 512 + bn * 128 + wn;
#pragma unroll
                for (int nt = 0; nt < 4; ++nt)
                    crow[nt * 16 + l16] = acc[mt][nt][r];
            }
        return;
    }

    if (bid >= 896) {
        // ---------------- w_o conversion: one row per block ----------------
        int row = bid - 896;
        int c = tid * 8;
        const float* p = w_o + (size_t)row * 2048 + c;
        float4 v0 = *(const float4*)p;
        float4 v1 = *(const float4*)(p + 4);
        bf16x8 o;
        o[0] = (bf16_t)v0.x; o[1] = (bf16_t)v0.y; o[2] = (bf16_t)v0.z; o[3] = (bf16_t)v0.w;
        o[4] = (bf16_t)v1.x; o[5] = (bf16_t)v1.y; o[6] = (bf16_t)v1.z; o[7] = (bf16_t)v1.w;
        *(bf16x8*)(qkv_bf + (size_t)row * ROW_BF + WO_OFF + c) = o;
        return;
    }

    // ---------------- qkv GEMM v4 block ----------------
    typedef bf16_t ldsbuf_t[2][128 * 64];
    ldsbuf_t* lds = (ldsbuf_t*)smem;           // [2][2][8192], 64 KiB

    const int gid = bid - 128;                 // 0..767
    const int xcd = gid & 7, idx = gid >> 3;   // 96 blocks per XCD, contiguous bn stripe
    const int bn_ = xcd * 6 + (idx >> 4);      // 0..47
    const int bm_ = idx & 15;                  // 0..15
    const int wave = tid >> 6, lane = tid & 63;
    const int quad = lane >> 4, l16 = lane & 15;
    const int wr = wave >> 1, wc = wave & 1;   // 2x2 wave grid, wave tile 64x64
    const int xsw = l16 & 7;

    // staging geometry: thread covers (row rS + 32*c, phys chunk tid&7);
    // global source chunk pre-swizzled: phys chunk p holds logical p^(row&7)
    const int rS = tid >> 3;                   // 0..31
    const int cS = ((tid & 7) ^ (rS & 7)) * 8; // global col (bf16)
    const int dS = (tid & 7) * 8;              // linear LDS chunk
    const bf16_t* gA = A + (size_t)(bm_ * 128 + rS) * 2048 + cS;
    const bf16_t* gB = B + (size_t)(bn_ * 128 + rS) * 2048 + cS;

    f32x4 acc[4][4];
#pragma unroll
    for (int i = 0; i < 4; ++i)
#pragma unroll
        for (int j = 0; j < 4; ++j) acc[i][j] = (f32x4){0.f, 0.f, 0.f, 0.f};

    // Prologue: stage tiles 0 and 1; wait for tile 0, leave tile 1 in flight.
    STG_A(0, 0); STG_B(0, 0);
    STG_A(1, 1); STG_B(1, 1);
    asm volatile("s_waitcnt vmcnt(8)" ::: "memory");
    __builtin_amdgcn_s_barrier();

    for (int kt = 0; kt < NTK; ++kt) {
        const int b = kt & 1;
        bf16x8 af[4][2], bfr[4][2];
#pragma unroll
        for (int m = 0; m < 4; ++m) { af[m][0] = RD_A(b, m, 0); af[m][1] = RD_A(b, m, 1); }
#pragma unroll
        for (int n = 0; n < 4; ++n) { bfr[n][0] = RD_B(b, n, 0); bfr[n][1] = RD_B(b, n, 1); }
        asm volatile("s_waitcnt lgkmcnt(0)" ::: "memory");
        __builtin_amdgcn_s_barrier();          // all waves done reading buf b

        __builtin_amdgcn_s_setprio(1);
#pragma unroll
        for (int m = 0; m < 4; ++m)
#pragma unroll
            for (int n = 0; n < 4; ++n)
                acc[m][n] = __builtin_amdgcn_mfma_f32_16x16x32_bf16(af[m][0], bfr[n][0], acc[m][n], 0, 0, 0);
        __builtin_amdgcn_s_setprio(0);
        if (kt + 2 < NTK) STG_A(b, kt + 2);    // buf b safe to overwrite now

        __builtin_amdgcn_s_setprio(1);
#pragma unroll
        for (int m = 0; m < 4; ++m)
#pragma unroll
            for (int n = 0; n < 4; ++n)
                acc[m][n] = __builtin_amdgcn_mfma_f32_16x16x32_bf16(af[m][1], bfr[n][1], acc[m][n], 0, 0, 0);
        __builtin_amdgcn_s_setprio(0);
        if (kt + 2 < NTK) STG_B(b, kt + 2);

        if (kt < NTK - 2) { asm volatile("s_waitcnt vmcnt(8)" ::: "memory"); }
        else              { asm volatile("s_waitcnt vmcnt(0)" ::: "memory"); }
        __builtin_amdgcn_s_barrier();
    }

    // ---- epilogue ----
    const int colbase = bn_ * 128 + wc * 64;
    const int region = (bn_ * 128) >> 11;      // 0=q, 1=k, 2=v (block-uniform)
    const int rowbase = bm_ * 128 + wr * 64;
    const bool odd = (l16 & 1);

    if (region == 2) {
        // (a) row-major V overlay (for kvr)
#pragma unroll
        for (int mt = 0; mt < 4; ++mt)
#pragma unroll
            for (int r = 0; r < 4; ++r) {
                int t = rowbase + mt * 16 + quad * 4 + r;
                bf16_t* brow = qkv_bf + (size_t)t * ROW_BF + VB_OFF + (colbase - 4096);
#pragma unroll
                for (int nt = 0; nt < 4; ++nt)
                    brow[nt * 16 + l16] = (bf16_t)acc[mt][nt][r];
            }
        // (b) transposed vt[h][d][t] via LDS transpose (tile = exactly one head)
        bf16_t* Tl = (bf16_t*)smem;            // [128][136] bf16, 34.8 KB
#pragma unroll
        for (int mt = 0; mt < 4; ++mt)
#pragma unroll
            for (int r = 0; r < 4; ++r) {
                int rloc = wr * 64 + mt * 16 + quad * 4 + r;
#pragma unroll
                for (int nt = 0; nt < 4; ++nt) {
                    int cloc = wc * 64 + nt * 16 + l16;
                    Tl[cloc * 136 + rloc] = (bf16_t)acc[mt][nt][r];
                }
            }
        __syncthreads();
        const int hh = bn_ - 32;               // head index
        const int d = tid >> 1, th = (tid & 1) * 64;
        bf16_t* dst = vt + ((size_t)(hh * 128 + d)) * 2048 + bm_ * 128 + th;
        const bf16_t* srcT = Tl + d * 136 + th;
#pragma unroll
        for (int j = 0; j < 8; ++j)
            *(bf16x8*)(dst + j * 8) = *(const bf16x8*)(srcT + j * 8);
    } else {
        // RoPE for q/k; store bf16 overlay (q @0, k @KB_OFF)
#pragma unroll
        for (int mt = 0; mt < 4; ++mt)
#pragma unroll
            for (int r = 0; r < 4; ++r) {
                int t = rowbase + mt * 16 + quad * 4 + r;
                const float* trow = tab + t * 128;
#pragma unroll
                for (int nt = 0; nt < 4; ++nt) {
                    float v = acc[mt][nt][r];
                    float vp = __shfl_xor(v, 1);    // pair column value
                    int col = colbase + nt * 16 + l16;
                    int j = col & 63;
                    float c = trow[j], s = trow[64 + j];
                    float y = odd ? (v * c + vp * s) : (v * c - vp * s);
                    qkv_bf[(size_t)t * ROW_BF + (region == 0 ? col : col + 2048)] = (bf16_t)y;
                }
            }
    }
}

// ---------------------------------------------------------------------------
// Final GEMM: out = ctx @ w_o^T, v4 pipelined structure. A = cxb (bf16,
// lda 2048); B = wob (bf16 overlay inside qkv rows, ldb ROW_BF). Grid 256
// (16x16), XCD-chunked. Same counted-vmcnt schedule + both-sides swizzle.
// ---------------------------------------------------------------------------
#define STG_A2(bb, ktile) do {                                                 \
    _Pragma("unroll")                                                          \
    for (int c_ = 0; c_ < 4; ++c_)                                             \
        async_copy16(gA + (size_t)(c_ * 32) * 2048 + (ktile) * 64,             \
                     &lds[bb][0][(c_ * 32 + rS) * 64 + dS]);                   \
} while (0)

#define STG_B2(bb, ktile) do {                                                 \
    _Pragma("unroll")                                                          \
    for (int c_ = 0; c_ < 4; ++c_)                                             \
        async_copy16(gB + (size_t)(c_ * 32) * ROW_BF + (ktile) * 64,           \
                     &lds[bb][1][(c_ * 32 + rS) * 64 + dS]);                   \
} while (0)

__global__ __launch_bounds__(256, 2)
void gemm_ctx_wo(const bf16_t* __restrict__ A, const bf16_t* __restrict__ Bov,
                 float* __restrict__ C) {
    __shared__ __align__(16) bf16_t ldss[2][2][128 * 64];   // 64 KiB
    typedef bf16_t ldsbuf_t[2][128 * 64];
    ldsbuf_t* lds = (ldsbuf_t*)ldss;

    const int bid = blockIdx.x;                // 0..255
    const int xcd = bid & 7, idx = bid >> 3;   // 32 blocks per XCD
    const int bn_ = xcd * 2 + (idx >> 4);      // 0..15
    const int bm_ = idx & 15;                  // 0..15
    const int tid = threadIdx.x;
    const int wave = tid >> 6, lane = tid & 63;
    const int quad = lane >> 4, l16 = lane & 15;
    const int wr = wave >> 1, wc = wave & 1;
    const int xsw = l16 & 7;

    const int rS = tid >> 3;
    const int cS = ((tid & 7) ^ (rS & 7)) * 8;
    const int dS = (tid & 7) * 8;
    const bf16_t* gA = A + (size_t)(bm_ * 128 + rS) * 2048 + cS;
    const bf16_t* gB = Bov + (size_t)(bn_ * 128 + rS) * ROW_BF + cS;

    f32x4 acc[4][4];
#pragma unroll
    for (int i = 0; i < 4; ++i)
#pragma unroll
        for (int j = 0; j < 4; ++j) acc[i][j] = (f32x4){0.f, 0.f, 0.f, 0.f};

    STG_A2(0, 0); STG_B2(0, 0);
    STG_A2(1, 1); STG_B2(1, 1);
    asm volatile("s_waitcnt vmcnt(8)" ::: "memory");
    __builtin_amdgcn_s_barrier();

    for (int kt = 0; kt < NTK; ++kt) {
        const int b = kt & 1;
        bf16x8 af[4][2], bfr[4][2];
#pragma unroll
        for (int m = 0; m < 4; ++m) { af[m][0] = RD_A(b, m, 0); af[m][1] = RD_A(b, m, 1); }
#pragma unroll
        for (int n = 0; n < 4; ++n) { bfr[n][0] = RD_B(b, n, 0); bfr[n][1] = RD_B(b, n, 1); }
        asm volatile("s_waitcnt lgkmcnt(0)" ::: "memory");
        __builtin_amdgcn_s_barrier();

        __builtin_amdgcn_s_setprio(1);
#pragma unroll
        for (int m = 0; m < 4; ++m)
#pragma unroll
            for (int n = 0; n < 4; ++n)
                acc[m][n] = __builtin_amdgcn_mfma_f32_16x16x32_bf16(af[m][0], bfr[n][0], acc[m][n], 0, 0, 0);
        __builtin_amdgcn_s_setprio(0);
        if (kt + 2 < NTK) STG_A2(b, kt + 2);

        __builtin_amdgcn_s_setprio(1);
#pragma unroll
        for (int m = 0; m < 4; ++m)
#pragma unroll
            for (int n = 0; n < 4; ++n)
                acc[m][n] = __builtin_amdgcn_mfma_f32_16x16x32_bf16(af[m][1], bfr[n][1], acc[m][n], 0, 0, 0);
        __builtin_amdgcn_s_setprio(0);
        if (kt + 2 < NTK) STG_B2(b, kt + 2);

        if (kt < NTK - 2) { asm volatile("s_waitcnt vmcnt(8)" ::: "memory"); }
        else              { asm volatile("s_waitcnt vmcnt(0)" ::: "memory"); }
        __builtin_amdgcn_s_barrier();
    }

    const int colbase = bn_ * 128 + wc * 64;
    const int rowbase = bm_ * 128 + wr * 64;
#pragma unroll
    for (int mt = 0; mt < 4; ++mt)
#pragma unroll
        for (int r = 0; r < 4; ++r) {
            int row = rowbase + mt * 16 + quad * 4 + r;
            float* crow = C + (size_t)row * 2048 + colbase;
#pragma unroll
            for (int nt = 0; nt < 4; ++nt)
                crow[nt * 16 + l16] = acc[mt][nt][r];
        }
}

__device__ __forceinline__ float gelu_exact(float v) {
    return 0.5f * v * (1.0f + erff(v * 0.70710678118654752f));
}

// ---------------------------------------------------------------------------
// Fused: reduce 2 split-K partials + gelu + dot(w2) + sigmoid -> gate[t].
// ---------------------------------------------------------------------------
__global__ __launch_bounds__(64)
void info_gate_kernel(const float* __restrict__ Cpart, const float* __restrict__ w2,
                      float* __restrict__ gate) {
    const int t = blockIdx.x;
    const int lane = threadIdx.x;
    const float* p0 = Cpart + (size_t)t * 512;
    float s = 0.f;
#pragma unroll
    for (int i = lane; i < 512; i += 64) {
        float v = p0[i] + p0[i + 1048576];
        s += gelu_exact(v) * w2[i];
    }
#pragma unroll
    for (int off = 32; off > 0; off >>= 1) s += __shfl_down(s, off);
    if (lane == 0) {
        float sig = 1.f / (1.f + expf(-s));
        gate[t] = (sig > 0.75f) ? 1.f : 0.f;
    }
}

// ---------------------------------------------------------------------------
// MFMA kvr: Q/K/V all bf16 overlays (q roped unscaled @0).
// ---------------------------------------------------------------------------
#define KV_LD 136

__global__ __launch_bounds__(256)
void kvr_mfma_kernel(const bf16_t* __restrict__ qkv_bf,
                     const float* __restrict__ pk, const float* __restrict__ pv,
                     float* __restrict__ kr, float* __restrict__ vr,
                     bf16_t* __restrict__ qr) {
    __shared__ bf16_t Kt[64 * KV_LD];
    __shared__ bf16_t Vt[64 * KV_LD];
    __shared__ bf16_t Qt[64 * KV_LD];
    __shared__ bf16_t Pk[64 * KV_LD];
    __shared__ bf16_t Pv[64 * KV_LD];

    const int h = blockIdx.y;
    const int s0 = blockIdx.x * 64;
    const int tid = threadIdx.x;
    const int wave = tid >> 6, lane = tid & 63;
    const int quad = lane >> 4, l16 = lane & 15;

#pragma unroll
    for (int i = 0; i < 4; ++i) {
        int gid = i * 256 + tid;
        int row = gid >> 4, ch = (gid & 15) << 3;
        const bf16_t* rb = qkv_bf + (size_t)(s0 + row) * ROW_BF + h * HD + ch;
        *(bf16x8*)&Qt[row * KV_LD + ch] = *(const bf16x8*)(rb);
        *(bf16x8*)&Kt[row * KV_LD + ch] = *(const bf16x8*)(rb + KB_OFF);
        *(bf16x8*)&Vt[row * KV_LD + ch] = *(const bf16x8*)(rb + VB_OFF);
    }
#pragma unroll
    for (int i = 0; i < 8; ++i) {
        int gid = i * 256 + tid;
        int row = gid >> 5, c = (gid & 31) << 2;
        float4 wk = *(const float4*)(pk + (size_t)row * HD + c);
        float4 wv = *(const float4*)(pv + (size_t)row * HD + c);
        bf16x4 qk4, qv4;
        qk4[0] = (bf16_t)wk.x; qk4[1] = (bf16_t)wk.y; qk4[2] = (bf16_t)wk.z; qk4[3] = (bf16_t)wk.w;
        qv4[0] = (bf16_t)wv.x; qv4[1] = (bf16_t)wv.y; qv4[2] = (bf16_t)wv.z; qv4[3] = (bf16_t)wv.w;
        *(bf16x4*)&Pk[row * KV_LD + c] = qk4;
        *(bf16x4*)&Pv[row * KV_LD + c] = qv4;
    }
    __syncthreads();

    f32x4 ak[4], av[4], aq[4];
#pragma unroll
    for (int nt = 0; nt < 4; ++nt) {
        ak[nt] = (f32x4){0.f, 0.f, 0.f, 0.f};
        av[nt] = (f32x4){0.f, 0.f, 0.f, 0.f};
        aq[nt] = (f32x4){0.f, 0.f, 0.f, 0.f};
    }

#pragma unroll
    for (int ks = 0; ks < 4; ++ks) {
        const int ao = (wave * 16 + l16) * KV_LD + ks * 32 + quad * 8;
        bf16x8 a_k = *(const bf16x8*)&Kt[ao];
        bf16x8 a_v = *(const bf16x8*)&Vt[ao];
        bf16x8 a_q = *(const bf16x8*)&Qt[ao];
#pragma unroll
        for (int nt = 0; nt < 4; ++nt) {
            const int bo = (nt * 16 + l16) * KV_LD + ks * 32 + quad * 8;
            bf16x8 bk = *(const bf16x8*)&Pk[bo];
            bf16x8 bv = *(const bf16x8*)&Pv[bo];
            ak[nt] = __builtin_amdgcn_mfma_f32_16x16x32_bf16(a_k, bk, ak[nt], 0, 0, 0);
            av[nt] = __builtin_amdgcn_mfma_f32_16x16x32_bf16(a_v, bv, av[nt], 0, 0, 0);
            aq[nt] = __builtin_amdgcn_mfma_f32_16x16x32_bf16(a_q, bk, aq[nt], 0, 0, 0);
        }
    }

#pragma unroll
    for (int nt = 0; nt < 4; ++nt)
#pragma unroll
        for (int r = 0; r < 4; ++r) {
            int s = s0 + wave * 16 + quad * 4 + r;
            size_t idx = ((size_t)h * T_LEN + s) * RANK + nt * 16 + l16;
            kr[idx] = ak[nt][r];
            vr[idx] = av[nt][r];
            qr[idx] = (bf16_t)aq[nt][r];
        }
}

// ---------------------------------------------------------------------------
// MFMA bf16 flash local attention v3: all operands async-staged bf16.
// Q (roped, unscaled) from overlay @0; K from @KB_OFF; V^T from vt[h][d][t].
// All LDS tiles linear + chunk-swizzled (p = c ^ (row&7) on src and read).
// Scores scaled by SCALE post-MFMA. Mask only on kt==0 / kt==8.
// ---------------------------------------------------------------------------
#define QTI 64
#define KTI 64
#define PS_LD 72

__global__ __launch_bounds__(256)
void local_attn_kernel(const bf16_t* __restrict__ qkv_bf, const bf16_t* __restrict__ vt,
                       bf16_t* __restrict__ cxb) {
    __shared__ __align__(16) bf16_t Qs[QTI * 128];
    __shared__ __align__(16) bf16_t Ks[KTI * 128];
    __shared__ __align__(16) bf16_t Vts[128 * KTI];
    __shared__ bf16_t Ps[4][16 * PS_LD];

    const int h = blockIdx.y;
    const int t0 = blockIdx.x * QTI;
    const int tid = threadIdx.x;
    const int wave = tid >> 6, lane = tid & 63;
    const int quad = lane >> 4, l16 = lane & 15;
    const int xsw = l16 & 7;

    const bf16_t* vth = vt + (size_t)h * 128 * 2048;

    // stage Q once (async, swizzled): 1024 chunks
#pragma unroll
    for (int i = 0; i < 4; ++i) {
        int c = i * 256 + tid;
        int row = c >> 4, pc = c & 15;
        int lc = pc ^ (row & 7);
        async_copy16(qkv_bf + (size_t)(t0 + row) * ROW_BF + h * HD + lc * 8, &Qs[c * 8]);
    }

    f32x4 o[8];
#pragma unroll
    for (int d8 = 0; d8 < 8; ++d8) o[d8] = (f32x4){0.f, 0.f, 0.f, 0.f};
    float m_i[4] = {-1e30f, -1e30f, -1e30f, -1e30f};
    float l_i[4] = {0.f, 0.f, 0.f, 0.f};

    __syncthreads();

    for (int kt = 0; kt < 9; ++kt) {
        const int sbase = t0 - 512 + kt * KTI;
        if (sbase < 0) continue;
        __syncthreads();
        // K tile [64 s][128 d], async swizzled
#pragma unroll
        for (int i = 0; i < 4; ++i) {
            int c = i * 256 + tid;
            int row = c >> 4, pc = c & 15;
            int lc = pc ^ (row & 7);
            async_copy16(qkv_bf + (size_t)(sbase + row) * ROW_BF + KB_OFF + h * HD + lc * 8,
                         &Ks[c * 8]);
        }
        // V^T tile [128 d][64 s], async swizzled
#pragma unroll
        for (int i = 0; i < 4; ++i) {
            int c = i * 256 + tid;
            int row = c >> 3, pc = c & 7;
            int lc = pc ^ (row & 7);
            async_copy16(vth + (size_t)row * 2048 + sbase + lc * 8, &Vts[c * 8]);
        }
        __syncthreads();

        f32x4 sacc[4];
#pragma unroll
        for (int nt = 0; nt < 4; ++nt) sacc[nt] = (f32x4){0.f, 0.f, 0.f, 0.f};
#pragma unroll
        for (int ks = 0; ks < 4; ++ks) {
            bf16x8 a = *(const bf16x8*)&Qs[(wave * 16 + l16) * 128 + (((ks * 4 + quad) ^ xsw)) * 8];
#pragma unroll
            for (int nt = 0; nt < 4; ++nt) {
                bf16x8 b = *(const bf16x8*)&Ks[(nt * 16 + l16) * 128 + (((ks * 4 + quad) ^ xsw)) * 8];
                sacc[nt] = __builtin_amdgcn_mfma_f32_16x16x32_bf16(a, b, sacc[nt], 0, 0, 0);
            }
        }

#pragma unroll
        for (int nt = 0; nt < 4; ++nt)
#pragma unroll
            for (int r = 0; r < 4; ++r) sacc[nt][r] *= SCALE;

        if (kt == 0 || kt == 8) {   // uniform branch; interior tiles need no mask
#pragma unroll
            for (int nt = 0; nt < 4; ++nt) {
                int s_g = sbase + nt * 16 + l16;
#pragma unroll
                for (int r = 0; r < 4; ++r) {
                    int t_g = t0 + wave * 16 + quad * 4 + r;
                    bool valid = (s_g <= t_g) && (s_g + W_LOCAL > t_g);
                    if (!valid) sacc[nt][r] = -1e30f;
                }
            }
        }

#pragma unroll
        for (int r = 0; r < 4; ++r) {
            float mx = fmaxf(fmaxf(sacc[0][r], sacc[1][r]), fmaxf(sacc[2][r], sacc[3][r]));
            mx = fmaxf(mx, __shfl_xor(mx, 1));
            mx = fmaxf(mx, __shfl_xor(mx, 2));
            mx = fmaxf(mx, __shfl_xor(mx, 4));
            mx = fmaxf(mx, __shfl_xor(mx, 8));
            float mnew = fmaxf(m_i[r], mx);
            float alpha = __expf(m_i[r] - mnew);
            m_i[r] = mnew;
            float rs = 0.f;
#pragma unroll
            for (int nt = 0; nt < 4; ++nt) {
                float p = __expf(sacc[nt][r] - mnew);
                sacc[nt][r] = p;
                rs += p;
            }
            rs += __shfl_xor(rs, 1);
            rs += __shfl_xor(rs, 2);
            rs += __shfl_xor(rs, 4);
            rs += __shfl_xor(rs, 8);
            l_i[r] = l_i[r] * alpha + rs;
#pragma unroll
            for (int d8 = 0; d8 < 8; ++d8) o[d8][r] *= alpha;
        }

#pragma unroll
        for (int r = 0; r < 4; ++r)
#pragma unroll
            for (int nt = 0; nt < 4; ++nt)
                Ps[wave][(quad * 4 + r) * PS_LD + nt * 16 + l16] = (bf16_t)sacc[nt][r];

#pragma unroll
        for (int ks2 = 0; ks2 < 2; ++ks2) {
            bf16x8 a = *(const bf16x8*)&Ps[wave][l16 * PS_LD + ks2 * 32 + quad * 8];
#pragma unroll
            for (int d8 = 0; d8 < 8; ++d8) {
                int rw = d8 * 16 + l16;
                bf16x8 b = *(const bf16x8*)&Vts[rw * 64 + (((ks2 * 4 + quad) ^ xsw)) * 8];
                o[d8] = __builtin_amdgcn_mfma_f32_16x16x32_bf16(a, b, o[d8], 0, 0, 0);
            }
        }
    }

#pragma unroll
    for (int r = 0; r < 4; ++r) {
        float inv = 1.0f / l_i[r];
        size_t rowoff = (size_t)(t0 + wave * 16 + quad * 4 + r) * 2048 + h * HD;
#pragma unroll
        for (int d8 = 0; d8 < 8; ++d8)
            cxb[rowoff + d8 * 16 + l16] = (bf16_t)(o[d8][r] * inv);
    }
}

// ---------------------------------------------------------------------------
// Gated global low-rank branch (early-exit when gate==0); bf16 RMW into cxb
// ---------------------------------------------------------------------------
__device__ __forceinline__ float block_reduce_max512(float v, float* red, int tid) {
    red[tid] = v; __syncthreads();
    for (int s = 256; s > 0; s >>= 1) {
        if (tid < s) red[tid] = fmaxf(red[tid], red[tid + s]);
        __syncthreads();
    }
    float r = red[0]; __syncthreads();
    return r;
}
__device__ __forceinline__ float block_reduce_sum512(float v, float* red, int tid) {
    red[tid] = v; __syncthreads();
    for (int s = 256; s > 0; s >>= 1) {
        if (tid < s) red[tid] = red[tid] + red[tid + s];
        __syncthreads();
    }
    float r = red[0]; __syncthreads();
    return r;
}

__global__ __launch_bounds__(512)
void global_attn_kernel(bf16_t* __restrict__ cxb, const float* __restrict__ kr,
                        const float* __restrict__ vr, const bf16_t* __restrict__ qr,
                        const float* __restrict__ uo, const float* __restrict__ gate) {
    const int t = blockIdx.x, h = blockIdx.y;
    if (gate[t] <= 0.5f) return;

    __shared__ float qrs[64];
    __shared__ float red[512];
    __shared__ float cgr[64];
    __shared__ float sg[2048];
    const int tid = threadIdx.x;

    if (tid < 64) qrs[tid] = (float)qr[((size_t)h * T_LEN + t) * RANK + tid];
    __syncthreads();

    const float* krh = kr + (size_t)h * T_LEN * RANK;
    const float* vrh = vr + (size_t)h * T_LEN * RANK;
    float lmax = -INFINITY;
    for (int s = tid; s < T_LEN; s += 512) {
        const float* krr = krh + (size_t)s * RANK;
        float acc = 0.f;
#pragma unroll
        for (int r = 0; r < RANK; r += 4) {
            float4 k4 = *(const float4*)(krr + r);
            acc += qrs[r] * k4.x + qrs[r + 1] * k4.y + qrs[r + 2] * k4.z + qrs[r + 3] * k4.w;
        }
        float sc = acc * SCALE_G;
        sg[s] = sc;
        lmax = fmaxf(lmax, sc);
    }
    float gmx = block_reduce_max512(lmax, red, tid);
    float lsum = 0.f;
    for (int s = tid; s < T_LEN; s += 512) {
        float pp = expf(sg[s] - gmx);
        sg[s] = pp;
        lsum += pp;
    }
    float gsum = block_reduce_sum512(lsum, red, tid);

    {
        const int r = tid & 63, part = tid >> 6;
        float pacc = 0.f;
        for (int s = part; s < T_LEN; s += 8) pacc += sg[s] * vrh[(size_t)s * RANK + r];
        red[tid] = pacc;
        __syncthreads();
        if (tid < 64) {
            float c = 0.f;
#pragma unroll
            for (int pp = 0; pp < 8; ++pp) c += red[pp * 64 + tid];
            cgr[tid] = c / gsum;
        }
        __syncthreads();
    }

    if (tid < 128) {
        float cg = 0.f;
#pragma unroll
        for (int r = 0; r < RANK; ++r) cg += cgr[r] * uo[tid * RANK + r];
        size_t off = (size_t)t * 2048 + h * HD + tid;
        cxb[off] = (bf16_t)((float)cxb[off] + cg);
    }
}

// ---------------------------------------------------------------------------
extern "C" void kernel_launch(void* const* d_in, const int* in_sizes, int n_in,
                              void* d_out, int out_size, void* d_ws, size_t ws_size,
                              hipStream_t stream) {
    const float* x     = (const float*)d_in[0];
    const float* w_qkv = (const float*)d_in[1];
    const float* w_o   = (const float*)d_in[2];
    const float* pk    = (const float*)d_in[3];
    const float* pv    = (const float*)d_in[4];
    const float* uo    = (const float*)d_in[5];
    const float* w1    = (const float*)d_in[6];
    const float* w2    = (const float*)d_in[7];
    float* out = (float*)d_out;

    // Workspace layout (floats), lifetime-aliased (~88 MB):
    float* ws = (float*)d_ws;
    float* qkv   = ws;                        // 12,582,912 f: bf16 overlay rows
                                              //  q bf16 | K bf16 | wo bf16 | V bf16
    float* hinfo = qkv + (size_t)12582912;    // 1,048,576 f: rope tab, later qr bf16
    float* gatep = hinfo + (size_t)1048576;   // 2048 f
    bf16_t* xb   = (bf16_t*)(gatep + 2048);   // x_hi bf16 (later ctx bf16)
    float* wqbf  = gatep + 2048 + 2097152;    // 6,291,456 f region:
    bf16_t* wqb  = (bf16_t*)wqbf;             //   w_qkv bf16 (entire region)
    float* krp   = wqbf;                      //   later: kr
    float* vrp   = wqbf + (size_t)2097152;    //   later: vr
    float* tabp  = hinfo;                     // rope tables (dead before qr)
    bf16_t* qrp  = (bf16_t*)hinfo;            // qr bf16 (written by kvr)
    bf16_t* cxb  = xb;                        // ctx bf16
    bf16_t* qkvb = (bf16_t*)qkv;              // bf16 overlay view of qkv rows
    bf16_t* wob  = qkvb + WO_OFF;             // w_o bf16, row stride ROW_BF
    // d_out doubles as scratch until gemm_ctx_wo overwrites it:
    bf16_t* vtp  = (bf16_t*)d_out;            // V^T [16][128][2048] bf16 (8.39 MB)
    float* ipart = (float*)(vtp + (size_t)16 * 128 * 2048);  // 2x2048x512 f (8.39 MB)

    // 1) merged prep: x->bf16, w_qkv->bf16, rope tables
    prep_kernel<<<8704, 256, 0, stream>>>(x, xb, w_qkv, wqb, tabp);
    // 2) MERGED: info MLP (blocks [0,128), reg-staged from fp32 x/w1,
    //    partials->ipart in d_out) + qkv GEMM (blocks [128,896), 128x128 v4,
    //    fused RoPE, V overlay + V^T) + piggy w_o->bf16 (blocks [896,2944))
    gemm_qkv_rope<<<2944, 256, 0, stream>>>(xb, wqb, qkvb, vtp, tabp, w_o, x, w1, ipart);
    // 3) gate from 2 split-K partials
    info_gate_kernel<<<T_LEN, 64, 0, stream>>>(ipart, w2, gatep);
    // 4) k_r, v_r, q_r via MFMA (kr/vr overwrite dead wqb; qr over dead tab)
    kvr_mfma_kernel<<<dim3(T_LEN / 64, NH), 256, 0, stream>>>(qkvb, pk, pv, krp, vrp, qrp);
    // 5) flash local attention (async-staged Q/K/V^T) -> ctx bf16 (cxb)
    local_attn_kernel<<<dim3(T_LEN / QTI, NH), 256, 0, stream>>>(qkvb, vtp, cxb);
    // 6) gated global branch (bf16 RMW into cxb)
    global_attn_kernel<<<dim3(T_LEN, NH), 512, 0, stream>>>(cxb, krp, vrp, qrp, uo, gatep);
    // 7) out = ctx @ w_o^T  (v4 pipelined, B = wob overlay strided ROW_BF)
    gemm_ctx_wo<<<256, 256, 0, stream>>>(cxb, wob, out);
}

// Round 8
// 285.806 us; speedup vs baseline: 1.3849x; 1.0285x over previous
//
#include <hip/hip_runtime.h>
#include <hip/hip_bf16.h>
#include <math.h>

// Problem constants
#define T_LEN 2048
#define C_DIM 2048
#define NH 16
#define HD 128
#define RANK 64
#define W_LOCAL 512
#define QKV_LD 6144
#define ROW_BF 12288          // qkv row stride in bf16 elems
#define KB_OFF 4096           // bf16-elem offset of packed K overlay within row
#define VB_OFF 8192           // bf16-elem offset of packed V overlay within row
#define WO_OFF 6144           // bf16-elem offset of packed w_o row within qkv row
#define SCALE 0.08838834764831845f    // 1/sqrt(128)
#define SCALE_G 0.17677669529663687f  // scale * 128/64
#define LOG1E4_OVER_64 0.14391156831212787f

typedef __bf16 bf16_t;
typedef __bf16 bf16x8 __attribute__((ext_vector_type(8)));
typedef __bf16 bf16x4 __attribute__((ext_vector_type(4)));
typedef float f32x4 __attribute__((ext_vector_type(4)));

// ---------------------------------------------------------------------------
// async 16B global -> LDS (gfx950). LDS dst must be wave-uniform base+lane*16.
// ---------------------------------------------------------------------------
__device__ __forceinline__ void async_copy16(const bf16_t* g, bf16_t* l) {
    __builtin_amdgcn_global_load_lds(
        (const __attribute__((address_space(1))) unsigned int*)g,
        (__attribute__((address_space(3))) unsigned int*)l, 16, 0, 0);
}

// ---------------------------------------------------------------------------
// Merged prep kernel (block-range dispatch):
//  [0,2048):    x -> xb bf16 (hi only; info MLP re-derives lo from fp32 x)
//  [2048,8192): w_qkv -> wqb bf16
//  [8192,8704): rope tables
// ---------------------------------------------------------------------------
__global__ __launch_bounds__(256)
void prep_kernel(const float* __restrict__ x, bf16_t* __restrict__ xb,
                 const float* __restrict__ w_qkv, bf16_t* __restrict__ wqb,
                 float* __restrict__ tab) {
    const int bid = blockIdx.x;
    const int tid = threadIdx.x;
    if (bid < 2048) {
        int idx = bid * 256 + tid;                   // 8 elems each
        const float* p = x + (size_t)idx * 8;
        float4 v0 = *(const float4*)p;
        float4 v1 = *(const float4*)(p + 4);
        bf16x8 o;
        o[0] = (bf16_t)v0.x; o[1] = (bf16_t)v0.y; o[2] = (bf16_t)v0.z; o[3] = (bf16_t)v0.w;
        o[4] = (bf16_t)v1.x; o[5] = (bf16_t)v1.y; o[6] = (bf16_t)v1.z; o[7] = (bf16_t)v1.w;
        *(bf16x8*)(xb + (size_t)idx * 8) = o;
    } else if (bid < 8192) {
        // w_qkv fp32 -> bf16 (6144x2048)
        int idx = (bid - 2048) * 256 + tid;          // 8 elems each
        const float* p = w_qkv + (size_t)idx * 8;
        float4 v0 = *(const float4*)p;
        float4 v1 = *(const float4*)(p + 4);
        bf16x8 o;
        o[0] = (bf16_t)v0.x; o[1] = (bf16_t)v0.y; o[2] = (bf16_t)v0.z; o[3] = (bf16_t)v0.w;
        o[4] = (bf16_t)v1.x; o[5] = (bf16_t)v1.y; o[6] = (bf16_t)v1.z; o[7] = (bf16_t)v1.w;
        *(bf16x8*)(wqb + (size_t)idx * 8) = o;
    } else {
        // rope tables
        int idx = (bid - 8192) * 256 + tid;          // 2048*64
        int t = idx >> 6, j = idx & 63;
        float inv = expf(-(float)j * LOG1E4_OVER_64);
        float s, c;
        sincosf((float)t * inv, &s, &c);
        tab[t * 128 + j] = c;
        tab[t * 128 + 64 + j] = s;
    }
}

// ---------------------------------------------------------------------------
// MERGED dispatch: info-MLP GEMM + qkv GEMM v4 + piggy-backed w_o conversion.
//  Blocks [0,128):    info MLP split-bf16 GEMM (split-K=2), reg-staged from
//                     fp32 x/w1, partials->ipart (second half of d_out).
//  Blocks [128,896):  qkv GEMM 128x128/BK=64/2 blocks/CU, counted vmcnt,
//                     both-sides XOR swizzle, fused RoPE epilogue, V overlay
//                     + V^T (vt, first half of d_out).
//  Blocks [896,2944): w_o row -> bf16 WO_OFF overlay.
// ---------------------------------------------------------------------------
#define NTK 32      // 2048 / 64
#define ILD 40      // info LDS leading dim (padded: 128x40 bf16 per buffer)

#define STG_A(bb, ktile) do {                                                  \
    _Pragma("unroll")                                                          \
    for (int c_ = 0; c_ < 4; ++c_)                                             \
        async_copy16(gA + (size_t)(c_ * 32) * 2048 + (ktile) * 64,             \
                     &lds[bb][0][(c_ * 32 + rS) * 64 + dS]);                   \
} while (0)

#define STG_B(bb, ktile) do {                                                  \
    _Pragma("unroll")                                                          \
    for (int c_ = 0; c_ < 4; ++c_)                                             \
        async_copy16(gB + (size_t)(c_ * 32) * 2048 + (ktile) * 64,             \
                     &lds[bb][1][(c_ * 32 + rS) * 64 + dS]);                   \
} while (0)

#define RD_A(bb, m, k) (*(const bf16x8*)&lds[bb][0][(wr * 64 + (m) * 16 + l16) * 64 + (((k) * 4 + quad) ^ xsw) * 8])
#define RD_B(bb, n, k) (*(const bf16x8*)&lds[bb][1][(wc * 64 + (n) * 16 + l16) * 64 + (((k) * 4 + quad) ^ xsw) * 8])

__global__ __launch_bounds__(256, 2)
void gemm_qkv_rope(const bf16_t* __restrict__ A, const bf16_t* __restrict__ B,
                   bf16_t* __restrict__ qkv_bf, bf16_t* __restrict__ vt,
                   const float* __restrict__ tab, const float* __restrict__ w_o,
                   const float* __restrict__ x, const float* __restrict__ w1,
                   float* __restrict__ ipart) {
    __shared__ __align__(16) unsigned char smem[65536];
    const int bid = blockIdx.x;
    const int tid = threadIdx.x;

    if (bid < 128) {
        // ---------------- info MLP block (split-bf16, 3x MFMA) ----------------
        bf16_t* Ah = (bf16_t*)smem;            // [128][ILD]
        bf16_t* Al = Ah + 128 * ILD;
        bf16_t* Bh = Al + 128 * ILD;
        bf16_t* Bl = Bh + 128 * ILD;
        const int bn = bid & 3, bm = (bid >> 2) & 15, ks = bid >> 6;
        const int wave = tid >> 6, lane = tid & 63;
        const int quad = lane >> 4, l16 = lane & 15;
        const int wm = (wave >> 1) * 64, wn = (wave & 1) * 64;
        const int lrow = lane >> 2;
        const int lkb = (lane & 3) * 8;
        const int kbeg = ks * 1024;

        f32x4 acc[4][4];
#pragma unroll
        for (int i = 0; i < 4; ++i)
#pragma unroll
            for (int j = 0; j < 4; ++j) acc[i][j] = (f32x4){0.f, 0.f, 0.f, 0.f};

        const float* gx = x + (size_t)(bm * 128 + wave * 16 + lrow) * 2048 + kbeg + lkb;
        const float* gw = w1 + (size_t)(bn * 128 + wave * 16 + lrow) * 2048 + kbeg + lkb;
        const int wrow = (wave * 16 + lrow) * ILD + lkb;

        for (int k0 = 0; k0 < 1024; k0 += 32) {
            __syncthreads();
#pragma unroll
            for (int hr = 0; hr < 2; ++hr) {
                const float* px = gx + (size_t)hr * 64 * 2048 + k0;
                float4 a0 = *(const float4*)px, a1 = *(const float4*)(px + 4);
                float av[8] = {a0.x, a0.y, a0.z, a0.w, a1.x, a1.y, a1.z, a1.w};
                bf16x8 h, l;
#pragma unroll
                for (int i = 0; i < 8; ++i) {
                    bf16_t hb = (bf16_t)av[i];
                    h[i] = hb; l[i] = (bf16_t)(av[i] - (float)hb);
                }
                *(bf16x8*)&Ah[wrow + hr * 64 * ILD] = h;
                *(bf16x8*)&Al[wrow + hr * 64 * ILD] = l;

                const float* pw = gw + (size_t)hr * 64 * 2048 + k0;
                float4 b0 = *(const float4*)pw, b1 = *(const float4*)(pw + 4);
                float bv[8] = {b0.x, b0.y, b0.z, b0.w, b1.x, b1.y, b1.z, b1.w};
                bf16x8 hb2, lb2;
#pragma unroll
                for (int i = 0; i < 8; ++i) {
                    bf16_t hh = (bf16_t)bv[i];
                    hb2[i] = hh; lb2[i] = (bf16_t)(bv[i] - (float)hh);
                }
                *(bf16x8*)&Bh[wrow + hr * 64 * ILD] = hb2;
                *(bf16x8*)&Bl[wrow + hr * 64 * ILD] = lb2;
            }
            __syncthreads();

            bf16x8 ah[4], al[4], bh[4], bl[4];
#pragma unroll
            for (int mt = 0; mt < 4; ++mt) {
                ah[mt] = *(const bf16x8*)&Ah[(wm + mt * 16 + l16) * ILD + quad * 8];
                al[mt] = *(const bf16x8*)&Al[(wm + mt * 16 + l16) * ILD + quad * 8];
            }
#pragma unroll
            for (int nt = 0; nt < 4; ++nt) {
                bh[nt] = *(const bf16x8*)&Bh[(wn + nt * 16 + l16) * ILD + quad * 8];
                bl[nt] = *(const bf16x8*)&Bl[(wn + nt * 16 + l16) * ILD + quad * 8];
            }
#pragma unroll
            for (int mt = 0; mt < 4; ++mt)
#pragma unroll
                for (int nt = 0; nt < 4; ++nt) {
                    acc[mt][nt] = __builtin_amdgcn_mfma_f32_16x16x32_bf16(ah[mt], bh[nt], acc[mt][nt], 0, 0, 0);
                    acc[mt][nt] = __builtin_amdgcn_mfma_f32_16x16x32_bf16(ah[mt], bl[nt], acc[mt][nt], 0, 0, 0);
                    acc[mt][nt] = __builtin_amdgcn_mfma_f32_16x16x32_bf16(al[mt], bh[nt], acc[mt][nt], 0, 0, 0);
                }
        }

        float* cp = ipart + (size_t)ks * 2048 * 512;
#pragma unroll
        for (int mt = 0; mt < 4; ++mt)
#pragma unroll
            for (int r = 0; r < 4; ++r) {
                int row = bm * 128 + wm + mt * 16 + quad * 4 + r;
                float* crow = cp + (size_t)row * 512 + bn * 128 + wn;
#pragma unroll
                for (int nt = 0; nt < 4; ++nt)
                    crow[nt * 16 + l16] = acc[mt][nt][r];
            }
        return;
    }

    if (bid >= 896) {
        // ---------------- w_o conversion: one row per block ----------------
        int row = bid - 896;
        int c = tid * 8;
        const float* p = w_o + (size_t)row * 2048 + c;
        float4 v0 = *(const float4*)p;
        float4 v1 = *(const float4*)(p + 4);
        bf16x8 o;
        o[0] = (bf16_t)v0.x; o[1] = (bf16_t)v0.y; o[2] = (bf16_t)v0.z; o[3] = (bf16_t)v0.w;
        o[4] = (bf16_t)v1.x; o[5] = (bf16_t)v1.y; o[6] = (bf16_t)v1.z; o[7] = (bf16_t)v1.w;
        *(bf16x8*)(qkv_bf + (size_t)row * ROW_BF + WO_OFF + c) = o;
        return;
    }

    // ---------------- qkv GEMM v4 block ----------------
    typedef bf16_t ldsbuf_t[2][128 * 64];
    ldsbuf_t* lds = (ldsbuf_t*)smem;           // [2][2][8192], 64 KiB

    const int gid = bid - 128;                 // 0..767
    const int xcd = gid & 7, idx = gid >> 3;   // 96 blocks per XCD, contiguous bn stripe
    const int bn_ = xcd * 6 + (idx >> 4);      // 0..47
    const int bm_ = idx & 15;                  // 0..15
    const int wave = tid >> 6, lane = tid & 63;
    const int quad = lane >> 4, l16 = lane & 15;
    const int wr = wave >> 1, wc = wave & 1;   // 2x2 wave grid, wave tile 64x64
    const int xsw = l16 & 7;

    // staging geometry: thread covers (row rS + 32*c, phys chunk tid&7);
    // global source chunk pre-swizzled: phys chunk p holds logical p^(row&7)
    const int rS = tid >> 3;                   // 0..31
    const int cS = ((tid & 7) ^ (rS & 7)) * 8; // global col (bf16)
    const int dS = (tid & 7) * 8;              // linear LDS chunk
    const bf16_t* gA = A + (size_t)(bm_ * 128 + rS) * 2048 + cS;
    const bf16_t* gB = B + (size_t)(bn_ * 128 + rS) * 2048 + cS;

    f32x4 acc[4][4];
#pragma unroll
    for (int i = 0; i < 4; ++i)
#pragma unroll
        for (int j = 0; j < 4; ++j) acc[i][j] = (f32x4){0.f, 0.f, 0.f, 0.f};

    // Prologue: stage tiles 0 and 1; wait for tile 0, leave tile 1 in flight.
    STG_A(0, 0); STG_B(0, 0);
    STG_A(1, 1); STG_B(1, 1);
    asm volatile("s_waitcnt vmcnt(8)" ::: "memory");
    __builtin_amdgcn_s_barrier();

    for (int kt = 0; kt < NTK; ++kt) {
        const int b = kt & 1;
        bf16x8 af[4][2], bfr[4][2];
#pragma unroll
        for (int m = 0; m < 4; ++m) { af[m][0] = RD_A(b, m, 0); af[m][1] = RD_A(b, m, 1); }
#pragma unroll
        for (int n = 0; n < 4; ++n) { bfr[n][0] = RD_B(b, n, 0); bfr[n][1] = RD_B(b, n, 1); }
        asm volatile("s_waitcnt lgkmcnt(0)" ::: "memory");
        __builtin_amdgcn_s_barrier();          // all waves done reading buf b

        __builtin_amdgcn_s_setprio(1);
#pragma unroll
        for (int m = 0; m < 4; ++m)
#pragma unroll
            for (int n = 0; n < 4; ++n)
                acc[m][n] = __builtin_amdgcn_mfma_f32_16x16x32_bf16(af[m][0], bfr[n][0], acc[m][n], 0, 0, 0);
        __builtin_amdgcn_s_setprio(0);
        if (kt + 2 < NTK) STG_A(b, kt + 2);    // buf b safe to overwrite now

        __builtin_amdgcn_s_setprio(1);
#pragma unroll
        for (int m = 0; m < 4; ++m)
#pragma unroll
            for (int n = 0; n < 4; ++n)
                acc[m][n] = __builtin_amdgcn_mfma_f32_16x16x32_bf16(af[m][1], bfr[n][1], acc[m][n], 0, 0, 0);
        __builtin_amdgcn_s_setprio(0);
        if (kt + 2 < NTK) STG_B(b, kt + 2);

        if (kt < NTK - 2) { asm volatile("s_waitcnt vmcnt(8)" ::: "memory"); }
        else              { asm volatile("s_waitcnt vmcnt(0)" ::: "memory"); }
        __builtin_amdgcn_s_barrier();
    }

    // ---- epilogue ----
    const int colbase = bn_ * 128 + wc * 64;
    const int region = (bn_ * 128) >> 11;      // 0=q, 1=k, 2=v (block-uniform)
    const int rowbase = bm_ * 128 + wr * 64;
    const bool odd = (l16 & 1);

    if (region == 2) {
        // (a) row-major V overlay (for kvr)
#pragma unroll
        for (int mt = 0; mt < 4; ++mt)
#pragma unroll
            for (int r = 0; r < 4; ++r) {
                int t = rowbase + mt * 16 + quad * 4 + r;
                bf16_t* brow = qkv_bf + (size_t)t * ROW_BF + VB_OFF + (colbase - 4096);
#pragma unroll
                for (int nt = 0; nt < 4; ++nt)
                    brow[nt * 16 + l16] = (bf16_t)acc[mt][nt][r];
            }
        // (b) transposed vt[h][d][t] via LDS transpose (tile = exactly one head)
        bf16_t* Tl = (bf16_t*)smem;            // [128][136] bf16, 34.8 KB
#pragma unroll
        for (int mt = 0; mt < 4; ++mt)
#pragma unroll
            for (int r = 0; r < 4; ++r) {
                int rloc = wr * 64 + mt * 16 + quad * 4 + r;
#pragma unroll
                for (int nt = 0; nt < 4; ++nt) {
                    int cloc = wc * 64 + nt * 16 + l16;
                    Tl[cloc * 136 + rloc] = (bf16_t)acc[mt][nt][r];
                }
            }
        __syncthreads();
        const int hh = bn_ - 32;               // head index
        const int d = tid >> 1, th = (tid & 1) * 64;
        bf16_t* dst = vt + ((size_t)(hh * 128 + d)) * 2048 + bm_ * 128 + th;
        const bf16_t* srcT = Tl + d * 136 + th;
#pragma unroll
        for (int j = 0; j < 8; ++j)
            *(bf16x8*)(dst + j * 8) = *(const bf16x8*)(srcT + j * 8);
    } else {
        // RoPE for q/k; store bf16 overlay (q @0, k @KB_OFF)
#pragma unroll
        for (int mt = 0; mt < 4; ++mt)
#pragma unroll
            for (int r = 0; r < 4; ++r) {
                int t = rowbase + mt * 16 + quad * 4 + r;
                const float* trow = tab + t * 128;
#pragma unroll
                for (int nt = 0; nt < 4; ++nt) {
                    float v = acc[mt][nt][r];
                    float vp = __shfl_xor(v, 1);    // pair column value
                    int col = colbase + nt * 16 + l16;
                    int j = col & 63;
                    float c = trow[j], s = trow[64 + j];
                    float y = odd ? (v * c + vp * s) : (v * c - vp * s);
                    qkv_bf[(size_t)t * ROW_BF + (region == 0 ? col : col + 2048)] = (bf16_t)y;
                }
            }
    }
}

// ---------------------------------------------------------------------------
// Final GEMM: out = ctx @ w_o^T, v4 pipeline, 128x64 tile -> 512 blocks
// (2 blocks/CU for cross-block overlap). A = cxb (lda 2048); B = wob
// (overlay, ldb ROW_BF). Counted vmcnt(6); both-sides swizzle.
// ---------------------------------------------------------------------------
#define STG_A3(bb, ktile) do {                                                 \
    _Pragma("unroll")                                                          \
    for (int c_ = 0; c_ < 4; ++c_)                                             \
        async_copy16(gA + (size_t)(c_ * 32) * 2048 + (ktile) * 64,             \
                     &ldsA[bb][(c_ * 32 + rS) * 64 + dS]);                     \
} while (0)

#define STG_B3(bb, ktile) do {                                                 \
    _Pragma("unroll")                                                          \
    for (int c_ = 0; c_ < 2; ++c_)                                             \
        async_copy16(gB + (size_t)(c_ * 32) * ROW_BF + (ktile) * 64,           \
                     &ldsB[bb][(c_ * 32 + rS) * 64 + dS]);                     \
} while (0)

#define RD_A3(bb, m, k) (*(const bf16x8*)&ldsA[bb][(wr * 64 + (m) * 16 + l16) * 64 + (((k) * 4 + quad) ^ xsw) * 8])
#define RD_B3(bb, n, k) (*(const bf16x8*)&ldsB[bb][(wc * 32 + (n) * 16 + l16) * 64 + (((k) * 4 + quad) ^ xsw) * 8])

__global__ __launch_bounds__(256, 2)
void gemm_ctx_wo(const bf16_t* __restrict__ A, const bf16_t* __restrict__ Bov,
                 float* __restrict__ C) {
    __shared__ __align__(16) bf16_t ldsA[2][128 * 64];   // 32 KiB
    __shared__ __align__(16) bf16_t ldsB[2][64 * 64];    // 16 KiB

    const int bid = blockIdx.x;                // 0..511
    const int xcd = bid & 7, idx = bid >> 3;   // 64 blocks per XCD
    const int bn_ = xcd * 4 + (idx >> 4);      // 0..31
    const int bm_ = idx & 15;                  // 0..15
    const int tid = threadIdx.x;
    const int wave = tid >> 6, lane = tid & 63;
    const int quad = lane >> 4, l16 = lane & 15;
    const int wr = wave >> 1, wc = wave & 1;   // wave tile 64x32
    const int xsw = l16 & 7;

    const int rS = tid >> 3;
    const int cS = ((tid & 7) ^ (rS & 7)) * 8;
    const int dS = (tid & 7) * 8;
    const bf16_t* gA = A + (size_t)(bm_ * 128 + rS) * 2048 + cS;
    const bf16_t* gB = Bov + (size_t)(bn_ * 64 + rS) * ROW_BF + cS;

    f32x4 acc[4][2];
#pragma unroll
    for (int i = 0; i < 4; ++i)
#pragma unroll
        for (int j = 0; j < 2; ++j) acc[i][j] = (f32x4){0.f, 0.f, 0.f, 0.f};

    STG_A3(0, 0); STG_B3(0, 0);
    STG_A3(1, 1); STG_B3(1, 1);
    asm volatile("s_waitcnt vmcnt(6)" ::: "memory");
    __builtin_amdgcn_s_barrier();

    for (int kt = 0; kt < NTK; ++kt) {
        const int b = kt & 1;
        bf16x8 af[4][2], bfr[2][2];
#pragma unroll
        for (int m = 0; m < 4; ++m) { af[m][0] = RD_A3(b, m, 0); af[m][1] = RD_A3(b, m, 1); }
#pragma unroll
        for (int n = 0; n < 2; ++n) { bfr[n][0] = RD_B3(b, n, 0); bfr[n][1] = RD_B3(b, n, 1); }
        asm volatile("s_waitcnt lgkmcnt(0)" ::: "memory");
        __builtin_amdgcn_s_barrier();

        __builtin_amdgcn_s_setprio(1);
#pragma unroll
        for (int m = 0; m < 4; ++m)
#pragma unroll
            for (int n = 0; n < 2; ++n)
                acc[m][n] = __builtin_amdgcn_mfma_f32_16x16x32_bf16(af[m][0], bfr[n][0], acc[m][n], 0, 0, 0);
        __builtin_amdgcn_s_setprio(0);
        if (kt + 2 < NTK) STG_A3(b, kt + 2);

        __builtin_amdgcn_s_setprio(1);
#pragma unroll
        for (int m = 0; m < 4; ++m)
#pragma unroll
            for (int n = 0; n < 2; ++n)
                acc[m][n] = __builtin_amdgcn_mfma_f32_16x16x32_bf16(af[m][1], bfr[n][1], acc[m][n], 0, 0, 0);
        __builtin_amdgcn_s_setprio(0);
        if (kt + 2 < NTK) STG_B3(b, kt + 2);

        if (kt < NTK - 2) { asm volatile("s_waitcnt vmcnt(6)" ::: "memory"); }
        else              { asm volatile("s_waitcnt vmcnt(0)" ::: "memory"); }
        __builtin_amdgcn_s_barrier();
    }

    const int colbase = bn_ * 64 + wc * 32;
    const int rowbase = bm_ * 128 + wr * 64;
#pragma unroll
    for (int mt = 0; mt < 4; ++mt)
#pragma unroll
        for (int r = 0; r < 4; ++r) {
            int row = rowbase + mt * 16 + quad * 4 + r;
            float* crow = C + (size_t)row * 2048 + colbase;
#pragma unroll
            for (int nt = 0; nt < 2; ++nt)
                crow[nt * 16 + l16] = acc[mt][nt][r];
        }
}

__device__ __forceinline__ float gelu_exact(float v) {
    return 0.5f * v * (1.0f + erff(v * 0.70710678118654752f));
}

// ---------------------------------------------------------------------------
// MERGED attention dispatch (all inputs produced by the qkv dispatch):
//  Blocks [0,512):     flash local attention (h = bid>>5, t0 = (bid&31)*64)
//  Blocks [512,1024):  kvr (3-phase: Pk/Pv resident + Op buffer K->V->Q)
//  Blocks [1024,1536): gate (4 waves x 1 row each)
// LDS union = local's 58368 B -> 2 blocks/CU.
// ---------------------------------------------------------------------------
#define QTI 64
#define KTI 64
#define PS_LD 72
#define KV_LD 136

__global__ __launch_bounds__(256, 2)
void attn_fused(const bf16_t* __restrict__ qkv_bf, const bf16_t* __restrict__ vt,
                bf16_t* __restrict__ cxb,
                const float* __restrict__ pk, const float* __restrict__ pv,
                float* __restrict__ kr, float* __restrict__ vr,
                bf16_t* __restrict__ qr,
                const float* __restrict__ Cpart, const float* __restrict__ w2,
                float* __restrict__ gate) {
    __shared__ __align__(16) unsigned char smem[58368];
    const int bid = blockIdx.x;
    const int tid = threadIdx.x;
    const int wave = tid >> 6, lane = tid & 63;
    const int quad = lane >> 4, l16 = lane & 15;

    if (bid >= 1024) {
        // ---------------- gate: 4 waves, one t per wave ----------------
        const int t = (bid - 1024) * 4 + wave;
        const float* p0 = Cpart + (size_t)t * 512;
        float s = 0.f;
#pragma unroll
        for (int i = lane; i < 512; i += 64) {
            float v = p0[i] + p0[i + 1048576];
            s += gelu_exact(v) * w2[i];
        }
#pragma unroll
        for (int off = 32; off > 0; off >>= 1) s += __shfl_down(s, off);
        if (lane == 0) {
            float sig = 1.f / (1.f + expf(-s));
            gate[t] = (sig > 0.75f) ? 1.f : 0.f;
        }
        return;
    }

    if (bid >= 512) {
        // ---------------- kvr: 3-phase (Pk/Pv resident, Op = K->V->Q) --------
        bf16_t* Pk = (bf16_t*)smem;            // [64][KV_LD]
        bf16_t* Pv = Pk + 64 * KV_LD;
        bf16_t* Op = Pv + 64 * KV_LD;
        const int i0 = bid - 512;
        const int h = i0 >> 5, s0 = (i0 & 31) * 64;

#pragma unroll
        for (int i = 0; i < 8; ++i) {
            int gid = i * 256 + tid;
            int row = gid >> 5, c = (gid & 31) << 2;
            float4 wk = *(const float4*)(pk + (size_t)row * HD + c);
            float4 wv = *(const float4*)(pv + (size_t)row * HD + c);
            bf16x4 qk4, qv4;
            qk4[0] = (bf16_t)wk.x; qk4[1] = (bf16_t)wk.y; qk4[2] = (bf16_t)wk.z; qk4[3] = (bf16_t)wk.w;
            qv4[0] = (bf16_t)wv.x; qv4[1] = (bf16_t)wv.y; qv4[2] = (bf16_t)wv.z; qv4[3] = (bf16_t)wv.w;
            *(bf16x4*)&Pk[row * KV_LD + c] = qk4;
            *(bf16x4*)&Pv[row * KV_LD + c] = qv4;
        }

        f32x4 ak[4], av[4], aq[4];
#pragma unroll
        for (int nt = 0; nt < 4; ++nt) {
            ak[nt] = (f32x4){0.f, 0.f, 0.f, 0.f};
            av[nt] = (f32x4){0.f, 0.f, 0.f, 0.f};
            aq[nt] = (f32x4){0.f, 0.f, 0.f, 0.f};
        }

        // phase 1: K
#pragma unroll
        for (int i = 0; i < 4; ++i) {
            int gid = i * 256 + tid;
            int row = gid >> 4, ch = (gid & 15) << 3;
            *(bf16x8*)&Op[row * KV_LD + ch] =
                *(const bf16x8*)(qkv_bf + (size_t)(s0 + row) * ROW_BF + KB_OFF + h * HD + ch);
        }
        __syncthreads();
#pragma unroll
        for (int ks = 0; ks < 4; ++ks) {
            bf16x8 a = *(const bf16x8*)&Op[(wave * 16 + l16) * KV_LD + ks * 32 + quad * 8];
#pragma unroll
            for (int nt = 0; nt < 4; ++nt) {
                bf16x8 bk = *(const bf16x8*)&Pk[(nt * 16 + l16) * KV_LD + ks * 32 + quad * 8];
                ak[nt] = __builtin_amdgcn_mfma_f32_16x16x32_bf16(a, bk, ak[nt], 0, 0, 0);
            }
        }
        __syncthreads();
        // phase 2: V
#pragma unroll
        for (int i = 0; i < 4; ++i) {
            int gid = i * 256 + tid;
            int row = gid >> 4, ch = (gid & 15) << 3;
            *(bf16x8*)&Op[row * KV_LD + ch] =
                *(const bf16x8*)(qkv_bf + (size_t)(s0 + row) * ROW_BF + VB_OFF + h * HD + ch);
        }
        __syncthreads();
#pragma unroll
        for (int ks = 0; ks < 4; ++ks) {
            bf16x8 a = *(const bf16x8*)&Op[(wave * 16 + l16) * KV_LD + ks * 32 + quad * 8];
#pragma unroll
            for (int nt = 0; nt < 4; ++nt) {
                bf16x8 bv = *(const bf16x8*)&Pv[(nt * 16 + l16) * KV_LD + ks * 32 + quad * 8];
                av[nt] = __builtin_amdgcn_mfma_f32_16x16x32_bf16(a, bv, av[nt], 0, 0, 0);
            }
        }
        __syncthreads();
        // phase 3: Q
#pragma unroll
        for (int i = 0; i < 4; ++i) {
            int gid = i * 256 + tid;
            int row = gid >> 4, ch = (gid & 15) << 3;
            *(bf16x8*)&Op[row * KV_LD + ch] =
                *(const bf16x8*)(qkv_bf + (size_t)(s0 + row) * ROW_BF + h * HD + ch);
        }
        __syncthreads();
#pragma unroll
        for (int ks = 0; ks < 4; ++ks) {
            bf16x8 a = *(const bf16x8*)&Op[(wave * 16 + l16) * KV_LD + ks * 32 + quad * 8];
#pragma unroll
            for (int nt = 0; nt < 4; ++nt) {
                bf16x8 bk = *(const bf16x8*)&Pk[(nt * 16 + l16) * KV_LD + ks * 32 + quad * 8];
                aq[nt] = __builtin_amdgcn_mfma_f32_16x16x32_bf16(a, bk, aq[nt], 0, 0, 0);
            }
        }

#pragma unroll
        for (int nt = 0; nt < 4; ++nt)
#pragma unroll
            for (int r = 0; r < 4; ++r) {
                int s = s0 + wave * 16 + quad * 4 + r;
                size_t idx = ((size_t)h * T_LEN + s) * RANK + nt * 16 + l16;
                kr[idx] = ak[nt][r];
                vr[idx] = av[nt][r];
                qr[idx] = (bf16_t)aq[nt][r];
            }
        return;
    }

    // ---------------- flash local attention ----------------
    bf16_t* Qs  = (bf16_t*)smem;               // [QTI*128]
    bf16_t* Ks  = Qs + QTI * 128;
    bf16_t* Vts = Ks + KTI * 128;              // [128*KTI]
    bf16_t* Psb = Vts + 128 * KTI;             // [4][16*PS_LD]

    const int h = bid >> 5;
    const int t0 = (bid & 31) * QTI;
    const int xsw = l16 & 7;

    const bf16_t* vth = vt + (size_t)h * 128 * 2048;

    // stage Q once (async, swizzled)
#pragma unroll
    for (int i = 0; i < 4; ++i) {
        int c = i * 256 + tid;
        int row = c >> 4, pc = c & 15;
        int lc = pc ^ (row & 7);
        async_copy16(qkv_bf + (size_t)(t0 + row) * ROW_BF + h * HD + lc * 8, &Qs[c * 8]);
    }

    f32x4 o[8];
#pragma unroll
    for (int d8 = 0; d8 < 8; ++d8) o[d8] = (f32x4){0.f, 0.f, 0.f, 0.f};
    float m_i[4] = {-1e30f, -1e30f, -1e30f, -1e30f};
    float l_i[4] = {0.f, 0.f, 0.f, 0.f};

    __syncthreads();

    for (int kt = 0; kt < 9; ++kt) {
        const int sbase = t0 - 512 + kt * KTI;
        if (sbase < 0) continue;
        __syncthreads();
        // K tile [64 s][128 d], async swizzled
#pragma unroll
        for (int i = 0; i < 4; ++i) {
            int c = i * 256 + tid;
            int row = c >> 4, pc = c & 15;
            int lc = pc ^ (row & 7);
            async_copy16(qkv_bf + (size_t)(sbase + row) * ROW_BF + KB_OFF + h * HD + lc * 8,
                         &Ks[c * 8]);
        }
        // V^T tile [128 d][64 s], async swizzled
#pragma unroll
        for (int i = 0; i < 4; ++i) {
            int c = i * 256 + tid;
            int row = c >> 3, pc = c & 7;
            int lc = pc ^ (row & 7);
            async_copy16(vth + (size_t)row * 2048 + sbase + lc * 8, &Vts[c * 8]);
        }
        __syncthreads();

        f32x4 sacc[4];
#pragma unroll
        for (int nt = 0; nt < 4; ++nt) sacc[nt] = (f32x4){0.f, 0.f, 0.f, 0.f};
#pragma unroll
        for (int ks = 0; ks < 4; ++ks) {
            bf16x8 a = *(const bf16x8*)&Qs[(wave * 16 + l16) * 128 + (((ks * 4 + quad) ^ xsw)) * 8];
#pragma unroll
            for (int nt = 0; nt < 4; ++nt) {
                bf16x8 b = *(const bf16x8*)&Ks[(nt * 16 + l16) * 128 + (((ks * 4 + quad) ^ xsw)) * 8];
                sacc[nt] = __builtin_amdgcn_mfma_f32_16x16x32_bf16(a, b, sacc[nt], 0, 0, 0);
            }
        }

#pragma unroll
        for (int nt = 0; nt < 4; ++nt)
#pragma unroll
            for (int r = 0; r < 4; ++r) sacc[nt][r] *= SCALE;

        if (kt == 0 || kt == 8) {   // uniform branch; interior tiles need no mask
#pragma unroll
            for (int nt = 0; nt < 4; ++nt) {
                int s_g = sbase + nt * 16 + l16;
#pragma unroll
                for (int r = 0; r < 4; ++r) {
                    int t_g = t0 + wave * 16 + quad * 4 + r;
                    bool valid = (s_g <= t_g) && (s_g + W_LOCAL > t_g);
                    if (!valid) sacc[nt][r] = -1e30f;
                }
            }
        }

#pragma unroll
        for (int r = 0; r < 4; ++r) {
            float mx = fmaxf(fmaxf(sacc[0][r], sacc[1][r]), fmaxf(sacc[2][r], sacc[3][r]));
            mx = fmaxf(mx, __shfl_xor(mx, 1));
            mx = fmaxf(mx, __shfl_xor(mx, 2));
            mx = fmaxf(mx, __shfl_xor(mx, 4));
            mx = fmaxf(mx, __shfl_xor(mx, 8));
            float mnew = fmaxf(m_i[r], mx);
            float alpha = __expf(m_i[r] - mnew);
            m_i[r] = mnew;
            float rs = 0.f;
#pragma unroll
            for (int nt = 0; nt < 4; ++nt) {
                float p = __expf(sacc[nt][r] - mnew);
                sacc[nt][r] = p;
                rs += p;
            }
            rs += __shfl_xor(rs, 1);
            rs += __shfl_xor(rs, 2);
            rs += __shfl_xor(rs, 4);
            rs += __shfl_xor(rs, 8);
            l_i[r] = l_i[r] * alpha + rs;
#pragma unroll
            for (int d8 = 0; d8 < 8; ++d8) o[d8][r] *= alpha;
        }

#pragma unroll
        for (int r = 0; r < 4; ++r)
#pragma unroll
            for (int nt = 0; nt < 4; ++nt)
                Psb[wave * 16 * PS_LD + (quad * 4 + r) * PS_LD + nt * 16 + l16] = (bf16_t)sacc[nt][r];

#pragma unroll
        for (int ks2 = 0; ks2 < 2; ++ks2) {
            bf16x8 a = *(const bf16x8*)&Psb[wave * 16 * PS_LD + l16 * PS_LD + ks2 * 32 + quad * 8];
#pragma unroll
            for (int d8 = 0; d8 < 8; ++d8) {
                int rw = d8 * 16 + l16;
                bf16x8 b = *(const bf16x8*)&Vts[rw * 64 + (((ks2 * 4 + quad) ^ xsw)) * 8];
                o[d8] = __builtin_amdgcn_mfma_f32_16x16x32_bf16(a, b, o[d8], 0, 0, 0);
            }
        }
    }

#pragma unroll
    for (int r = 0; r < 4; ++r) {
        float inv = 1.0f / l_i[r];
        size_t rowoff = (size_t)(t0 + wave * 16 + quad * 4 + r) * 2048 + h * HD;
#pragma unroll
        for (int d8 = 0; d8 < 8; ++d8)
            cxb[rowoff + d8 * 16 + l16] = (bf16_t)(o[d8][r] * inv);
    }
}

// ---------------------------------------------------------------------------
// Gated global low-rank branch (early-exit when gate==0); bf16 RMW into cxb
// ---------------------------------------------------------------------------
__device__ __forceinline__ float block_reduce_max512(float v, float* red, int tid) {
    red[tid] = v; __syncthreads();
    for (int s = 256; s > 0; s >>= 1) {
        if (tid < s) red[tid] = fmaxf(red[tid], red[tid + s]);
        __syncthreads();
    }
    float r = red[0]; __syncthreads();
    return r;
}
__device__ __forceinline__ float block_reduce_sum512(float v, float* red, int tid) {
    red[tid] = v; __syncthreads();
    for (int s = 256; s > 0; s >>= 1) {
        if (tid < s) red[tid] = red[tid] + red[tid + s];
        __syncthreads();
    }
    float r = red[0]; __syncthreads();
    return r;
}

__global__ __launch_bounds__(512)
void global_attn_kernel(bf16_t* __restrict__ cxb, const float* __restrict__ kr,
                        const float* __restrict__ vr, const bf16_t* __restrict__ qr,
                        const float* __restrict__ uo, const float* __restrict__ gate) {
    const int t = blockIdx.x, h = blockIdx.y;
    if (gate[t] <= 0.5f) return;

    __shared__ float qrs[64];
    __shared__ float red[512];
    __shared__ float cgr[64];
    __shared__ float sg[2048];
    const int tid = threadIdx.x;

    if (tid < 64) qrs[tid] = (float)qr[((size_t)h * T_LEN + t) * RANK + tid];
    __syncthreads();

    const float* krh = kr + (size_t)h * T_LEN * RANK;
    const float* vrh = vr + (size_t)h * T_LEN * RANK;
    float lmax = -INFINITY;
    for (int s = tid; s < T_LEN; s += 512) {
        const float* krr = krh + (size_t)s * RANK;
        float acc = 0.f;
#pragma unroll
        for (int r = 0; r < RANK; r += 4) {
            float4 k4 = *(const float4*)(krr + r);
            acc += qrs[r] * k4.x + qrs[r + 1] * k4.y + qrs[r + 2] * k4.z + qrs[r + 3] * k4.w;
        }
        float sc = acc * SCALE_G;
        sg[s] = sc;
        lmax = fmaxf(lmax, sc);
    }
    float gmx = block_reduce_max512(lmax, red, tid);
    float lsum = 0.f;
    for (int s = tid; s < T_LEN; s += 512) {
        float pp = expf(sg[s] - gmx);
        sg[s] = pp;
        lsum += pp;
    }
    float gsum = block_reduce_sum512(lsum, red, tid);

    {
        const int r = tid & 63, part = tid >> 6;
        float pacc = 0.f;
        for (int s = part; s < T_LEN; s += 8) pacc += sg[s] * vrh[(size_t)s * RANK + r];
        red[tid] = pacc;
        __syncthreads();
        if (tid < 64) {
            float c = 0.f;
#pragma unroll
            for (int pp = 0; pp < 8; ++pp) c += red[pp * 64 + tid];
            cgr[tid] = c / gsum;
        }
        __syncthreads();
    }

    if (tid < 128) {
        float cg = 0.f;
#pragma unroll
        for (int r = 0; r < RANK; ++r) cg += cgr[r] * uo[tid * RANK + r];
        size_t off = (size_t)t * 2048 + h * HD + tid;
        cxb[off] = (bf16_t)((float)cxb[off] + cg);
    }
}

// ---------------------------------------------------------------------------
extern "C" void kernel_launch(void* const* d_in, const int* in_sizes, int n_in,
                              void* d_out, int out_size, void* d_ws, size_t ws_size,
                              hipStream_t stream) {
    const float* x     = (const float*)d_in[0];
    const float* w_qkv = (const float*)d_in[1];
    const float* w_o   = (const float*)d_in[2];
    const float* pk    = (const float*)d_in[3];
    const float* pv    = (const float*)d_in[4];
    const float* uo    = (const float*)d_in[5];
    const float* w1    = (const float*)d_in[6];
    const float* w2    = (const float*)d_in[7];
    float* out = (float*)d_out;

    // Workspace layout (floats), lifetime-aliased (~88 MB):
    float* ws = (float*)d_ws;
    float* qkv   = ws;                        // 12,582,912 f: bf16 overlay rows
                                              //  q bf16 | K bf16 | wo bf16 | V bf16
    float* hinfo = qkv + (size_t)12582912;    // 1,048,576 f: rope tab, later qr bf16
    float* gatep = hinfo + (size_t)1048576;   // 2048 f
    bf16_t* xb   = (bf16_t*)(gatep + 2048);   // x_hi bf16 (later ctx bf16)
    float* wqbf  = gatep + 2048 + 2097152;    // 6,291,456 f region:
    bf16_t* wqb  = (bf16_t*)wqbf;             //   w_qkv bf16 (entire region)
    float* krp   = wqbf;                      //   later: kr
    float* vrp   = wqbf + (size_t)2097152;    //   later: vr
    float* tabp  = hinfo;                     // rope tables (dead before qr)
    bf16_t* qrp  = (bf16_t*)hinfo;            // qr bf16 (written by attn_fused)
    bf16_t* cxb  = xb;                        // ctx bf16
    bf16_t* qkvb = (bf16_t*)qkv;              // bf16 overlay view of qkv rows
    bf16_t* wob  = qkvb + WO_OFF;             // w_o bf16, row stride ROW_BF
    // d_out doubles as scratch until gemm_ctx_wo overwrites it:
    bf16_t* vtp  = (bf16_t*)d_out;            // V^T [16][128][2048] bf16 (8.39 MB)
    float* ipart = (float*)(vtp + (size_t)16 * 128 * 2048);  // 2x2048x512 f (8.39 MB)

    // 1) merged prep: x->bf16, w_qkv->bf16, rope tables
    prep_kernel<<<8704, 256, 0, stream>>>(x, xb, w_qkv, wqb, tabp);
    // 2) MERGED: info MLP + qkv GEMM v4 (fused RoPE, V overlay + V^T) + w_o->bf16
    gemm_qkv_rope<<<2944, 256, 0, stream>>>(xb, wqb, qkvb, vtp, tabp, w_o, x, w1, ipart);
    // 3) MERGED: local attention [0,512) + kvr [512,1024) + gate [1024,1536)
    attn_fused<<<1536, 256, 0, stream>>>(qkvb, vtp, cxb, pk, pv, krp, vrp, qrp,
                                         ipart, w2, gatep);
    // 4) gated global branch (bf16 RMW into cxb)
    global_attn_kernel<<<dim3(T_LEN, NH), 512, 0, stream>>>(cxb, krp, vrp, qrp, uo, gatep);
    // 5) out = ctx @ w_o^T  (v4 pipelined, 128x64 tiles, 2 blocks/CU)
    gemm_ctx_wo<<<512, 256, 0, stream>>>(cxb, wob, out);
}

// Round 9
// 279.560 us; speedup vs baseline: 1.4158x; 1.0223x over previous
//
#include <hip/hip_runtime.h>
#include <hip/hip_bf16.h>
#include <math.h>

// Problem constants
#define T_LEN 2048
#define C_DIM 2048
#define NH 16
#define HD 128
#define RANK 64
#define W_LOCAL 512
#define QKV_LD 6144
#define ROW_BF 12288          // qkv row stride in bf16 elems
#define KB_OFF 4096           // bf16-elem offset of packed K overlay within row
#define VB_OFF 8192           // bf16-elem offset of packed V overlay within row
#define WO_OFF 6144           // bf16-elem offset of packed w_o row within qkv row
#define SCALE 0.08838834764831845f    // 1/sqrt(128)
#define SCALE_G 0.17677669529663687f  // scale * 128/64
#define LOG1E4_OVER_64 0.14391156831212787f

typedef __bf16 bf16_t;
typedef __bf16 bf16x8 __attribute__((ext_vector_type(8)));
typedef __bf16 bf16x4 __attribute__((ext_vector_type(4)));
typedef float f32x4 __attribute__((ext_vector_type(4)));

// ---------------------------------------------------------------------------
// async 16B global -> LDS (gfx950). LDS dst must be wave-uniform base+lane*16.
// ---------------------------------------------------------------------------
__device__ __forceinline__ void async_copy16(const bf16_t* g, bf16_t* l) {
    __builtin_amdgcn_global_load_lds(
        (const __attribute__((address_space(1))) unsigned int*)g,
        (__attribute__((address_space(3))) unsigned int*)l, 16, 0, 0);
}

// ---------------------------------------------------------------------------
// Merged prep kernel (block-range dispatch):
//  [0,2048):    x -> xb bf16 (hi only; info MLP re-derives lo from fp32 x)
//  [2048,8192): w_qkv -> wqb bf16
//  [8192,8704): rope tables
// ---------------------------------------------------------------------------
__global__ __launch_bounds__(256)
void prep_kernel(const float* __restrict__ x, bf16_t* __restrict__ xb,
                 const float* __restrict__ w_qkv, bf16_t* __restrict__ wqb,
                 float* __restrict__ tab) {
    const int bid = blockIdx.x;
    const int tid = threadIdx.x;
    if (bid < 2048) {
        int idx = bid * 256 + tid;                   // 8 elems each
        const float* p = x + (size_t)idx * 8;
        float4 v0 = *(const float4*)p;
        float4 v1 = *(const float4*)(p + 4);
        bf16x8 o;
        o[0] = (bf16_t)v0.x; o[1] = (bf16_t)v0.y; o[2] = (bf16_t)v0.z; o[3] = (bf16_t)v0.w;
        o[4] = (bf16_t)v1.x; o[5] = (bf16_t)v1.y; o[6] = (bf16_t)v1.z; o[7] = (bf16_t)v1.w;
        *(bf16x8*)(xb + (size_t)idx * 8) = o;
    } else if (bid < 8192) {
        // w_qkv fp32 -> bf16 (6144x2048)
        int idx = (bid - 2048) * 256 + tid;          // 8 elems each
        const float* p = w_qkv + (size_t)idx * 8;
        float4 v0 = *(const float4*)p;
        float4 v1 = *(const float4*)(p + 4);
        bf16x8 o;
        o[0] = (bf16_t)v0.x; o[1] = (bf16_t)v0.y; o[2] = (bf16_t)v0.z; o[3] = (bf16_t)v0.w;
        o[4] = (bf16_t)v1.x; o[5] = (bf16_t)v1.y; o[6] = (bf16_t)v1.z; o[7] = (bf16_t)v1.w;
        *(bf16x8*)(wqb + (size_t)idx * 8) = o;
    } else {
        // rope tables
        int idx = (bid - 8192) * 256 + tid;          // 2048*64
        int t = idx >> 6, j = idx & 63;
        float inv = expf(-(float)j * LOG1E4_OVER_64);
        float s, c;
        sincosf((float)t * inv, &s, &c);
        tab[t * 128 + j] = c;
        tab[t * 128 + 64 + j] = s;
    }
}

// ---------------------------------------------------------------------------
// MERGED dispatch: info-MLP GEMM + qkv GEMM v4 + piggy-backed w_o conversion.
//  Blocks [0,128):    info MLP split-bf16 GEMM (split-K=2), reg-staged from
//                     fp32 x/w1, partials->ipart (second half of d_out).
//  Blocks [128,896):  qkv GEMM 128x128/BK=64/2 blocks/CU, counted vmcnt,
//                     both-sides XOR swizzle, fused RoPE epilogue, V overlay
//                     + V^T (vt, first half of d_out).
//                     bn-FASTEST within XCD: the 3 MB B-stripe stays L2-
//                     resident across all 16 bm-groups (A-tile streams).
//  Blocks [896,2944): w_o row -> bf16 WO_OFF overlay.
// ---------------------------------------------------------------------------
#define NTK 32      // 2048 / 64
#define ILD 40      // info LDS leading dim (padded: 128x40 bf16 per buffer)

#define STG_A(bb, ktile) do {                                                  \
    _Pragma("unroll")                                                          \
    for (int c_ = 0; c_ < 4; ++c_)                                             \
        async_copy16(gA + (size_t)(c_ * 32) * 2048 + (ktile) * 64,             \
                     &lds[bb][0][(c_ * 32 + rS) * 64 + dS]);                   \
} while (0)

#define STG_B(bb, ktile) do {                                                  \
    _Pragma("unroll")                                                          \
    for (int c_ = 0; c_ < 4; ++c_)                                             \
        async_copy16(gB + (size_t)(c_ * 32) * 2048 + (ktile) * 64,             \
                     &lds[bb][1][(c_ * 32 + rS) * 64 + dS]);                   \
} while (0)

#define RD_A(bb, m, k) (*(const bf16x8*)&lds[bb][0][(wr * 64 + (m) * 16 + l16) * 64 + (((k) * 4 + quad) ^ xsw) * 8])
#define RD_B(bb, n, k) (*(const bf16x8*)&lds[bb][1][(wc * 64 + (n) * 16 + l16) * 64 + (((k) * 4 + quad) ^ xsw) * 8])

__global__ __launch_bounds__(256, 2)
void gemm_qkv_rope(const bf16_t* __restrict__ A, const bf16_t* __restrict__ B,
                   bf16_t* __restrict__ qkv_bf, bf16_t* __restrict__ vt,
                   const float* __restrict__ tab, const float* __restrict__ w_o,
                   const float* __restrict__ x, const float* __restrict__ w1,
                   float* __restrict__ ipart) {
    __shared__ __align__(16) unsigned char smem[65536];
    const int bid = blockIdx.x;
    const int tid = threadIdx.x;

    if (bid < 128) {
        // ---------------- info MLP block (split-bf16, 3x MFMA) ----------------
        bf16_t* Ah = (bf16_t*)smem;            // [128][ILD]
        bf16_t* Al = Ah + 128 * ILD;
        bf16_t* Bh = Al + 128 * ILD;
        bf16_t* Bl = Bh + 128 * ILD;
        const int bn = bid & 3, bm = (bid >> 2) & 15, ks = bid >> 6;
        const int wave = tid >> 6, lane = tid & 63;
        const int quad = lane >> 4, l16 = lane & 15;
        const int wm = (wave >> 1) * 64, wn = (wave & 1) * 64;
        const int lrow = lane >> 2;
        const int lkb = (lane & 3) * 8;
        const int kbeg = ks * 1024;

        f32x4 acc[4][4];
#pragma unroll
        for (int i = 0; i < 4; ++i)
#pragma unroll
            for (int j = 0; j < 4; ++j) acc[i][j] = (f32x4){0.f, 0.f, 0.f, 0.f};

        const float* gx = x + (size_t)(bm * 128 + wave * 16 + lrow) * 2048 + kbeg + lkb;
        const float* gw = w1 + (size_t)(bn * 128 + wave * 16 + lrow) * 2048 + kbeg + lkb;
        const int wrow = (wave * 16 + lrow) * ILD + lkb;

        for (int k0 = 0; k0 < 1024; k0 += 32) {
            __syncthreads();
#pragma unroll
            for (int hr = 0; hr < 2; ++hr) {
                const float* px = gx + (size_t)hr * 64 * 2048 + k0;
                float4 a0 = *(const float4*)px, a1 = *(const float4*)(px + 4);
                float av[8] = {a0.x, a0.y, a0.z, a0.w, a1.x, a1.y, a1.z, a1.w};
                bf16x8 h, l;
#pragma unroll
                for (int i = 0; i < 8; ++i) {
                    bf16_t hb = (bf16_t)av[i];
                    h[i] = hb; l[i] = (bf16_t)(av[i] - (float)hb);
                }
                *(bf16x8*)&Ah[wrow + hr * 64 * ILD] = h;
                *(bf16x8*)&Al[wrow + hr * 64 * ILD] = l;

                const float* pw = gw + (size_t)hr * 64 * 2048 + k0;
                float4 b0 = *(const float4*)pw, b1 = *(const float4*)(pw + 4);
                float bv[8] = {b0.x, b0.y, b0.z, b0.w, b1.x, b1.y, b1.z, b1.w};
                bf16x8 hb2, lb2;
#pragma unroll
                for (int i = 0; i < 8; ++i) {
                    bf16_t hh = (bf16_t)bv[i];
                    hb2[i] = hh; lb2[i] = (bf16_t)(bv[i] - (float)hh);
                }
                *(bf16x8*)&Bh[wrow + hr * 64 * ILD] = hb2;
                *(bf16x8*)&Bl[wrow + hr * 64 * ILD] = lb2;
            }
            __syncthreads();

            bf16x8 ah[4], al[4], bh[4], bl[4];
#pragma unroll
            for (int mt = 0; mt < 4; ++mt) {
                ah[mt] = *(const bf16x8*)&Ah[(wm + mt * 16 + l16) * ILD + quad * 8];
                al[mt] = *(const bf16x8*)&Al[(wm + mt * 16 + l16) * ILD + quad * 8];
            }
#pragma unroll
            for (int nt = 0; nt < 4; ++nt) {
                bh[nt] = *(const bf16x8*)&Bh[(wn + nt * 16 + l16) * ILD + quad * 8];
                bl[nt] = *(const bf16x8*)&Bl[(wn + nt * 16 + l16) * ILD + quad * 8];
            }
#pragma unroll
            for (int mt = 0; mt < 4; ++mt)
#pragma unroll
                for (int nt = 0; nt < 4; ++nt) {
                    acc[mt][nt] = __builtin_amdgcn_mfma_f32_16x16x32_bf16(ah[mt], bh[nt], acc[mt][nt], 0, 0, 0);
                    acc[mt][nt] = __builtin_amdgcn_mfma_f32_16x16x32_bf16(ah[mt], bl[nt], acc[mt][nt], 0, 0, 0);
                    acc[mt][nt] = __builtin_amdgcn_mfma_f32_16x16x32_bf16(al[mt], bh[nt], acc[mt][nt], 0, 0, 0);
                }
        }

        float* cp = ipart + (size_t)ks * 2048 * 512;
#pragma unroll
        for (int mt = 0; mt < 4; ++mt)
#pragma unroll
            for (int r = 0; r < 4; ++r) {
                int row = bm * 128 + wm + mt * 16 + quad * 4 + r;
                float* crow = cp + (size_t)row * 512 + bn * 128 + wn;
#pragma unroll
                for (int nt = 0; nt < 4; ++nt)
                    crow[nt * 16 + l16] = acc[mt][nt][r];
            }
        return;
    }

    if (bid >= 896) {
        // ---------------- w_o conversion: one row per block ----------------
        int row = bid - 896;
        int c = tid * 8;
        const float* p = w_o + (size_t)row * 2048 + c;
        float4 v0 = *(const float4*)p;
        float4 v1 = *(const float4*)(p + 4);
        bf16x8 o;
        o[0] = (bf16_t)v0.x; o[1] = (bf16_t)v0.y; o[2] = (bf16_t)v0.z; o[3] = (bf16_t)v0.w;
        o[4] = (bf16_t)v1.x; o[5] = (bf16_t)v1.y; o[6] = (bf16_t)v1.z; o[7] = (bf16_t)v1.w;
        *(bf16x8*)(qkv_bf + (size_t)row * ROW_BF + WO_OFF + c) = o;
        return;
    }

    // ---------------- qkv GEMM v4 block ----------------
    typedef bf16_t ldsbuf_t[2][128 * 64];
    ldsbuf_t* lds = (ldsbuf_t*)smem;           // [2][2][8192], 64 KiB

    const int gid = bid - 128;                 // 0..767
    const int xcd = gid & 7, idx = gid >> 3;   // 96 blocks per XCD
    const int bn_ = xcd * 6 + (idx % 6);       // bn FASTEST: B-stripe L2-resident
    const int bm_ = idx / 6;                   // 0..15
    const int wave = tid >> 6, lane = tid & 63;
    const int quad = lane >> 4, l16 = lane & 15;
    const int wr = wave >> 1, wc = wave & 1;   // 2x2 wave grid, wave tile 64x64
    const int xsw = l16 & 7;

    // staging geometry: thread covers (row rS + 32*c, phys chunk tid&7);
    // global source chunk pre-swizzled: phys chunk p holds logical p^(row&7)
    const int rS = tid >> 3;                   // 0..31
    const int cS = ((tid & 7) ^ (rS & 7)) * 8; // global col (bf16)
    const int dS = (tid & 7) * 8;              // linear LDS chunk
    const bf16_t* gA = A + (size_t)(bm_ * 128 + rS) * 2048 + cS;
    const bf16_t* gB = B + (size_t)(bn_ * 128 + rS) * 2048 + cS;

    f32x4 acc[4][4];
#pragma unroll
    for (int i = 0; i < 4; ++i)
#pragma unroll
        for (int j = 0; j < 4; ++j) acc[i][j] = (f32x4){0.f, 0.f, 0.f, 0.f};

    // Prologue: stage tiles 0 and 1; wait for tile 0, leave tile 1 in flight.
    STG_A(0, 0); STG_B(0, 0);
    STG_A(1, 1); STG_B(1, 1);
    asm volatile("s_waitcnt vmcnt(8)" ::: "memory");
    __builtin_amdgcn_s_barrier();

    for (int kt = 0; kt < NTK; ++kt) {
        const int b = kt & 1;
        bf16x8 af[4][2], bfr[4][2];
#pragma unroll
        for (int m = 0; m < 4; ++m) { af[m][0] = RD_A(b, m, 0); af[m][1] = RD_A(b, m, 1); }
#pragma unroll
        for (int n = 0; n < 4; ++n) { bfr[n][0] = RD_B(b, n, 0); bfr[n][1] = RD_B(b, n, 1); }
        asm volatile("s_waitcnt lgkmcnt(0)" ::: "memory");
        __builtin_amdgcn_s_barrier();          // all waves done reading buf b

        __builtin_amdgcn_s_setprio(1);
#pragma unroll
        for (int m = 0; m < 4; ++m)
#pragma unroll
            for (int n = 0; n < 4; ++n)
                acc[m][n] = __builtin_amdgcn_mfma_f32_16x16x32_bf16(af[m][0], bfr[n][0], acc[m][n], 0, 0, 0);
        __builtin_amdgcn_s_setprio(0);
        if (kt + 2 < NTK) STG_A(b, kt + 2);    // buf b safe to overwrite now

        __builtin_amdgcn_s_setprio(1);
#pragma unroll
        for (int m = 0; m < 4; ++m)
#pragma unroll
            for (int n = 0; n < 4; ++n)
                acc[m][n] = __builtin_amdgcn_mfma_f32_16x16x32_bf16(af[m][1], bfr[n][1], acc[m][n], 0, 0, 0);
        __builtin_amdgcn_s_setprio(0);
        if (kt + 2 < NTK) STG_B(b, kt + 2);

        if (kt < NTK - 2) { asm volatile("s_waitcnt vmcnt(8)" ::: "memory"); }
        else              { asm volatile("s_waitcnt vmcnt(0)" ::: "memory"); }
        __builtin_amdgcn_s_barrier();
    }

    // ---- epilogue ----
    const int colbase = bn_ * 128 + wc * 64;
    const int region = (bn_ * 128) >> 11;      // 0=q, 1=k, 2=v (block-uniform)
    const int rowbase = bm_ * 128 + wr * 64;
    const bool odd = (l16 & 1);

    if (region == 2) {
        // (a) row-major V overlay (for kvr)
#pragma unroll
        for (int mt = 0; mt < 4; ++mt)
#pragma unroll
            for (int r = 0; r < 4; ++r) {
                int t = rowbase + mt * 16 + quad * 4 + r;
                bf16_t* brow = qkv_bf + (size_t)t * ROW_BF + VB_OFF + (colbase - 4096);
#pragma unroll
                for (int nt = 0; nt < 4; ++nt)
                    brow[nt * 16 + l16] = (bf16_t)acc[mt][nt][r];
            }
        // (b) transposed vt[h][d][t] via LDS transpose (tile = exactly one head)
        bf16_t* Tl = (bf16_t*)smem;            // [128][136] bf16, 34.8 KB
#pragma unroll
        for (int mt = 0; mt < 4; ++mt)
#pragma unroll
            for (int r = 0; r < 4; ++r) {
                int rloc = wr * 64 + mt * 16 + quad * 4 + r;
#pragma unroll
                for (int nt = 0; nt < 4; ++nt) {
                    int cloc = wc * 64 + nt * 16 + l16;
                    Tl[cloc * 136 + rloc] = (bf16_t)acc[mt][nt][r];
                }
            }
        __syncthreads();
        const int hh = bn_ - 32;               // head index
        const int d = tid >> 1, th = (tid & 1) * 64;
        bf16_t* dst = vt + ((size_t)(hh * 128 + d)) * 2048 + bm_ * 128 + th;
        const bf16_t* srcT = Tl + d * 136 + th;
#pragma unroll
        for (int j = 0; j < 8; ++j)
            *(bf16x8*)(dst + j * 8) = *(const bf16x8*)(srcT + j * 8);
    } else {
        // RoPE for q/k; store bf16 overlay (q @0, k @KB_OFF)
#pragma unroll
        for (int mt = 0; mt < 4; ++mt)
#pragma unroll
            for (int r = 0; r < 4; ++r) {
                int t = rowbase + mt * 16 + quad * 4 + r;
                const float* trow = tab + t * 128;
#pragma unroll
                for (int nt = 0; nt < 4; ++nt) {
                    float v = acc[mt][nt][r];
                    float vp = __shfl_xor(v, 1);    // pair column value
                    int col = colbase + nt * 16 + l16;
                    int j = col & 63;
                    float c = trow[j], s = trow[64 + j];
                    float y = odd ? (v * c + vp * s) : (v * c - vp * s);
                    qkv_bf[(size_t)t * ROW_BF + (region == 0 ? col : col + 2048)] = (bf16_t)y;
                }
            }
    }
}

// ---------------------------------------------------------------------------
// Final GEMM: out = ctx @ w_o^T, v4 pipeline, 128x64 tile -> 512 blocks
// (2 blocks/CU). bn-fastest within XCD (B-stripe 1 MB L2-resident).
// Counted vmcnt(6); both-sides swizzle.
// ---------------------------------------------------------------------------
#define STG_A3(bb, ktile) do {                                                 \
    _Pragma("unroll")                                                          \
    for (int c_ = 0; c_ < 4; ++c_)                                             \
        async_copy16(gA + (size_t)(c_ * 32) * 2048 + (ktile) * 64,             \
                     &ldsA[bb][(c_ * 32 + rS) * 64 + dS]);                     \
} while (0)

#define STG_B3(bb, ktile) do {                                                 \
    _Pragma("unroll")                                                          \
    for (int c_ = 0; c_ < 2; ++c_)                                             \
        async_copy16(gB + (size_t)(c_ * 32) * ROW_BF + (ktile) * 64,           \
                     &ldsB[bb][(c_ * 32 + rS) * 64 + dS]);                     \
} while (0)

#define RD_A3(bb, m, k) (*(const bf16x8*)&ldsA[bb][(wr * 64 + (m) * 16 + l16) * 64 + (((k) * 4 + quad) ^ xsw) * 8])
#define RD_B3(bb, n, k) (*(const bf16x8*)&ldsB[bb][(wc * 32 + (n) * 16 + l16) * 64 + (((k) * 4 + quad) ^ xsw) * 8])

__global__ __launch_bounds__(256, 2)
void gemm_ctx_wo(const bf16_t* __restrict__ A, const bf16_t* __restrict__ Bov,
                 float* __restrict__ C) {
    __shared__ __align__(16) bf16_t ldsA[2][128 * 64];   // 32 KiB
    __shared__ __align__(16) bf16_t ldsB[2][64 * 64];    // 16 KiB

    const int bid = blockIdx.x;                // 0..511
    const int xcd = bid & 7, idx = bid >> 3;   // 64 blocks per XCD
    const int bn_ = xcd * 4 + (idx & 3);       // bn FASTEST: B-stripe L2-resident
    const int bm_ = idx >> 2;                  // 0..15
    const int tid = threadIdx.x;
    const int wave = tid >> 6, lane = tid & 63;
    const int quad = lane >> 4, l16 = lane & 15;
    const int wr = wave >> 1, wc = wave & 1;   // wave tile 64x32
    const int xsw = l16 & 7;

    const int rS = tid >> 3;
    const int cS = ((tid & 7) ^ (rS & 7)) * 8;
    const int dS = (tid & 7) * 8;
    const bf16_t* gA = A + (size_t)(bm_ * 128 + rS) * 2048 + cS;
    const bf16_t* gB = Bov + (size_t)(bn_ * 64 + rS) * ROW_BF + cS;

    f32x4 acc[4][2];
#pragma unroll
    for (int i = 0; i < 4; ++i)
#pragma unroll
        for (int j = 0; j < 2; ++j) acc[i][j] = (f32x4){0.f, 0.f, 0.f, 0.f};

    STG_A3(0, 0); STG_B3(0, 0);
    STG_A3(1, 1); STG_B3(1, 1);
    asm volatile("s_waitcnt vmcnt(6)" ::: "memory");
    __builtin_amdgcn_s_barrier();

    for (int kt = 0; kt < NTK; ++kt) {
        const int b = kt & 1;
        bf16x8 af[4][2], bfr[2][2];
#pragma unroll
        for (int m = 0; m < 4; ++m) { af[m][0] = RD_A3(b, m, 0); af[m][1] = RD_A3(b, m, 1); }
#pragma unroll
        for (int n = 0; n < 2; ++n) { bfr[n][0] = RD_B3(b, n, 0); bfr[n][1] = RD_B3(b, n, 1); }
        asm volatile("s_waitcnt lgkmcnt(0)" ::: "memory");
        __builtin_amdgcn_s_barrier();

        __builtin_amdgcn_s_setprio(1);
#pragma unroll
        for (int m = 0; m < 4; ++m)
#pragma unroll
            for (int n = 0; n < 2; ++n)
                acc[m][n] = __builtin_amdgcn_mfma_f32_16x16x32_bf16(af[m][0], bfr[n][0], acc[m][n], 0, 0, 0);
        __builtin_amdgcn_s_setprio(0);
        if (kt + 2 < NTK) STG_A3(b, kt + 2);

        __builtin_amdgcn_s_setprio(1);
#pragma unroll
        for (int m = 0; m < 4; ++m)
#pragma unroll
            for (int n = 0; n < 2; ++n)
                acc[m][n] = __builtin_amdgcn_mfma_f32_16x16x32_bf16(af[m][1], bfr[n][1], acc[m][n], 0, 0, 0);
        __builtin_amdgcn_s_setprio(0);
        if (kt + 2 < NTK) STG_B3(b, kt + 2);

        if (kt < NTK - 2) { asm volatile("s_waitcnt vmcnt(6)" ::: "memory"); }
        else              { asm volatile("s_waitcnt vmcnt(0)" ::: "memory"); }
        __builtin_amdgcn_s_barrier();
    }

    const int colbase = bn_ * 64 + wc * 32;
    const int rowbase = bm_ * 128 + wr * 64;
#pragma unroll
    for (int mt = 0; mt < 4; ++mt)
#pragma unroll
        for (int r = 0; r < 4; ++r) {
            int row = rowbase + mt * 16 + quad * 4 + r;
            float* crow = C + (size_t)row * 2048 + colbase;
#pragma unroll
            for (int nt = 0; nt < 2; ++nt)
                crow[nt * 16 + l16] = acc[mt][nt][r];
        }
}

__device__ __forceinline__ float gelu_exact(float v) {
    return 0.5f * v * (1.0f + erff(v * 0.70710678118654752f));
}

// ---------------------------------------------------------------------------
// MERGED attention dispatch (all inputs produced by the qkv dispatch):
//  Blocks [0,512):     flash local attention (h = bid>>5, t0 = (bid&31)*64)
//  Blocks [512,1024):  kvr (3-phase: Pk/Pv resident + Op buffer K->V->Q)
//  Blocks [1024,1536): gate (4 waves x 1 row each)
// LDS union = local's 58368 B -> 2 blocks/CU.
// ---------------------------------------------------------------------------
#define QTI 64
#define KTI 64
#define PS_LD 72
#define KV_LD 136

__global__ __launch_bounds__(256, 2)
void attn_fused(const bf16_t* __restrict__ qkv_bf, const bf16_t* __restrict__ vt,
                bf16_t* __restrict__ cxb,
                const float* __restrict__ pk, const float* __restrict__ pv,
                float* __restrict__ kr, float* __restrict__ vr,
                bf16_t* __restrict__ qr,
                const float* __restrict__ Cpart, const float* __restrict__ w2,
                float* __restrict__ gate) {
    __shared__ __align__(16) unsigned char smem[58368];
    const int bid = blockIdx.x;
    const int tid = threadIdx.x;
    const int wave = tid >> 6, lane = tid & 63;
    const int quad = lane >> 4, l16 = lane & 15;

    if (bid >= 1024) {
        // ---------------- gate: 4 waves, one t per wave ----------------
        const int t = (bid - 1024) * 4 + wave;
        const float* p0 = Cpart + (size_t)t * 512;
        float s = 0.f;
#pragma unroll
        for (int i = lane; i < 512; i += 64) {
            float v = p0[i] + p0[i + 1048576];
            s += gelu_exact(v) * w2[i];
        }
#pragma unroll
        for (int off = 32; off > 0; off >>= 1) s += __shfl_down(s, off);
        if (lane == 0) {
            float sig = 1.f / (1.f + expf(-s));
            gate[t] = (sig > 0.75f) ? 1.f : 0.f;
        }
        return;
    }

    if (bid >= 512) {
        // ---------------- kvr: 3-phase (Pk/Pv resident, Op = K->V->Q) --------
        bf16_t* Pk = (bf16_t*)smem;            // [64][KV_LD]
        bf16_t* Pv = Pk + 64 * KV_LD;
        bf16_t* Op = Pv + 64 * KV_LD;
        const int i0 = bid - 512;
        const int h = i0 >> 5, s0 = (i0 & 31) * 64;

#pragma unroll
        for (int i = 0; i < 8; ++i) {
            int gid = i * 256 + tid;
            int row = gid >> 5, c = (gid & 31) << 2;
            float4 wk = *(const float4*)(pk + (size_t)row * HD + c);
            float4 wv = *(const float4*)(pv + (size_t)row * HD + c);
            bf16x4 qk4, qv4;
            qk4[0] = (bf16_t)wk.x; qk4[1] = (bf16_t)wk.y; qk4[2] = (bf16_t)wk.z; qk4[3] = (bf16_t)wk.w;
            qv4[0] = (bf16_t)wv.x; qv4[1] = (bf16_t)wv.y; qv4[2] = (bf16_t)wv.z; qv4[3] = (bf16_t)wv.w;
            *(bf16x4*)&Pk[row * KV_LD + c] = qk4;
            *(bf16x4*)&Pv[row * KV_LD + c] = qv4;
        }

        f32x4 ak[4], av[4], aq[4];
#pragma unroll
        for (int nt = 0; nt < 4; ++nt) {
            ak[nt] = (f32x4){0.f, 0.f, 0.f, 0.f};
            av[nt] = (f32x4){0.f, 0.f, 0.f, 0.f};
            aq[nt] = (f32x4){0.f, 0.f, 0.f, 0.f};
        }

        // phase 1: K
#pragma unroll
        for (int i = 0; i < 4; ++i) {
            int gid = i * 256 + tid;
            int row = gid >> 4, ch = (gid & 15) << 3;
            *(bf16x8*)&Op[row * KV_LD + ch] =
                *(const bf16x8*)(qkv_bf + (size_t)(s0 + row) * ROW_BF + KB_OFF + h * HD + ch);
        }
        __syncthreads();
#pragma unroll
        for (int ks = 0; ks < 4; ++ks) {
            bf16x8 a = *(const bf16x8*)&Op[(wave * 16 + l16) * KV_LD + ks * 32 + quad * 8];
#pragma unroll
            for (int nt = 0; nt < 4; ++nt) {
                bf16x8 bk = *(const bf16x8*)&Pk[(nt * 16 + l16) * KV_LD + ks * 32 + quad * 8];
                ak[nt] = __builtin_amdgcn_mfma_f32_16x16x32_bf16(a, bk, ak[nt], 0, 0, 0);
            }
        }
        __syncthreads();
        // phase 2: V
#pragma unroll
        for (int i = 0; i < 4; ++i) {
            int gid = i * 256 + tid;
            int row = gid >> 4, ch = (gid & 15) << 3;
            *(bf16x8*)&Op[row * KV_LD + ch] =
                *(const bf16x8*)(qkv_bf + (size_t)(s0 + row) * ROW_BF + VB_OFF + h * HD + ch);
        }
        __syncthreads();
#pragma unroll
        for (int ks = 0; ks < 4; ++ks) {
            bf16x8 a = *(const bf16x8*)&Op[(wave * 16 + l16) * KV_LD + ks * 32 + quad * 8];
#pragma unroll
            for (int nt = 0; nt < 4; ++nt) {
                bf16x8 bv = *(const bf16x8*)&Pv[(nt * 16 + l16) * KV_LD + ks * 32 + quad * 8];
                av[nt] = __builtin_amdgcn_mfma_f32_16x16x32_bf16(a, bv, av[nt], 0, 0, 0);
            }
        }
        __syncthreads();
        // phase 3: Q
#pragma unroll
        for (int i = 0; i < 4; ++i) {
            int gid = i * 256 + tid;
            int row = gid >> 4, ch = (gid & 15) << 3;
            *(bf16x8*)&Op[row * KV_LD + ch] =
                *(const bf16x8*)(qkv_bf + (size_t)(s0 + row) * ROW_BF + h * HD + ch);
        }
        __syncthreads();
#pragma unroll
        for (int ks = 0; ks < 4; ++ks) {
            bf16x8 a = *(const bf16x8*)&Op[(wave * 16 + l16) * KV_LD + ks * 32 + quad * 8];
#pragma unroll
            for (int nt = 0; nt < 4; ++nt) {
                bf16x8 bk = *(const bf16x8*)&Pk[(nt * 16 + l16) * KV_LD + ks * 32 + quad * 8];
                aq[nt] = __builtin_amdgcn_mfma_f32_16x16x32_bf16(a, bk, aq[nt], 0, 0, 0);
            }
        }

#pragma unroll
        for (int nt = 0; nt < 4; ++nt)
#pragma unroll
            for (int r = 0; r < 4; ++r) {
                int s = s0 + wave * 16 + quad * 4 + r;
                size_t idx = ((size_t)h * T_LEN + s) * RANK + nt * 16 + l16;
                kr[idx] = ak[nt][r];
                vr[idx] = av[nt][r];
                qr[idx] = (bf16_t)aq[nt][r];
            }
        return;
    }

    // ---------------- flash local attention ----------------
    bf16_t* Qs  = (bf16_t*)smem;               // [QTI*128]
    bf16_t* Ks  = Qs + QTI * 128;
    bf16_t* Vts = Ks + KTI * 128;              // [128*KTI]
    bf16_t* Psb = Vts + 128 * KTI;             // [4][16*PS_LD]

    const int h = bid >> 5;
    const int t0 = (bid & 31) * QTI;
    const int xsw = l16 & 7;

    const bf16_t* vth = vt + (size_t)h * 128 * 2048;

    // stage Q once (async, swizzled)
#pragma unroll
    for (int i = 0; i < 4; ++i) {
        int c = i * 256 + tid;
        int row = c >> 4, pc = c & 15;
        int lc = pc ^ (row & 7);
        async_copy16(qkv_bf + (size_t)(t0 + row) * ROW_BF + h * HD + lc * 8, &Qs[c * 8]);
    }

    f32x4 o[8];
#pragma unroll
    for (int d8 = 0; d8 < 8; ++d8) o[d8] = (f32x4){0.f, 0.f, 0.f, 0.f};
    float m_i[4] = {-1e30f, -1e30f, -1e30f, -1e30f};
    float l_i[4] = {0.f, 0.f, 0.f, 0.f};

    __syncthreads();

    for (int kt = 0; kt < 9; ++kt) {
        const int sbase = t0 - 512 + kt * KTI;
        if (sbase < 0) continue;
        __syncthreads();
        // K tile [64 s][128 d], async swizzled
#pragma unroll
        for (int i = 0; i < 4; ++i) {
            int c = i * 256 + tid;
            int row = c >> 4, pc = c & 15;
            int lc = pc ^ (row & 7);
            async_copy16(qkv_bf + (size_t)(sbase + row) * ROW_BF + KB_OFF + h * HD + lc * 8,
                         &Ks[c * 8]);
        }
        // V^T tile [128 d][64 s], async swizzled
#pragma unroll
        for (int i = 0; i < 4; ++i) {
            int c = i * 256 + tid;
            int row = c >> 3, pc = c & 7;
            int lc = pc ^ (row & 7);
            async_copy16(vth + (size_t)row * 2048 + sbase + lc * 8, &Vts[c * 8]);
        }
        __syncthreads();

        f32x4 sacc[4];
#pragma unroll
        for (int nt = 0; nt < 4; ++nt) sacc[nt] = (f32x4){0.f, 0.f, 0.f, 0.f};
#pragma unroll
        for (int ks = 0; ks < 4; ++ks) {
            bf16x8 a = *(const bf16x8*)&Qs[(wave * 16 + l16) * 128 + (((ks * 4 + quad) ^ xsw)) * 8];
#pragma unroll
            for (int nt = 0; nt < 4; ++nt) {
                bf16x8 b = *(const bf16x8*)&Ks[(nt * 16 + l16) * 128 + (((ks * 4 + quad) ^ xsw)) * 8];
                sacc[nt] = __builtin_amdgcn_mfma_f32_16x16x32_bf16(a, b, sacc[nt], 0, 0, 0);
            }
        }

#pragma unroll
        for (int nt = 0; nt < 4; ++nt)
#pragma unroll
            for (int r = 0; r < 4; ++r) sacc[nt][r] *= SCALE;

        if (kt == 0 || kt == 8) {   // uniform branch; interior tiles need no mask
#pragma unroll
            for (int nt = 0; nt < 4; ++nt) {
                int s_g = sbase + nt * 16 + l16;
#pragma unroll
                for (int r = 0; r < 4; ++r) {
                    int t_g = t0 + wave * 16 + quad * 4 + r;
                    bool valid = (s_g <= t_g) && (s_g + W_LOCAL > t_g);
                    if (!valid) sacc[nt][r] = -1e30f;
                }
            }
        }

#pragma unroll
        for (int r = 0; r < 4; ++r) {
            float mx = fmaxf(fmaxf(sacc[0][r], sacc[1][r]), fmaxf(sacc[2][r], sacc[3][r]));
            mx = fmaxf(mx, __shfl_xor(mx, 1));
            mx = fmaxf(mx, __shfl_xor(mx, 2));
            mx = fmaxf(mx, __shfl_xor(mx, 4));
            mx = fmaxf(mx, __shfl_xor(mx, 8));
            float mnew = fmaxf(m_i[r], mx);
            float alpha = __expf(m_i[r] - mnew);
            m_i[r] = mnew;
            float rs = 0.f;
#pragma unroll
            for (int nt = 0; nt < 4; ++nt) {
                float p = __expf(sacc[nt][r] - mnew);
                sacc[nt][r] = p;
                rs += p;
            }
            rs += __shfl_xor(rs, 1);
            rs += __shfl_xor(rs, 2);
            rs += __shfl_xor(rs, 4);
            rs += __shfl_xor(rs, 8);
            l_i[r] = l_i[r] * alpha + rs;
#pragma unroll
            for (int d8 = 0; d8 < 8; ++d8) o[d8][r] *= alpha;
        }

#pragma unroll
        for (int r = 0; r < 4; ++r)
#pragma unroll
            for (int nt = 0; nt < 4; ++nt)
                Psb[wave * 16 * PS_LD + (quad * 4 + r) * PS_LD + nt * 16 + l16] = (bf16_t)sacc[nt][r];

#pragma unroll
        for (int ks2 = 0; ks2 < 2; ++ks2) {
            bf16x8 a = *(const bf16x8*)&Psb[wave * 16 * PS_LD + l16 * PS_LD + ks2 * 32 + quad * 8];
#pragma unroll
            for (int d8 = 0; d8 < 8; ++d8) {
                int rw = d8 * 16 + l16;
                bf16x8 b = *(const bf16x8*)&Vts[rw * 64 + (((ks2 * 4 + quad) ^ xsw)) * 8];
                o[d8] = __builtin_amdgcn_mfma_f32_16x16x32_bf16(a, b, o[d8], 0, 0, 0);
            }
        }
    }

#pragma unroll
    for (int r = 0; r < 4; ++r) {
        float inv = 1.0f / l_i[r];
        size_t rowoff = (size_t)(t0 + wave * 16 + quad * 4 + r) * 2048 + h * HD;
#pragma unroll
        for (int d8 = 0; d8 < 8; ++d8)
            cxb[rowoff + d8 * 16 + l16] = (bf16_t)(o[d8][r] * inv);
    }
}

// ---------------------------------------------------------------------------
// Gated global low-rank branch (early-exit when gate==0); bf16 RMW into cxb
// ---------------------------------------------------------------------------
__device__ __forceinline__ float block_reduce_max512(float v, float* red, int tid) {
    red[tid] = v; __syncthreads();
    for (int s = 256; s > 0; s >>= 1) {
        if (tid < s) red[tid] = fmaxf(red[tid], red[tid + s]);
        __syncthreads();
    }
    float r = red[0]; __syncthreads();
    return r;
}
__device__ __forceinline__ float block_reduce_sum512(float v, float* red, int tid) {
    red[tid] = v; __syncthreads();
    for (int s = 256; s > 0; s >>= 1) {
        if (tid < s) red[tid] = red[tid] + red[tid + s];
        __syncthreads();
    }
    float r = red[0]; __syncthreads();
    return r;
}

__global__ __launch_bounds__(512)
void global_attn_kernel(bf16_t* __restrict__ cxb, const float* __restrict__ kr,
                        const float* __restrict__ vr, const bf16_t* __restrict__ qr,
                        const float* __restrict__ uo, const float* __restrict__ gate) {
    const int t = blockIdx.x, h = blockIdx.y;
    if (gate[t] <= 0.5f) return;

    __shared__ float qrs[64];
    __shared__ float red[512];
    __shared__ float cgr[64];
    __shared__ float sg[2048];
    const int tid = threadIdx.x;

    if (tid < 64) qrs[tid] = (float)qr[((size_t)h * T_LEN + t) * RANK + tid];
    __syncthreads();

    const float* krh = kr + (size_t)h * T_LEN * RANK;
    const float* vrh = vr + (size_t)h * T_LEN * RANK;
    float lmax = -INFINITY;
    for (int s = tid; s < T_LEN; s += 512) {
        const float* krr = krh + (size_t)s * RANK;
        float acc = 0.f;
#pragma unroll
        for (int r = 0; r < RANK; r += 4) {
            float4 k4 = *(const float4*)(krr + r);
            acc += qrs[r] * k4.x + qrs[r + 1] * k4.y + qrs[r + 2] * k4.z + qrs[r + 3] * k4.w;
        }
        float sc = acc * SCALE_G;
        sg[s] = sc;
        lmax = fmaxf(lmax, sc);
    }
    float gmx = block_reduce_max512(lmax, red, tid);
    float lsum = 0.f;
    for (int s = tid; s < T_LEN; s += 512) {
        float pp = expf(sg[s] - gmx);
        sg[s] = pp;
        lsum += pp;
    }
    float gsum = block_reduce_sum512(lsum, red, tid);

    {
        const int r = tid & 63, part = tid >> 6;
        float pacc = 0.f;
        for (int s = part; s < T_LEN; s += 8) pacc += sg[s] * vrh[(size_t)s * RANK + r];
        red[tid] = pacc;
        __syncthreads();
        if (tid < 64) {
            float c = 0.f;
#pragma unroll
            for (int pp = 0; pp < 8; ++pp) c += red[pp * 64 + tid];
            cgr[tid] = c / gsum;
        }
        __syncthreads();
    }

    if (tid < 128) {
        float cg = 0.f;
#pragma unroll
        for (int r = 0; r < RANK; ++r) cg += cgr[r] * uo[tid * RANK + r];
        size_t off = (size_t)t * 2048 + h * HD + tid;
        cxb[off] = (bf16_t)((float)cxb[off] + cg);
    }
}

// ---------------------------------------------------------------------------
extern "C" void kernel_launch(void* const* d_in, const int* in_sizes, int n_in,
                              void* d_out, int out_size, void* d_ws, size_t ws_size,
                              hipStream_t stream) {
    const float* x     = (const float*)d_in[0];
    const float* w_qkv = (const float*)d_in[1];
    const float* w_o   = (const float*)d_in[2];
    const float* pk    = (const float*)d_in[3];
    const float* pv    = (const float*)d_in[4];
    const float* uo    = (const float*)d_in[5];
    const float* w1    = (const float*)d_in[6];
    const float* w2    = (const float*)d_in[7];
    float* out = (float*)d_out;

    // Workspace layout (floats), lifetime-aliased (~88 MB):
    float* ws = (float*)d_ws;
    float* qkv   = ws;                        // 12,582,912 f: bf16 overlay rows
                                              //  q bf16 | K bf16 | wo bf16 | V bf16
    float* hinfo = qkv + (size_t)12582912;    // 1,048,576 f: rope tab, later qr bf16
    float* gatep = hinfo + (size_t)1048576;   // 2048 f
    bf16_t* xb   = (bf16_t*)(gatep + 2048);   // x_hi bf16 (later ctx bf16)
    float* wqbf  = gatep + 2048 + 2097152;    // 6,291,456 f region:
    bf16_t* wqb  = (bf16_t*)wqbf;             //   w_qkv bf16 (entire region)
    float* krp   = wqbf;                      //   later: kr
    float* vrp   = wqbf + (size_t)2097152;    //   later: vr
    float* tabp  = hinfo;                     // rope tables (dead before qr)
    bf16_t* qrp  = (bf16_t*)hinfo;            // qr bf16 (written by attn_fused)
    bf16_t* cxb  = xb;                        // ctx bf16
    bf16_t* qkvb = (bf16_t*)qkv;              // bf16 overlay view of qkv rows
    bf16_t* wob  = qkvb + WO_OFF;             // w_o bf16, row stride ROW_BF
    // d_out doubles as scratch until gemm_ctx_wo overwrites it:
    bf16_t* vtp  = (bf16_t*)d_out;            // V^T [16][128][2048] bf16 (8.39 MB)
    float* ipart = (float*)(vtp + (size_t)16 * 128 * 2048);  // 2x2048x512 f (8.39 MB)

    // 1) merged prep: x->bf16, w_qkv->bf16, rope tables
    prep_kernel<<<8704, 256, 0, stream>>>(x, xb, w_qkv, wqb, tabp);
    // 2) MERGED: info MLP + qkv GEMM v4 (fused RoPE, V overlay + V^T) + w_o->bf16
    gemm_qkv_rope<<<2944, 256, 0, stream>>>(xb, wqb, qkvb, vtp, tabp, w_o, x, w1, ipart);
    // 3) MERGED: local attention [0,512) + kvr [512,1024) + gate [1024,1536)
    attn_fused<<<1536, 256, 0, stream>>>(qkvb, vtp, cxb, pk, pv, krp, vrp, qrp,
                                         ipart, w2, gatep);
    // 4) gated global branch (bf16 RMW into cxb)
    global_attn_kernel<<<dim3(T_LEN, NH), 512, 0, stream>>>(cxb, krp, vrp, qrp, uo, gatep);
    // 5) out = ctx @ w_o^T  (v4 pipelined, 128x64 tiles, 2 blocks/CU)
    gemm_ctx_wo<<<512, 256, 0, stream>>>(cxb, wob, out);
}